// Round 1
// baseline (1342.548 us; speedup 1.0000x reference)
//
#include <hip/hip_runtime.h>

// ---------------------------------------------------------------------------
// GAT 3-layer forward on MI355X.
// Layers: (3 -> 4x64 concat, relu) -> (256 -> 4x64 concat, relu) -> (256 -> 1x32)
// Self-loops appended. Per-dst segment softmax with online (chunked) rescaling.
// ---------------------------------------------------------------------------

#define NEG_SLOPE 0.2f
#define SM_EPS 1e-16f

// --- edge dtype detection: int64 arrays read as int32 have zero odd words ---
__global__ void detect_i64_kernel(const int* __restrict__ ei, int* __restrict__ flag) {
  if (blockIdx.x == 0 && threadIdx.x == 0) {
    int orv = 0;
    for (int k = 0; k < 64; ++k) orv |= ei[2 * k + 1];
    *flag = (orv == 0) ? 1 : 0;
  }
}

__device__ __forceinline__ int load_idx(const int* __restrict__ ei, int logical, int is64) {
  return is64 ? ei[2 * logical] : ei[logical];
}

// --- CSR build -------------------------------------------------------------
__global__ void deg_kernel(const int* __restrict__ ei, int E, const int* __restrict__ flag,
                           int* __restrict__ deg) {
  int i = blockIdx.x * blockDim.x + threadIdx.x;
  if (i < E) {
    int d = load_idx(ei, E + i, *flag);
    atomicAdd(&deg[d], 1);
  }
}

// single block, 256 threads; rowptr gets deg[i]+1 (self loop) prefix-summed
__global__ void scan_kernel(const int* __restrict__ deg, int* __restrict__ rowptr, int N) {
  __shared__ int sums[256];
  int t = threadIdx.x;
  int per = (N + 255) / 256;
  int start = t * per;
  int end = start + per; if (end > N) end = N;
  int s = 0;
  for (int i = start; i < end; ++i) s += deg[i] + 1;
  sums[t] = s;
  __syncthreads();
  for (int d = 1; d < 256; d <<= 1) {
    int v = (t >= d) ? sums[t - d] : 0;
    __syncthreads();
    sums[t] += v;
    __syncthreads();
  }
  int run = sums[t] - s;  // exclusive
  for (int i = start; i < end; ++i) { rowptr[i] = run; run += deg[i] + 1; }
  if (start < N && end == N) rowptr[N] = run;
}

__global__ void scatter_kernel(const int* __restrict__ ei, int E, int N,
                               const int* __restrict__ flag,
                               int* __restrict__ cursor, int* __restrict__ colA) {
  int i = blockIdx.x * blockDim.x + threadIdx.x;
  int is64 = *flag;
  if (i < E) {
    int s = load_idx(ei, i, is64);
    int d = load_idx(ei, E + i, is64);
    int pos = atomicAdd(&cursor[d], 1);
    colA[pos] = s;
  } else if (i < E + N) {
    int n = i - E;
    int pos = atomicAdd(&cursor[n], 1);
    colA[pos] = n;
  }
}

// --- layer-1 GEMM: [N,3] @ [3,256] -> [N,256] ------------------------------
__global__ void gemm_k3_kernel(const float* __restrict__ x, const float* __restrict__ W,
                               float* __restrict__ h, int N) {
  int n = blockIdx.x;
  int c = threadIdx.x;
  if (n < N) {
    float x0 = x[n * 3 + 0], x1 = x[n * 3 + 1], x2 = x[n * 3 + 2];
    h[(size_t)n * 256 + c] = x0 * W[c] + x1 * W[256 + c] + x2 * W[512 + c];
  }
}

// --- generic tiled fp32 GEMM: C[M,N] = A[M,K] @ B[K,N], K % 16 == 0, N % 4 == 0
__global__ __launch_bounds__(256) void gemm_nn(const float* __restrict__ A,
                                               const float* __restrict__ B,
                                               float* __restrict__ Cm,
                                               int M, int N, int K) {
  __shared__ float As[64][17];
  __shared__ float Bs[16][64];
  int bm = blockIdx.y * 64, bn = blockIdx.x * 64;
  int tx = threadIdx.x & 15, ty = threadIdx.x >> 4;
  float acc[4][4] = {};
  for (int k0 = 0; k0 < K; k0 += 16) {
    {
      int row = threadIdx.x >> 2;        // 0..63
      int cq = (threadIdx.x & 3) << 2;   // 0,4,8,12
      int gr = bm + row;
      float4 v = make_float4(0.f, 0.f, 0.f, 0.f);
      if (gr < M) v = *reinterpret_cast<const float4*>(A + (size_t)gr * K + k0 + cq);
      As[row][cq + 0] = v.x; As[row][cq + 1] = v.y;
      As[row][cq + 2] = v.z; As[row][cq + 3] = v.w;
    }
    {
      int row = threadIdx.x >> 4;        // 0..15
      int cq = (threadIdx.x & 15) << 2;  // 0..60
      int gc = bn + cq;
      float4 v = make_float4(0.f, 0.f, 0.f, 0.f);
      if (gc < N) v = *reinterpret_cast<const float4*>(B + (size_t)(k0 + row) * N + gc);
      *reinterpret_cast<float4*>(&Bs[row][cq]) = v;
    }
    __syncthreads();
#pragma unroll
    for (int kk = 0; kk < 16; ++kk) {
      float a0 = As[ty * 4 + 0][kk];
      float a1 = As[ty * 4 + 1][kk];
      float a2 = As[ty * 4 + 2][kk];
      float a3 = As[ty * 4 + 3][kk];
      float4 b = *reinterpret_cast<const float4*>(&Bs[kk][tx * 4]);
      acc[0][0] += a0 * b.x; acc[0][1] += a0 * b.y; acc[0][2] += a0 * b.z; acc[0][3] += a0 * b.w;
      acc[1][0] += a1 * b.x; acc[1][1] += a1 * b.y; acc[1][2] += a1 * b.z; acc[1][3] += a1 * b.w;
      acc[2][0] += a2 * b.x; acc[2][1] += a2 * b.y; acc[2][2] += a2 * b.z; acc[2][3] += a2 * b.w;
      acc[3][0] += a3 * b.x; acc[3][1] += a3 * b.y; acc[3][2] += a3 * b.z; acc[3][3] += a3 * b.w;
    }
    __syncthreads();
  }
#pragma unroll
  for (int i = 0; i < 4; ++i) {
    int gr = bm + ty * 4 + i;
    if (gr < M) {
#pragma unroll
      for (int j = 0; j < 4; ++j) {
        int gc = bn + tx * 4 + j;
        if (gc < N) Cm[(size_t)gr * N + gc] = acc[i][j];
      }
    }
  }
}

// --- attention coefficients: as[n,h] = sum_c h[n,h,c]*a_src[h,c] -----------
__global__ void attn_coef_kernel(const float* __restrict__ h, const float* __restrict__ a_src,
                                 const float* __restrict__ a_dst, float* __restrict__ asv,
                                 float* __restrict__ adv, int N, int H, int C) {
  int n = blockIdx.x;
  int t = threadIdx.x;
  int HC = H * C;
  if (t < HC) {
    int hh = t / C, c = t % C;
    float v = h[(size_t)n * HC + t];
    float vs = v * a_src[t];
    float vd = v * a_dst[t];
    for (int off = C >> 1; off > 0; off >>= 1) {
      vs += __shfl_down(vs, off, C);
      vd += __shfl_down(vd, off, C);
    }
    if (c == 0) {
      asv[(size_t)n * H + hh] = vs;
      adv[(size_t)n * H + hh] = vd;
    }
  }
}

// --- per-dst softmax + aggregation (block per dst node) --------------------
template <int H, int C, bool RELU>
__global__ void gat_agg_kernel(const float* __restrict__ hbuf, const float* __restrict__ asv,
                               const float* __restrict__ adv, const int* __restrict__ rowptr,
                               const int* __restrict__ colA, const float* __restrict__ bias,
                               float* __restrict__ out, int N) {
  constexpr int HC = H * C;
  constexpr int CHK = 64;
  int d = blockIdx.x;
  int t = threadIdx.x;
  __shared__ float ad_sh[H], m_sh[H], s_sh[H], f_sh[H];
  __shared__ float w_lds[CHK * H];
  __shared__ int src_lds[CHK];
  if (t < H) {
    ad_sh[t] = adv[(size_t)d * H + t];
    m_sh[t] = -1e30f;
    s_sh[t] = 0.f;
  }
  int r0 = rowptr[d], r1 = rowptr[d + 1];
  float acc = 0.f;
  const int hh = (t < HC) ? (t / C) : 0;
  for (int base = r0; base < r1; base += CHK) {
    int len = r1 - base; if (len > CHK) len = CHK;
    __syncthreads();  // protects src_lds/w_lds reuse + initial ad/m/s
    if (t < len) src_lds[t] = colA[base + t];
    __syncthreads();
    if (t < len * H) {
      int e = t / H, h2 = t % H;
      float a = asv[(size_t)src_lds[e] * H + h2] + ad_sh[h2];
      w_lds[t] = (a > 0.f) ? a : NEG_SLOPE * a;
    }
    __syncthreads();
    if (t < H) {
      float mx = m_sh[t];
      for (int e = 0; e < len; ++e) mx = fmaxf(mx, w_lds[e * H + t]);
      f_sh[t] = __expf(m_sh[t] - mx);
      m_sh[t] = mx;
    }
    __syncthreads();
    if (t < len * H) {
      int h2 = t % H;
      w_lds[t] = __expf(w_lds[t] - m_sh[h2]);
    }
    if (t < HC) acc *= f_sh[hh];
    __syncthreads();
    if (t < H) {
      float ss = s_sh[t] * f_sh[t];
      for (int e = 0; e < len; ++e) ss += w_lds[e * H + t];
      s_sh[t] = ss;
    }
    if (t < HC) {
      for (int e = 0; e < len; ++e)
        acc += w_lds[e * H + hh] * hbuf[(size_t)src_lds[e] * HC + t];
    }
  }
  __syncthreads();
  if (t < HC) {
    float o = acc / (s_sh[hh] + SM_EPS) + bias[t];
    if (RELU) o = fmaxf(o, 0.f);
    out[(size_t)d * HC + t] = o;
  }
}

// ---------------------------------------------------------------------------
extern "C" void kernel_launch(void* const* d_in, const int* in_sizes, int n_in,
                              void* d_out, int out_size, void* d_ws, size_t ws_size,
                              hipStream_t stream) {
  const float* x   = (const float*)d_in[0];
  const int*   ei  = (const int*)d_in[1];
  const float* W1  = (const float*)d_in[2];
  const float* as1 = (const float*)d_in[3];
  const float* ad1 = (const float*)d_in[4];
  const float* b1  = (const float*)d_in[5];
  const float* W2  = (const float*)d_in[6];
  const float* as2 = (const float*)d_in[7];
  const float* ad2 = (const float*)d_in[8];
  const float* b2  = (const float*)d_in[9];
  const float* W3  = (const float*)d_in[10];
  const float* as3 = (const float*)d_in[11];
  const float* ad3 = (const float*)d_in[12];
  const float* b3  = (const float*)d_in[13];
  float* out = (float*)d_out;

  const int N = in_sizes[0] / 3;
  const int E = in_sizes[1] / 2;
  const int ET = E + N;  // with self loops

  char* ws = (char*)d_ws;
  size_t off = 0;
  auto alloc = [&](size_t bytes) -> void* {
    void* p = ws + off;
    off = (off + bytes + 255) & ~(size_t)255;
    return p;
  };
  float* bufA   = (float*)alloc((size_t)N * 256 * 4);
  float* bufB   = (float*)alloc((size_t)N * 256 * 4);
  float* asbuf  = (float*)alloc((size_t)N * 4 * 4);
  float* adbuf  = (float*)alloc((size_t)N * 4 * 4);
  int*   rowptr = (int*)alloc((size_t)(N + 1) * 4);
  int*   cursor = (int*)alloc((size_t)N * 4);
  int*   colA   = (int*)alloc((size_t)ET * 4);
  int*   dflag  = (int*)alloc(256);
  (void)ws_size;

  // --- CSR build (per call; no caching) ---
  detect_i64_kernel<<<1, 64, 0, stream>>>(ei, dflag);
  hipMemsetAsync(cursor, 0, (size_t)N * 4, stream);
  deg_kernel<<<(E + 255) / 256, 256, 0, stream>>>(ei, E, dflag, cursor);
  scan_kernel<<<1, 256, 0, stream>>>(cursor, rowptr, N);
  hipMemcpyAsync(cursor, rowptr, (size_t)N * 4, hipMemcpyDeviceToDevice, stream);
  scatter_kernel<<<(ET + 255) / 256, 256, 0, stream>>>(ei, E, N, dflag, cursor, colA);

  // --- layer 1: h1 = x@W1 -> bufA ; agg -> bufB (relu) ---
  gemm_k3_kernel<<<N, 256, 0, stream>>>(x, W1, bufA, N);
  attn_coef_kernel<<<N, 256, 0, stream>>>(bufA, as1, ad1, asbuf, adbuf, N, 4, 64);
  gat_agg_kernel<4, 64, true><<<N, 256, 0, stream>>>(bufA, asbuf, adbuf, rowptr, colA, b1, bufB, N);

  // --- layer 2: h2 = bufB@W2 -> bufA ; agg -> bufB (relu) ---
  {
    dim3 grid((256 + 63) / 64, (N + 63) / 64);
    gemm_nn<<<grid, 256, 0, stream>>>(bufB, W2, bufA, N, 256, 256);
  }
  attn_coef_kernel<<<N, 256, 0, stream>>>(bufA, as2, ad2, asbuf, adbuf, N, 4, 64);
  gat_agg_kernel<4, 64, true><<<N, 256, 0, stream>>>(bufA, asbuf, adbuf, rowptr, colA, b2, bufB, N);

  // --- layer 3: h3 = bufB@W3 -> bufA[0:N*32] ; agg -> out (no relu) ---
  {
    dim3 grid((32 + 63) / 64, (N + 63) / 64);
    gemm_nn<<<grid, 256, 0, stream>>>(bufB, W3, bufA, N, 32, 256);
  }
  attn_coef_kernel<<<N, 64, 0, stream>>>(bufA, as3, ad3, asbuf, adbuf, N, 1, 32);
  gat_agg_kernel<1, 32, false><<<N, 64, 0, stream>>>(bufA, asbuf, adbuf, rowptr, colA, b3, out, N);
}

// Round 2
// 1259.886 us; speedup vs baseline: 1.0656x; 1.0656x over previous
//
#include <hip/hip_runtime.h>

// ---------------------------------------------------------------------------
// GAT 3-layer forward on MI355X.
// R2: softmax stats split into a wave-per-dst kernel writing normalized
// per-edge weights (CSR order); gather kernel is a pure float4 FMA-gather
// (wave-per-dst, no LDS, no syncthreads).
// ---------------------------------------------------------------------------

#define NEG_SLOPE 0.2f
#define SM_EPS 1e-16f

// --- edge dtype detection: int64 arrays read as int32 have zero odd words ---
__global__ void detect_i64_kernel(const int* __restrict__ ei, int* __restrict__ flag) {
  if (blockIdx.x == 0 && threadIdx.x == 0) {
    int orv = 0;
    for (int k = 0; k < 64; ++k) orv |= ei[2 * k + 1];
    *flag = (orv == 0) ? 1 : 0;
  }
}

__device__ __forceinline__ int load_idx(const int* __restrict__ ei, int logical, int is64) {
  return is64 ? ei[2 * logical] : ei[logical];
}

// --- CSR build -------------------------------------------------------------
__global__ void deg_kernel(const int* __restrict__ ei, int E, const int* __restrict__ flag,
                           int* __restrict__ deg) {
  int i = blockIdx.x * blockDim.x + threadIdx.x;
  if (i < E) {
    int d = load_idx(ei, E + i, *flag);
    atomicAdd(&deg[d], 1);
  }
}

// single block, 256 threads; rowptr gets deg[i]+1 (self loop) prefix-summed
__global__ void scan_kernel(const int* __restrict__ deg, int* __restrict__ rowptr, int N) {
  __shared__ int sums[256];
  int t = threadIdx.x;
  int per = (N + 255) / 256;
  int start = t * per;
  int end = start + per; if (end > N) end = N;
  int s = 0;
  for (int i = start; i < end; ++i) s += deg[i] + 1;
  sums[t] = s;
  __syncthreads();
  for (int d = 1; d < 256; d <<= 1) {
    int v = (t >= d) ? sums[t - d] : 0;
    __syncthreads();
    sums[t] += v;
    __syncthreads();
  }
  int run = sums[t] - s;  // exclusive
  for (int i = start; i < end; ++i) { rowptr[i] = run; run += deg[i] + 1; }
  if (start < N && end == N) rowptr[N] = run;
}

__global__ void scatter_kernel(const int* __restrict__ ei, int E, int N,
                               const int* __restrict__ flag,
                               int* __restrict__ cursor, int* __restrict__ colA) {
  int i = blockIdx.x * blockDim.x + threadIdx.x;
  int is64 = *flag;
  if (i < E) {
    int s = load_idx(ei, i, is64);
    int d = load_idx(ei, E + i, is64);
    int pos = atomicAdd(&cursor[d], 1);
    colA[pos] = s;
  } else if (i < E + N) {
    int n = i - E;
    int pos = atomicAdd(&cursor[n], 1);
    colA[pos] = n;
  }
}

// --- layer-1 GEMM: [N,3] @ [3,256] -> [N,256] ------------------------------
__global__ void gemm_k3_kernel(const float* __restrict__ x, const float* __restrict__ W,
                               float* __restrict__ h, int N) {
  int n = blockIdx.x;
  int c = threadIdx.x;
  if (n < N) {
    float x0 = x[n * 3 + 0], x1 = x[n * 3 + 1], x2 = x[n * 3 + 2];
    h[(size_t)n * 256 + c] = x0 * W[c] + x1 * W[256 + c] + x2 * W[512 + c];
  }
}

// --- generic tiled fp32 GEMM: C[M,N] = A[M,K] @ B[K,N], K % 16 == 0, N % 4 == 0
__global__ __launch_bounds__(256) void gemm_nn(const float* __restrict__ A,
                                               const float* __restrict__ B,
                                               float* __restrict__ Cm,
                                               int M, int N, int K) {
  __shared__ float As[64][17];
  __shared__ float Bs[16][64];
  int bm = blockIdx.y * 64, bn = blockIdx.x * 64;
  int tx = threadIdx.x & 15, ty = threadIdx.x >> 4;
  float acc[4][4] = {};
  for (int k0 = 0; k0 < K; k0 += 16) {
    {
      int row = threadIdx.x >> 2;        // 0..63
      int cq = (threadIdx.x & 3) << 2;   // 0,4,8,12
      int gr = bm + row;
      float4 v = make_float4(0.f, 0.f, 0.f, 0.f);
      if (gr < M) v = *reinterpret_cast<const float4*>(A + (size_t)gr * K + k0 + cq);
      As[row][cq + 0] = v.x; As[row][cq + 1] = v.y;
      As[row][cq + 2] = v.z; As[row][cq + 3] = v.w;
    }
    {
      int row = threadIdx.x >> 4;        // 0..15
      int cq = (threadIdx.x & 15) << 2;  // 0..60
      int gc = bn + cq;
      float4 v = make_float4(0.f, 0.f, 0.f, 0.f);
      if (gc < N) v = *reinterpret_cast<const float4*>(B + (size_t)(k0 + row) * N + gc);
      *reinterpret_cast<float4*>(&Bs[row][cq]) = v;
    }
    __syncthreads();
#pragma unroll
    for (int kk = 0; kk < 16; ++kk) {
      float a0 = As[ty * 4 + 0][kk];
      float a1 = As[ty * 4 + 1][kk];
      float a2 = As[ty * 4 + 2][kk];
      float a3 = As[ty * 4 + 3][kk];
      float4 b = *reinterpret_cast<const float4*>(&Bs[kk][tx * 4]);
      acc[0][0] += a0 * b.x; acc[0][1] += a0 * b.y; acc[0][2] += a0 * b.z; acc[0][3] += a0 * b.w;
      acc[1][0] += a1 * b.x; acc[1][1] += a1 * b.y; acc[1][2] += a1 * b.z; acc[1][3] += a1 * b.w;
      acc[2][0] += a2 * b.x; acc[2][1] += a2 * b.y; acc[2][2] += a2 * b.z; acc[2][3] += a2 * b.w;
      acc[3][0] += a3 * b.x; acc[3][1] += a3 * b.y; acc[3][2] += a3 * b.z; acc[3][3] += a3 * b.w;
    }
    __syncthreads();
  }
#pragma unroll
  for (int i = 0; i < 4; ++i) {
    int gr = bm + ty * 4 + i;
    if (gr < M) {
#pragma unroll
      for (int j = 0; j < 4; ++j) {
        int gc = bn + tx * 4 + j;
        if (gc < N) Cm[(size_t)gr * N + gc] = acc[i][j];
      }
    }
  }
}

// --- attention coefficients: as[n,h] = sum_c h[n,h,c]*a_src[h,c] -----------
__global__ void attn_coef_kernel(const float* __restrict__ h, const float* __restrict__ a_src,
                                 const float* __restrict__ a_dst, float* __restrict__ asv,
                                 float* __restrict__ adv, int N, int H, int C) {
  int n = blockIdx.x;
  int t = threadIdx.x;
  int HC = H * C;
  if (t < HC) {
    int hh = t / C, c = t % C;
    float v = h[(size_t)n * HC + t];
    float vs = v * a_src[t];
    float vd = v * a_dst[t];
    for (int off = C >> 1; off > 0; off >>= 1) {
      vs += __shfl_down(vs, off, C);
      vd += __shfl_down(vd, off, C);
    }
    if (c == 0) {
      asv[(size_t)n * H + hh] = vs;
      adv[(size_t)n * H + hh] = vd;
    }
  }
}

// --- softmax stats: wave per dst; writes normalized weights in CSR order ---
// lane = e_local*H + h ; EPC = 64/H edges per chunk
template <int H>
__global__ __launch_bounds__(256) void gat_stats_kernel(
    const float* __restrict__ asv, const float* __restrict__ adv,
    const int* __restrict__ rowptr, const int* __restrict__ colA,
    float* __restrict__ wbuf, int N) {
  constexpr int EPC = 64 / H;
  constexpr int LOG2H = (H == 1) ? 0 : 2;  // H in {1,4}
  int wv = threadIdx.x >> 6;
  int d = blockIdx.x * 4 + wv;
  if (d >= N) return;
  int lane = threadIdx.x & 63;
  int el = lane >> LOG2H;
  int h = lane & (H - 1);
  float ad = adv[(size_t)d * H + h];
  int r0 = rowptr[d], r1 = rowptr[d + 1];
  int len = r1 - r0;
  float m = -1e30f, s = 0.f;
  for (int base = 0; base < len; base += EPC) {
    int e = base + el;
    float alpha = -1e30f;
    if (e < len) {
      int sc = colA[r0 + e];
      float a = asv[(size_t)sc * H + h] + ad;
      alpha = (a > 0.f) ? a : NEG_SLOPE * a;
    }
    float mx = alpha;
#pragma unroll
    for (int off = H; off < 64; off <<= 1) mx = fmaxf(mx, __shfl_xor(mx, off));
    float mn = fmaxf(m, mx);
    float ex = (e < len) ? __expf(alpha - mn) : 0.f;
    float cs = ex;
#pragma unroll
    for (int off = H; off < 64; off <<= 1) cs += __shfl_xor(cs, off);
    s = s * __expf(m - mn) + cs;
    m = mn;
  }
  float inv = 1.f / (s + SM_EPS);
  for (int base = 0; base < len; base += EPC) {
    int e = base + el;
    if (e < len) {
      int sc = colA[r0 + e];
      float a = asv[(size_t)sc * H + h] + ad;
      a = (a > 0.f) ? a : NEG_SLOPE * a;
      wbuf[(size_t)(r0 + e) * H + h] = __expf(a - m) * inv;
    }
  }
}

// --- gather: wave per dst, float4 per lane (H=4, C=64, HC=256) -------------
template <bool RELU>
__global__ __launch_bounds__(256) void gat_gather256_kernel(
    const float* __restrict__ hbuf, const float* __restrict__ wbuf,
    const int* __restrict__ rowptr, const int* __restrict__ colA,
    const float* __restrict__ bias, float* __restrict__ out, int N) {
  int wv = threadIdx.x >> 6;
  int d = blockIdx.x * 4 + wv;
  if (d >= N) return;
  int t = threadIdx.x & 63;
  int hh = t >> 4;  // head of channels [t*4, t*4+3]
  int r0 = rowptr[d], r1 = rowptr[d + 1];
  float4 acc = make_float4(0.f, 0.f, 0.f, 0.f);
#pragma unroll 2
  for (int e = r0; e < r1; ++e) {
    int sc = colA[e];
    float w = wbuf[(size_t)e * 4 + hh];
    const float4 hv = *reinterpret_cast<const float4*>(hbuf + (size_t)sc * 256 + t * 4);
    acc.x += w * hv.x; acc.y += w * hv.y; acc.z += w * hv.z; acc.w += w * hv.w;
  }
  const float4 bi = *reinterpret_cast<const float4*>(bias + t * 4);
  float4 o;
  o.x = acc.x + bi.x; o.y = acc.y + bi.y; o.z = acc.z + bi.z; o.w = acc.w + bi.w;
  if (RELU) {
    o.x = fmaxf(o.x, 0.f); o.y = fmaxf(o.y, 0.f);
    o.z = fmaxf(o.z, 0.f); o.w = fmaxf(o.w, 0.f);
  }
  *reinterpret_cast<float4*>(out + (size_t)d * 256 + t * 4) = o;
}

// --- gather: 32-lane group per dst (H=1, C=32) -----------------------------
__global__ __launch_bounds__(256) void gat_gather32_kernel(
    const float* __restrict__ hbuf, const float* __restrict__ wbuf,
    const int* __restrict__ rowptr, const int* __restrict__ colA,
    const float* __restrict__ bias, float* __restrict__ out, int N) {
  int g = threadIdx.x >> 5;
  int d = blockIdx.x * 8 + g;
  if (d >= N) return;
  int c = threadIdx.x & 31;
  int r0 = rowptr[d], r1 = rowptr[d + 1];
  float acc = 0.f;
#pragma unroll 2
  for (int e = r0; e < r1; ++e) {
    int sc = colA[e];
    float w = wbuf[e];
    acc += w * hbuf[(size_t)sc * 32 + c];
  }
  out[(size_t)d * 32 + c] = acc + bias[c];
}

// ---------------------------------------------------------------------------
extern "C" void kernel_launch(void* const* d_in, const int* in_sizes, int n_in,
                              void* d_out, int out_size, void* d_ws, size_t ws_size,
                              hipStream_t stream) {
  const float* x   = (const float*)d_in[0];
  const int*   ei  = (const int*)d_in[1];
  const float* W1  = (const float*)d_in[2];
  const float* as1 = (const float*)d_in[3];
  const float* ad1 = (const float*)d_in[4];
  const float* b1  = (const float*)d_in[5];
  const float* W2  = (const float*)d_in[6];
  const float* as2 = (const float*)d_in[7];
  const float* ad2 = (const float*)d_in[8];
  const float* b2  = (const float*)d_in[9];
  const float* W3  = (const float*)d_in[10];
  const float* as3 = (const float*)d_in[11];
  const float* ad3 = (const float*)d_in[12];
  const float* b3  = (const float*)d_in[13];
  float* out = (float*)d_out;

  const int N = in_sizes[0] / 3;
  const int E = in_sizes[1] / 2;
  const int ET = E + N;  // with self loops

  char* ws = (char*)d_ws;
  size_t off = 0;
  auto alloc = [&](size_t bytes) -> void* {
    void* p = ws + off;
    off = (off + bytes + 255) & ~(size_t)255;
    return p;
  };
  float* bufA   = (float*)alloc((size_t)N * 256 * 4);
  float* bufB   = (float*)alloc((size_t)N * 256 * 4);
  float* asbuf  = (float*)alloc((size_t)N * 4 * 4);
  float* adbuf  = (float*)alloc((size_t)N * 4 * 4);
  int*   rowptr = (int*)alloc((size_t)(N + 1) * 4);
  int*   cursor = (int*)alloc((size_t)N * 4);
  int*   colA   = (int*)alloc((size_t)ET * 4);
  float* wbuf   = (float*)alloc((size_t)ET * 4 * 4);
  int*   dflag  = (int*)alloc(256);
  (void)ws_size;

  // --- CSR build (per call; no caching) ---
  detect_i64_kernel<<<1, 64, 0, stream>>>(ei, dflag);
  hipMemsetAsync(cursor, 0, (size_t)N * 4, stream);
  deg_kernel<<<(E + 255) / 256, 256, 0, stream>>>(ei, E, dflag, cursor);
  scan_kernel<<<1, 256, 0, stream>>>(cursor, rowptr, N);
  hipMemcpyAsync(cursor, rowptr, (size_t)N * 4, hipMemcpyDeviceToDevice, stream);
  scatter_kernel<<<(ET + 255) / 256, 256, 0, stream>>>(ei, E, N, dflag, cursor, colA);

  const int nb4 = (N + 3) / 4;  // wave-per-dst launches (4 waves/block)
  const int nb8 = (N + 7) / 8;  // 32-lane-group-per-dst launches

  // --- layer 1: h1 = x@W1 -> bufA ; agg -> bufB (relu) ---
  gemm_k3_kernel<<<N, 256, 0, stream>>>(x, W1, bufA, N);
  attn_coef_kernel<<<N, 256, 0, stream>>>(bufA, as1, ad1, asbuf, adbuf, N, 4, 64);
  gat_stats_kernel<4><<<nb4, 256, 0, stream>>>(asbuf, adbuf, rowptr, colA, wbuf, N);
  gat_gather256_kernel<true><<<nb4, 256, 0, stream>>>(bufA, wbuf, rowptr, colA, b1, bufB, N);

  // --- layer 2: h2 = bufB@W2 -> bufA ; agg -> bufB (relu) ---
  {
    dim3 grid((256 + 63) / 64, (N + 63) / 64);
    gemm_nn<<<grid, 256, 0, stream>>>(bufB, W2, bufA, N, 256, 256);
  }
  attn_coef_kernel<<<N, 256, 0, stream>>>(bufA, as2, ad2, asbuf, adbuf, N, 4, 64);
  gat_stats_kernel<4><<<nb4, 256, 0, stream>>>(asbuf, adbuf, rowptr, colA, wbuf, N);
  gat_gather256_kernel<true><<<nb4, 256, 0, stream>>>(bufA, wbuf, rowptr, colA, b2, bufB, N);

  // --- layer 3: h3 = bufB@W3 -> bufA[0:N*32] ; agg -> out (no relu) ---
  {
    dim3 grid((32 + 63) / 64, (N + 63) / 64);
    gemm_nn<<<grid, 256, 0, stream>>>(bufB, W3, bufA, N, 32, 256);
  }
  attn_coef_kernel<<<N, 64, 0, stream>>>(bufA, as3, ad3, asbuf, adbuf, N, 1, 32);
  gat_stats_kernel<1><<<nb4, 256, 0, stream>>>(asbuf, adbuf, rowptr, colA, wbuf, N);
  gat_gather32_kernel<<<nb8, 256, 0, stream>>>(bufA, wbuf, rowptr, colA, b3, out, N);
}

// Round 3
// 893.479 us; speedup vs baseline: 1.5026x; 1.4101x over previous
//
#include <hip/hip_runtime.h>

// ---------------------------------------------------------------------------
// GAT 3-layer forward on MI355X. R3: bf16 feature pipeline + MFMA GEMM.
// Storage bf16 (ushort), accumulation fp32 throughout.
// ---------------------------------------------------------------------------

#define NEG_SLOPE 0.2f
#define SM_EPS 1e-16f

typedef __bf16 bf16x8 __attribute__((ext_vector_type(8)));
typedef float f32x4 __attribute__((ext_vector_type(4)));

__device__ __forceinline__ float bf2f(unsigned short u) {
  union { unsigned int i; float f; } v; v.i = ((unsigned int)u) << 16; return v.f;
}
__device__ __forceinline__ unsigned short f2bf(float f) {
  union { float f; unsigned int i; } v; v.f = f;
  unsigned int lsb = (v.i >> 16) & 1u;
  v.i += 0x7fffu + lsb;  // RNE
  return (unsigned short)(v.i >> 16);
}
__device__ __forceinline__ void bf2x(unsigned int u, float& f0, float& f1) {
  union { unsigned int i; float f; } a, b;
  a.i = u << 16; b.i = u & 0xffff0000u;
  f0 = a.f; f1 = b.f;
}

// --- edge dtype detection: int64 arrays read as int32 have zero odd words ---
__global__ void detect_i64_kernel(const int* __restrict__ ei, int* __restrict__ flag) {
  if (blockIdx.x == 0 && threadIdx.x == 0) {
    int orv = 0;
    for (int k = 0; k < 64; ++k) orv |= ei[2 * k + 1];
    *flag = (orv == 0) ? 1 : 0;
  }
}

__device__ __forceinline__ int load_idx(const int* __restrict__ ei, int logical, int is64) {
  return is64 ? ei[2 * logical] : ei[logical];
}

// --- CSR build -------------------------------------------------------------
__global__ void deg_kernel(const int* __restrict__ ei, int E, const int* __restrict__ flag,
                           int* __restrict__ deg) {
  int i = blockIdx.x * blockDim.x + threadIdx.x;
  if (i < E) {
    int d = load_idx(ei, E + i, *flag);
    atomicAdd(&deg[d], 1);
  }
}

__global__ void scan_kernel(const int* __restrict__ deg, int* __restrict__ rowptr, int N) {
  __shared__ int sums[256];
  int t = threadIdx.x;
  int per = (N + 255) / 256;
  int start = t * per;
  int end = start + per; if (end > N) end = N;
  int s = 0;
  for (int i = start; i < end; ++i) s += deg[i] + 1;
  sums[t] = s;
  __syncthreads();
  for (int d = 1; d < 256; d <<= 1) {
    int v = (t >= d) ? sums[t - d] : 0;
    __syncthreads();
    sums[t] += v;
    __syncthreads();
  }
  int run = sums[t] - s;  // exclusive
  for (int i = start; i < end; ++i) { rowptr[i] = run; run += deg[i] + 1; }
  if (start < N && end == N) rowptr[N] = run;
}

__global__ void scatter_kernel(const int* __restrict__ ei, int E, int N,
                               const int* __restrict__ flag,
                               int* __restrict__ cursor, int* __restrict__ colA) {
  int i = blockIdx.x * blockDim.x + threadIdx.x;
  int is64 = *flag;
  if (i < E) {
    int s = load_idx(ei, i, is64);
    int d = load_idx(ei, E + i, is64);
    int pos = atomicAdd(&cursor[d], 1);
    colA[pos] = s;
  } else if (i < E + N) {
    int n = i - E;
    int pos = atomicAdd(&cursor[n], 1);
    colA[pos] = n;
  }
}

// --- weight transpose + bf16 cast: Wt[n][k] = bf16(W[k][n]) ----------------
__global__ void wt_bf16_kernel(const float* __restrict__ W, unsigned short* __restrict__ Wt,
                               int K, int N) {
  int idx = blockIdx.x * 256 + threadIdx.x;
  if (idx < K * N) {
    int k = idx / N, n = idx - k * N;
    Wt[(size_t)n * K + k] = f2bf(W[idx]);
  }
}

// --- layer-1 GEMM: [N,3] @ [3,256] -> bf16 [N,256] -------------------------
__global__ void gemm_k3_kernel(const float* __restrict__ x, const float* __restrict__ W,
                               unsigned short* __restrict__ h, int N) {
  int n = blockIdx.x;
  int c = threadIdx.x;
  if (n < N) {
    float x0 = x[n * 3 + 0], x1 = x[n * 3 + 1], x2 = x[n * 3 + 2];
    h[(size_t)n * 256 + c] = f2bf(x0 * W[c] + x1 * W[256 + c] + x2 * W[512 + c]);
  }
}

// --- bf16 MFMA GEMM: C[M,N] = A[M,K] @ Bt[N,K]^T, K%64==0 ------------------
// Wave grid WR x WC; each wave computes 32x32 via 2x2 of 16x16x32 MFMA.
template <int WR, int WC>
__global__ __launch_bounds__(64 * WR * WC) void gemm_mfma(
    const unsigned short* __restrict__ A, const unsigned short* __restrict__ Bt,
    unsigned short* __restrict__ C, int M, int N, int K) {
  constexpr int BM = 32 * WR, BN = 32 * WC, BK = 64;
  constexpr int T = 64 * WR * WC;
  constexpr int RPP = T / 8;  // staging rows per pass (8 threads x 16B per row)
  __shared__ unsigned short As[BM][BK + 8];
  __shared__ unsigned short Bs[BN][BK + 8];
  const int bm = blockIdx.y * BM, bn = blockIdx.x * BN;
  const int tid = threadIdx.x, wid = tid >> 6, lane = tid & 63;
  const int wr = wid / WC, wc = wid % WC;
  const int lrow = lane & 15, lkh = lane >> 4;
  const int srow = tid >> 3, scol = (tid & 7) * 8;
  f32x4 acc[2][2] = {};
  for (int k0 = 0; k0 < K; k0 += BK) {
#pragma unroll
    for (int r0 = 0; r0 < BM; r0 += RPP) {
      int r = r0 + srow, gr = bm + r;
      uint4 v = make_uint4(0u, 0u, 0u, 0u);
      if (gr < M) v = *(const uint4*)(A + (size_t)gr * K + k0 + scol);
      *(uint4*)(&As[r][scol]) = v;
    }
#pragma unroll
    for (int r0 = 0; r0 < BN; r0 += RPP) {
      int r = r0 + srow;
      if (r < BN) {
        int gn = bn + r;
        uint4 v = *(const uint4*)(Bt + (size_t)gn * K + k0 + scol);
        *(uint4*)(&Bs[r][scol]) = v;
      }
    }
    __syncthreads();
#pragma unroll
    for (int kk = 0; kk < 2; ++kk) {
      bf16x8 a0 = *(const bf16x8*)(&As[wr * 32 + lrow][kk * 32 + lkh * 8]);
      bf16x8 a1 = *(const bf16x8*)(&As[wr * 32 + 16 + lrow][kk * 32 + lkh * 8]);
      bf16x8 b0 = *(const bf16x8*)(&Bs[wc * 32 + lrow][kk * 32 + lkh * 8]);
      bf16x8 b1 = *(const bf16x8*)(&Bs[wc * 32 + 16 + lrow][kk * 32 + lkh * 8]);
      acc[0][0] = __builtin_amdgcn_mfma_f32_16x16x32_bf16(a0, b0, acc[0][0], 0, 0, 0);
      acc[0][1] = __builtin_amdgcn_mfma_f32_16x16x32_bf16(a0, b1, acc[0][1], 0, 0, 0);
      acc[1][0] = __builtin_amdgcn_mfma_f32_16x16x32_bf16(a1, b0, acc[1][0], 0, 0, 0);
      acc[1][1] = __builtin_amdgcn_mfma_f32_16x16x32_bf16(a1, b1, acc[1][1], 0, 0, 0);
    }
    __syncthreads();
  }
  // epilogue: C/D layout col = lane&15, row = (lane>>4)*4 + q  [m89 verified]
#pragma unroll
  for (int m = 0; m < 2; ++m) {
#pragma unroll
    for (int q = 0; q < 4; ++q) {
      int grow = bm + wr * 32 + m * 16 + lkh * 4 + q;
      if (grow < M) {
#pragma unroll
        for (int n = 0; n < 2; ++n) {
          int gcol = bn + wc * 32 + n * 16 + lrow;
          C[(size_t)grow * N + gcol] = f2bf(acc[m][n][q]);
        }
      }
    }
  }
}

// --- attention coefficients from bf16 h ------------------------------------
__global__ void attn_coef_kernel(const unsigned short* __restrict__ h,
                                 const float* __restrict__ a_src,
                                 const float* __restrict__ a_dst, float* __restrict__ asv,
                                 float* __restrict__ adv, int N, int H, int C) {
  int n = blockIdx.x;
  int t = threadIdx.x;
  int HC = H * C;
  if (t < HC) {
    int hh = t / C, c = t % C;
    float v = bf2f(h[(size_t)n * HC + t]);
    float vs = v * a_src[t];
    float vd = v * a_dst[t];
    for (int off = C >> 1; off > 0; off >>= 1) {
      vs += __shfl_down(vs, off, C);
      vd += __shfl_down(vd, off, C);
    }
    if (c == 0) {
      asv[(size_t)n * H + hh] = vs;
      adv[(size_t)n * H + hh] = vd;
    }
  }
}

// --- softmax stats: wave per dst; writes normalized weights in CSR order ---
template <int H>
__global__ __launch_bounds__(256) void gat_stats_kernel(
    const float* __restrict__ asv, const float* __restrict__ adv,
    const int* __restrict__ rowptr, const int* __restrict__ colA,
    float* __restrict__ wbuf, int N) {
  constexpr int EPC = 64 / H;
  constexpr int LOG2H = (H == 1) ? 0 : 2;  // H in {1,4}
  int wv = threadIdx.x >> 6;
  int d = blockIdx.x * 4 + wv;
  if (d >= N) return;
  int lane = threadIdx.x & 63;
  int el = lane >> LOG2H;
  int h = lane & (H - 1);
  float ad = adv[(size_t)d * H + h];
  int r0 = rowptr[d], r1 = rowptr[d + 1];
  int len = r1 - r0;
  float m = -1e30f, s = 0.f;
  for (int base = 0; base < len; base += EPC) {
    int e = base + el;
    float alpha = -1e30f;
    if (e < len) {
      int sc = colA[r0 + e];
      float a = asv[(size_t)sc * H + h] + ad;
      alpha = (a > 0.f) ? a : NEG_SLOPE * a;
    }
    float mx = alpha;
#pragma unroll
    for (int off = H; off < 64; off <<= 1) mx = fmaxf(mx, __shfl_xor(mx, off));
    float mn = fmaxf(m, mx);
    float ex = (e < len) ? __expf(alpha - mn) : 0.f;
    float cs = ex;
#pragma unroll
    for (int off = H; off < 64; off <<= 1) cs += __shfl_xor(cs, off);
    s = s * __expf(m - mn) + cs;
    m = mn;
  }
  float inv = 1.f / (s + SM_EPS);
  for (int base = 0; base < len; base += EPC) {
    int e = base + el;
    if (e < len) {
      int sc = colA[r0 + e];
      float a = asv[(size_t)sc * H + h] + ad;
      a = (a > 0.f) ? a : NEG_SLOPE * a;
      wbuf[(size_t)(r0 + e) * H + h] = __expf(a - m) * inv;
    }
  }
}

// --- gather: 32-lane group per dst, bf16 h (H=4, C=64, HC=256) -------------
template <bool RELU>
__global__ __launch_bounds__(256) void gat_gather256_kernel(
    const unsigned short* __restrict__ hbuf, const float* __restrict__ wbuf,
    const int* __restrict__ rowptr, const int* __restrict__ colA,
    const float* __restrict__ bias, unsigned short* __restrict__ out, int N) {
  int g = threadIdx.x >> 5;
  int d = blockIdx.x * 8 + g;
  if (d >= N) return;
  int c = threadIdx.x & 31;   // channels [c*8, c*8+7]
  int hh = c >> 3;            // head
  int r0 = rowptr[d], r1 = rowptr[d + 1];
  float acc[8] = {};
  for (int e = r0; e < r1; ++e) {
    int sc = colA[e];
    float w = wbuf[(size_t)e * 4 + hh];
    uint4 hv = *(const uint4*)(hbuf + (size_t)sc * 256 + c * 8);
    float f0, f1;
    bf2x(hv.x, f0, f1); acc[0] += w * f0; acc[1] += w * f1;
    bf2x(hv.y, f0, f1); acc[2] += w * f0; acc[3] += w * f1;
    bf2x(hv.z, f0, f1); acc[4] += w * f0; acc[5] += w * f1;
    bf2x(hv.w, f0, f1); acc[6] += w * f0; acc[7] += w * f1;
  }
  unsigned short o[8];
#pragma unroll
  for (int j = 0; j < 8; ++j) {
    float v = acc[j] + bias[c * 8 + j];
    if (RELU) v = fmaxf(v, 0.f);
    o[j] = f2bf(v);
  }
  *(uint4*)(out + (size_t)d * 256 + c * 8) = *(uint4*)o;
}

// --- gather: 32-lane group per dst (H=1, C=32), fp32 out -------------------
__global__ __launch_bounds__(256) void gat_gather32_kernel(
    const unsigned short* __restrict__ hbuf, const float* __restrict__ wbuf,
    const int* __restrict__ rowptr, const int* __restrict__ colA,
    const float* __restrict__ bias, float* __restrict__ out, int N) {
  int g = threadIdx.x >> 5;
  int d = blockIdx.x * 8 + g;
  if (d >= N) return;
  int c = threadIdx.x & 31;
  int r0 = rowptr[d], r1 = rowptr[d + 1];
  float acc = 0.f;
#pragma unroll 2
  for (int e = r0; e < r1; ++e) {
    int sc = colA[e];
    acc += wbuf[e] * bf2f(hbuf[(size_t)sc * 32 + c]);
  }
  out[(size_t)d * 32 + c] = acc + bias[c];
}

// ---------------------------------------------------------------------------
extern "C" void kernel_launch(void* const* d_in, const int* in_sizes, int n_in,
                              void* d_out, int out_size, void* d_ws, size_t ws_size,
                              hipStream_t stream) {
  const float* x   = (const float*)d_in[0];
  const int*   ei  = (const int*)d_in[1];
  const float* W1  = (const float*)d_in[2];
  const float* as1 = (const float*)d_in[3];
  const float* ad1 = (const float*)d_in[4];
  const float* b1  = (const float*)d_in[5];
  const float* W2  = (const float*)d_in[6];
  const float* as2 = (const float*)d_in[7];
  const float* ad2 = (const float*)d_in[8];
  const float* b2  = (const float*)d_in[9];
  const float* W3  = (const float*)d_in[10];
  const float* as3 = (const float*)d_in[11];
  const float* ad3 = (const float*)d_in[12];
  const float* b3  = (const float*)d_in[13];
  float* out = (float*)d_out;

  const int N = in_sizes[0] / 3;
  const int E = in_sizes[1] / 2;
  const int ET = E + N;  // with self loops

  char* ws = (char*)d_ws;
  size_t off = 0;
  auto alloc = [&](size_t bytes) -> void* {
    void* p = ws + off;
    off = (off + bytes + 255) & ~(size_t)255;
    return p;
  };
  unsigned short* bufA = (unsigned short*)alloc((size_t)N * 256 * 2);
  unsigned short* bufB = (unsigned short*)alloc((size_t)N * 256 * 2);
  unsigned short* w2t  = (unsigned short*)alloc((size_t)256 * 256 * 2);
  unsigned short* w3t  = (unsigned short*)alloc((size_t)32 * 256 * 2);
  float* asbuf  = (float*)alloc((size_t)N * 4 * 4);
  float* adbuf  = (float*)alloc((size_t)N * 4 * 4);
  int*   rowptr = (int*)alloc((size_t)(N + 1) * 4);
  int*   cursor = (int*)alloc((size_t)N * 4);
  int*   colA   = (int*)alloc((size_t)ET * 4);
  float* wbuf   = (float*)alloc((size_t)ET * 4 * 4);
  int*   dflag  = (int*)alloc(256);
  (void)ws_size;

  // --- CSR build + weight prep ---
  detect_i64_kernel<<<1, 64, 0, stream>>>(ei, dflag);
  hipMemsetAsync(cursor, 0, (size_t)N * 4, stream);
  wt_bf16_kernel<<<(256 * 256 + 255) / 256, 256, 0, stream>>>(W2, w2t, 256, 256);
  wt_bf16_kernel<<<(256 * 32 + 255) / 256, 256, 0, stream>>>(W3, w3t, 256, 32);
  deg_kernel<<<(E + 255) / 256, 256, 0, stream>>>(ei, E, dflag, cursor);
  scan_kernel<<<1, 256, 0, stream>>>(cursor, rowptr, N);
  hipMemcpyAsync(cursor, rowptr, (size_t)N * 4, hipMemcpyDeviceToDevice, stream);
  scatter_kernel<<<(ET + 255) / 256, 256, 0, stream>>>(ei, E, N, dflag, cursor, colA);

  const int nb4 = (N + 3) / 4;
  const int nb8 = (N + 7) / 8;

  // --- layer 1 ---
  gemm_k3_kernel<<<N, 256, 0, stream>>>(x, W1, bufA, N);
  attn_coef_kernel<<<N, 256, 0, stream>>>(bufA, as1, ad1, asbuf, adbuf, N, 4, 64);
  gat_stats_kernel<4><<<nb4, 256, 0, stream>>>(asbuf, adbuf, rowptr, colA, wbuf, N);
  gat_gather256_kernel<true><<<nb8, 256, 0, stream>>>(bufA, wbuf, rowptr, colA, b1, bufB, N);

  // --- layer 2: h2 = bufB @ W2 (MFMA) -> bufA ---
  {
    dim3 grid(256 / 64, (N + 63) / 64);
    gemm_mfma<2, 2><<<grid, 256, 0, stream>>>(bufB, w2t, bufA, N, 256, 256);
  }
  attn_coef_kernel<<<N, 256, 0, stream>>>(bufA, as2, ad2, asbuf, adbuf, N, 4, 64);
  gat_stats_kernel<4><<<nb4, 256, 0, stream>>>(asbuf, adbuf, rowptr, colA, wbuf, N);
  gat_gather256_kernel<true><<<nb8, 256, 0, stream>>>(bufA, wbuf, rowptr, colA, b2, bufB, N);

  // --- layer 3: h3 = bufB @ W3 (MFMA) -> bufA[0:N*32] ---
  {
    dim3 grid(1, (N + 127) / 128);
    gemm_mfma<4, 1><<<grid, 256, 0, stream>>>(bufB, w3t, bufA, N, 32, 256);
  }
  attn_coef_kernel<<<N, 64, 0, stream>>>(bufA, as3, ad3, asbuf, adbuf, N, 1, 32);
  gat_stats_kernel<1><<<nb4, 256, 0, stream>>>(asbuf, adbuf, rowptr, colA, wbuf, N);
  gat_gather32_kernel<<<nb8, 256, 0, stream>>>(bufA, wbuf, rowptr, colA, b3, out, N);
}

// Round 4
// 740.047 us; speedup vs baseline: 1.8141x; 1.2073x over previous
//
#include <hip/hip_runtime.h>

// ---------------------------------------------------------------------------
// GAT 3-layer forward on MI355X. R4: parallel 3-phase CSR scan (the R3
// single-block scan was 162us of pure latency). bf16 features + MFMA GEMM.
// ---------------------------------------------------------------------------

#define NEG_SLOPE 0.2f
#define SM_EPS 1e-16f
#define SCAN_CHUNK 2048

typedef __bf16 bf16x8 __attribute__((ext_vector_type(8)));
typedef float f32x4 __attribute__((ext_vector_type(4)));

__device__ __forceinline__ float bf2f(unsigned short u) {
  union { unsigned int i; float f; } v; v.i = ((unsigned int)u) << 16; return v.f;
}
__device__ __forceinline__ unsigned short f2bf(float f) {
  union { float f; unsigned int i; } v; v.f = f;
  unsigned int lsb = (v.i >> 16) & 1u;
  v.i += 0x7fffu + lsb;  // RNE
  return (unsigned short)(v.i >> 16);
}
__device__ __forceinline__ void bf2x(unsigned int u, float& f0, float& f1) {
  union { unsigned int i; float f; } a, b;
  a.i = u << 16; b.i = u & 0xffff0000u;
  f0 = a.f; f1 = b.f;
}

// --- edge dtype detection: int64 arrays read as int32 have zero odd words ---
__global__ void detect_i64_kernel(const int* __restrict__ ei, int* __restrict__ flag) {
  if (blockIdx.x == 0 && threadIdx.x == 0) {
    int orv = 0;
    for (int k = 0; k < 64; ++k) orv |= ei[2 * k + 1];
    *flag = (orv == 0) ? 1 : 0;
  }
}

__device__ __forceinline__ int load_idx(const int* __restrict__ ei, int logical, int is64) {
  return is64 ? ei[2 * logical] : ei[logical];
}

// --- CSR build -------------------------------------------------------------
__global__ void deg_kernel(const int* __restrict__ ei, int E, const int* __restrict__ flag,
                           int* __restrict__ deg) {
  int i = blockIdx.x * blockDim.x + threadIdx.x;
  if (i < E) {
    int d = load_idx(ei, E + i, *flag);
    atomicAdd(&deg[d], 1);
  }
}

// phase A: per-block sums of (deg[i]+1) over SCAN_CHUNK elements
__global__ __launch_bounds__(256) void scan_phaseA(const int* __restrict__ deg,
                                                   int* __restrict__ bsum, int N) {
  int t = threadIdx.x;
  int base = blockIdx.x * SCAN_CHUNK + t * 8;
  int s = 0;
#pragma unroll
  for (int i = 0; i < 8; ++i) {
    int idx = base + i;
    if (idx < N) s += deg[idx] + 1;
  }
  __shared__ int red[256];
  red[t] = s;
  __syncthreads();
  for (int d = 128; d > 0; d >>= 1) {
    if (t < d) red[t] += red[t + d];
    __syncthreads();
  }
  if (t == 0) bsum[blockIdx.x] = red[0];
}

// phase B: single-block exclusive scan of block sums (nb <= 256)
__global__ void scan_phaseB(int* __restrict__ bsum, int nb) {
  __shared__ int sh[256];
  int t = threadIdx.x;
  int v = (t < nb) ? bsum[t] : 0;
  sh[t] = v;
  __syncthreads();
  for (int d = 1; d < 256; d <<= 1) {
    int u = (t >= d) ? sh[t - d] : 0;
    __syncthreads();
    sh[t] += u;
    __syncthreads();
  }
  if (t < nb) bsum[t] = sh[t] - v;  // exclusive
}

// phase C: local exclusive scan + block offset -> rowptr (and rowptr[N])
__global__ __launch_bounds__(256) void scan_phaseC(const int* __restrict__ deg,
                                                   const int* __restrict__ bsum,
                                                   int* __restrict__ rowptr, int N) {
  int t = threadIdx.x;
  int base = blockIdx.x * SCAN_CHUNK + t * 8;
  int v[8];
  int s = 0;
#pragma unroll
  for (int i = 0; i < 8; ++i) {
    int idx = base + i;
    v[i] = (idx < N) ? deg[idx] + 1 : 0;
    s += v[i];
  }
  __shared__ int sh[256];
  sh[t] = s;
  __syncthreads();
  for (int d = 1; d < 256; d <<= 1) {
    int u = (t >= d) ? sh[t - d] : 0;
    __syncthreads();
    sh[t] += u;
    __syncthreads();
  }
  int run = bsum[blockIdx.x] + sh[t] - s;
#pragma unroll
  for (int i = 0; i < 8; ++i) {
    int idx = base + i;
    if (idx < N) rowptr[idx] = run;
    run += v[i];
  }
  if (base < N && base + 8 >= N) rowptr[N] = run;
}

__global__ void scatter_kernel(const int* __restrict__ ei, int E, int N,
                               const int* __restrict__ flag,
                               int* __restrict__ cursor, int* __restrict__ colA) {
  int i = blockIdx.x * blockDim.x + threadIdx.x;
  int is64 = *flag;
  if (i < E) {
    int s = load_idx(ei, i, is64);
    int d = load_idx(ei, E + i, is64);
    int pos = atomicAdd(&cursor[d], 1);
    colA[pos] = s;
  } else if (i < E + N) {
    int n = i - E;
    int pos = atomicAdd(&cursor[n], 1);
    colA[pos] = n;
  }
}

// --- weight transpose + bf16 cast: Wt[n][k] = bf16(W[k][n]) ----------------
__global__ void wt_bf16_kernel(const float* __restrict__ W, unsigned short* __restrict__ Wt,
                               int K, int N) {
  int idx = blockIdx.x * 256 + threadIdx.x;
  if (idx < K * N) {
    int k = idx / N, n = idx - k * N;
    Wt[(size_t)n * K + k] = f2bf(W[idx]);
  }
}

// --- layer-1 GEMM: [N,3] @ [3,256] -> bf16 [N,256] -------------------------
__global__ void gemm_k3_kernel(const float* __restrict__ x, const float* __restrict__ W,
                               unsigned short* __restrict__ h, int N) {
  int n = blockIdx.x;
  int c = threadIdx.x;
  if (n < N) {
    float x0 = x[n * 3 + 0], x1 = x[n * 3 + 1], x2 = x[n * 3 + 2];
    h[(size_t)n * 256 + c] = f2bf(x0 * W[c] + x1 * W[256 + c] + x2 * W[512 + c]);
  }
}

// --- bf16 MFMA GEMM: C[M,N] = A[M,K] @ Bt[N,K]^T, K%64==0 ------------------
template <int WR, int WC>
__global__ __launch_bounds__(64 * WR * WC) void gemm_mfma(
    const unsigned short* __restrict__ A, const unsigned short* __restrict__ Bt,
    unsigned short* __restrict__ C, int M, int N, int K) {
  constexpr int BM = 32 * WR, BN = 32 * WC, BK = 64;
  constexpr int T = 64 * WR * WC;
  constexpr int RPP = T / 8;  // staging rows per pass (8 threads x 16B per row)
  __shared__ unsigned short As[BM][BK + 8];
  __shared__ unsigned short Bs[BN][BK + 8];
  const int bm = blockIdx.y * BM, bn = blockIdx.x * BN;
  const int tid = threadIdx.x, wid = tid >> 6, lane = tid & 63;
  const int wr = wid / WC, wc = wid % WC;
  const int lrow = lane & 15, lkh = lane >> 4;
  const int srow = tid >> 3, scol = (tid & 7) * 8;
  f32x4 acc[2][2] = {};
  for (int k0 = 0; k0 < K; k0 += BK) {
#pragma unroll
    for (int r0 = 0; r0 < BM; r0 += RPP) {
      int r = r0 + srow, gr = bm + r;
      uint4 v = make_uint4(0u, 0u, 0u, 0u);
      if (gr < M) v = *(const uint4*)(A + (size_t)gr * K + k0 + scol);
      *(uint4*)(&As[r][scol]) = v;
    }
#pragma unroll
    for (int r0 = 0; r0 < BN; r0 += RPP) {
      int r = r0 + srow;
      if (r < BN) {
        int gn = bn + r;
        uint4 v = *(const uint4*)(Bt + (size_t)gn * K + k0 + scol);
        *(uint4*)(&Bs[r][scol]) = v;
      }
    }
    __syncthreads();
#pragma unroll
    for (int kk = 0; kk < 2; ++kk) {
      bf16x8 a0 = *(const bf16x8*)(&As[wr * 32 + lrow][kk * 32 + lkh * 8]);
      bf16x8 a1 = *(const bf16x8*)(&As[wr * 32 + 16 + lrow][kk * 32 + lkh * 8]);
      bf16x8 b0 = *(const bf16x8*)(&Bs[wc * 32 + lrow][kk * 32 + lkh * 8]);
      bf16x8 b1 = *(const bf16x8*)(&Bs[wc * 32 + 16 + lrow][kk * 32 + lkh * 8]);
      acc[0][0] = __builtin_amdgcn_mfma_f32_16x16x32_bf16(a0, b0, acc[0][0], 0, 0, 0);
      acc[0][1] = __builtin_amdgcn_mfma_f32_16x16x32_bf16(a0, b1, acc[0][1], 0, 0, 0);
      acc[1][0] = __builtin_amdgcn_mfma_f32_16x16x32_bf16(a1, b0, acc[1][0], 0, 0, 0);
      acc[1][1] = __builtin_amdgcn_mfma_f32_16x16x32_bf16(a1, b1, acc[1][1], 0, 0, 0);
    }
    __syncthreads();
  }
  // epilogue: C/D layout col = lane&15, row = (lane>>4)*4 + q  [m89 verified]
#pragma unroll
  for (int m = 0; m < 2; ++m) {
#pragma unroll
    for (int q = 0; q < 4; ++q) {
      int grow = bm + wr * 32 + m * 16 + lkh * 4 + q;
      if (grow < M) {
#pragma unroll
        for (int n = 0; n < 2; ++n) {
          int gcol = bn + wc * 32 + n * 16 + lrow;
          C[(size_t)grow * N + gcol] = f2bf(acc[m][n][q]);
        }
      }
    }
  }
}

// --- attention coefficients from bf16 h ------------------------------------
__global__ void attn_coef_kernel(const unsigned short* __restrict__ h,
                                 const float* __restrict__ a_src,
                                 const float* __restrict__ a_dst, float* __restrict__ asv,
                                 float* __restrict__ adv, int N, int H, int C) {
  int n = blockIdx.x;
  int t = threadIdx.x;
  int HC = H * C;
  if (t < HC) {
    int hh = t / C, c = t % C;
    float v = bf2f(h[(size_t)n * HC + t]);
    float vs = v * a_src[t];
    float vd = v * a_dst[t];
    for (int off = C >> 1; off > 0; off >>= 1) {
      vs += __shfl_down(vs, off, C);
      vd += __shfl_down(vd, off, C);
    }
    if (c == 0) {
      asv[(size_t)n * H + hh] = vs;
      adv[(size_t)n * H + hh] = vd;
    }
  }
}

// --- softmax stats: wave per dst; writes normalized weights in CSR order ---
template <int H>
__global__ __launch_bounds__(256) void gat_stats_kernel(
    const float* __restrict__ asv, const float* __restrict__ adv,
    const int* __restrict__ rowptr, const int* __restrict__ colA,
    float* __restrict__ wbuf, int N) {
  constexpr int EPC = 64 / H;
  constexpr int LOG2H = (H == 1) ? 0 : 2;  // H in {1,4}
  int wv = threadIdx.x >> 6;
  int d = blockIdx.x * 4 + wv;
  if (d >= N) return;
  int lane = threadIdx.x & 63;
  int el = lane >> LOG2H;
  int h = lane & (H - 1);
  float ad = adv[(size_t)d * H + h];
  int r0 = rowptr[d], r1 = rowptr[d + 1];
  int len = r1 - r0;
  float m = -1e30f, s = 0.f;
  for (int base = 0; base < len; base += EPC) {
    int e = base + el;
    float alpha = -1e30f;
    if (e < len) {
      int sc = colA[r0 + e];
      float a = asv[(size_t)sc * H + h] + ad;
      alpha = (a > 0.f) ? a : NEG_SLOPE * a;
    }
    float mx = alpha;
#pragma unroll
    for (int off = H; off < 64; off <<= 1) mx = fmaxf(mx, __shfl_xor(mx, off));
    float mn = fmaxf(m, mx);
    float ex = (e < len) ? __expf(alpha - mn) : 0.f;
    float cs = ex;
#pragma unroll
    for (int off = H; off < 64; off <<= 1) cs += __shfl_xor(cs, off);
    s = s * __expf(m - mn) + cs;
    m = mn;
  }
  float inv = 1.f / (s + SM_EPS);
  for (int base = 0; base < len; base += EPC) {
    int e = base + el;
    if (e < len) {
      int sc = colA[r0 + e];
      float a = asv[(size_t)sc * H + h] + ad;
      a = (a > 0.f) ? a : NEG_SLOPE * a;
      wbuf[(size_t)(r0 + e) * H + h] = __expf(a - m) * inv;
    }
  }
}

// --- gather: 32-lane group per dst, bf16 h (H=4, C=64, HC=256) -------------
template <bool RELU>
__global__ __launch_bounds__(256) void gat_gather256_kernel(
    const unsigned short* __restrict__ hbuf, const float* __restrict__ wbuf,
    const int* __restrict__ rowptr, const int* __restrict__ colA,
    const float* __restrict__ bias, unsigned short* __restrict__ out, int N) {
  int g = threadIdx.x >> 5;
  int d = blockIdx.x * 8 + g;
  if (d >= N) return;
  int c = threadIdx.x & 31;   // channels [c*8, c*8+7]
  int hh = c >> 3;            // head
  int r0 = rowptr[d], r1 = rowptr[d + 1];
  float acc[8] = {};
  for (int e = r0; e < r1; ++e) {
    int sc = colA[e];
    float w = wbuf[(size_t)e * 4 + hh];
    uint4 hv = *(const uint4*)(hbuf + (size_t)sc * 256 + c * 8);
    float f0, f1;
    bf2x(hv.x, f0, f1); acc[0] += w * f0; acc[1] += w * f1;
    bf2x(hv.y, f0, f1); acc[2] += w * f0; acc[3] += w * f1;
    bf2x(hv.z, f0, f1); acc[4] += w * f0; acc[5] += w * f1;
    bf2x(hv.w, f0, f1); acc[6] += w * f0; acc[7] += w * f1;
  }
  unsigned short o[8];
#pragma unroll
  for (int j = 0; j < 8; ++j) {
    float v = acc[j] + bias[c * 8 + j];
    if (RELU) v = fmaxf(v, 0.f);
    o[j] = f2bf(v);
  }
  *(uint4*)(out + (size_t)d * 256 + c * 8) = *(uint4*)o;
}

// --- gather: 32-lane group per dst (H=1, C=32), fp32 out -------------------
__global__ __launch_bounds__(256) void gat_gather32_kernel(
    const unsigned short* __restrict__ hbuf, const float* __restrict__ wbuf,
    const int* __restrict__ rowptr, const int* __restrict__ colA,
    const float* __restrict__ bias, float* __restrict__ out, int N) {
  int g = threadIdx.x >> 5;
  int d = blockIdx.x * 8 + g;
  if (d >= N) return;
  int c = threadIdx.x & 31;
  int r0 = rowptr[d], r1 = rowptr[d + 1];
  float acc = 0.f;
#pragma unroll 2
  for (int e = r0; e < r1; ++e) {
    int sc = colA[e];
    acc += wbuf[e] * bf2f(hbuf[(size_t)sc * 32 + c]);
  }
  out[(size_t)d * 32 + c] = acc + bias[c];
}

// ---------------------------------------------------------------------------
extern "C" void kernel_launch(void* const* d_in, const int* in_sizes, int n_in,
                              void* d_out, int out_size, void* d_ws, size_t ws_size,
                              hipStream_t stream) {
  const float* x   = (const float*)d_in[0];
  const int*   ei  = (const int*)d_in[1];
  const float* W1  = (const float*)d_in[2];
  const float* as1 = (const float*)d_in[3];
  const float* ad1 = (const float*)d_in[4];
  const float* b1  = (const float*)d_in[5];
  const float* W2  = (const float*)d_in[6];
  const float* as2 = (const float*)d_in[7];
  const float* ad2 = (const float*)d_in[8];
  const float* b2  = (const float*)d_in[9];
  const float* W3  = (const float*)d_in[10];
  const float* as3 = (const float*)d_in[11];
  const float* ad3 = (const float*)d_in[12];
  const float* b3  = (const float*)d_in[13];
  float* out = (float*)d_out;

  const int N = in_sizes[0] / 3;
  const int E = in_sizes[1] / 2;
  const int ET = E + N;  // with self loops

  char* ws = (char*)d_ws;
  size_t off = 0;
  auto alloc = [&](size_t bytes) -> void* {
    void* p = ws + off;
    off = (off + bytes + 255) & ~(size_t)255;
    return p;
  };
  unsigned short* bufA = (unsigned short*)alloc((size_t)N * 256 * 2);
  unsigned short* bufB = (unsigned short*)alloc((size_t)N * 256 * 2);
  unsigned short* w2t  = (unsigned short*)alloc((size_t)256 * 256 * 2);
  unsigned short* w3t  = (unsigned short*)alloc((size_t)32 * 256 * 2);
  float* asbuf  = (float*)alloc((size_t)N * 4 * 4);
  float* adbuf  = (float*)alloc((size_t)N * 4 * 4);
  int*   rowptr = (int*)alloc((size_t)(N + 1) * 4);
  int*   cursor = (int*)alloc((size_t)N * 4);
  int*   colA   = (int*)alloc((size_t)ET * 4);
  float* wbuf   = (float*)alloc((size_t)ET * 4 * 4);
  int*   bsum   = (int*)alloc(1024);
  int*   dflag  = (int*)alloc(256);
  (void)ws_size;

  const int nScanB = (N + SCAN_CHUNK - 1) / SCAN_CHUNK;

  // --- CSR build + weight prep ---
  detect_i64_kernel<<<1, 64, 0, stream>>>(ei, dflag);
  hipMemsetAsync(cursor, 0, (size_t)N * 4, stream);
  wt_bf16_kernel<<<(256 * 256 + 255) / 256, 256, 0, stream>>>(W2, w2t, 256, 256);
  wt_bf16_kernel<<<(256 * 32 + 255) / 256, 256, 0, stream>>>(W3, w3t, 256, 32);
  deg_kernel<<<(E + 255) / 256, 256, 0, stream>>>(ei, E, dflag, cursor);
  scan_phaseA<<<nScanB, 256, 0, stream>>>(cursor, bsum, N);
  scan_phaseB<<<1, 256, 0, stream>>>(bsum, nScanB);
  scan_phaseC<<<nScanB, 256, 0, stream>>>(cursor, bsum, rowptr, N);
  hipMemcpyAsync(cursor, rowptr, (size_t)N * 4, hipMemcpyDeviceToDevice, stream);
  scatter_kernel<<<(ET + 255) / 256, 256, 0, stream>>>(ei, E, N, dflag, cursor, colA);

  const int nb4 = (N + 3) / 4;
  const int nb8 = (N + 7) / 8;

  // --- layer 1 ---
  gemm_k3_kernel<<<N, 256, 0, stream>>>(x, W1, bufA, N);
  attn_coef_kernel<<<N, 256, 0, stream>>>(bufA, as1, ad1, asbuf, adbuf, N, 4, 64);
  gat_stats_kernel<4><<<nb4, 256, 0, stream>>>(asbuf, adbuf, rowptr, colA, wbuf, N);
  gat_gather256_kernel<true><<<nb8, 256, 0, stream>>>(bufA, wbuf, rowptr, colA, b1, bufB, N);

  // --- layer 2: h2 = bufB @ W2 (MFMA) -> bufA ---
  {
    dim3 grid(256 / 64, (N + 63) / 64);
    gemm_mfma<2, 2><<<grid, 256, 0, stream>>>(bufB, w2t, bufA, N, 256, 256);
  }
  attn_coef_kernel<<<N, 256, 0, stream>>>(bufA, as2, ad2, asbuf, adbuf, N, 4, 64);
  gat_stats_kernel<4><<<nb4, 256, 0, stream>>>(asbuf, adbuf, rowptr, colA, wbuf, N);
  gat_gather256_kernel<true><<<nb8, 256, 0, stream>>>(bufA, wbuf, rowptr, colA, b2, bufB, N);

  // --- layer 3: h3 = bufB @ W3 (MFMA) -> bufA[0:N*32] ---
  {
    dim3 grid(1, (N + 127) / 128);
    gemm_mfma<4, 1><<<grid, 256, 0, stream>>>(bufB, w3t, bufA, N, 32, 256);
  }
  attn_coef_kernel<<<N, 64, 0, stream>>>(bufA, as3, ad3, asbuf, adbuf, N, 1, 32);
  gat_stats_kernel<1><<<nb4, 256, 0, stream>>>(asbuf, adbuf, rowptr, colA, wbuf, N);
  gat_gather32_kernel<<<nb8, 256, 0, stream>>>(bufA, wbuf, rowptr, colA, b3, out, N);
}

// Round 5
// 613.450 us; speedup vs baseline: 2.1885x; 1.2064x over previous
//
#include <hip/hip_runtime.h>

// ---------------------------------------------------------------------------
// GAT 3-layer forward on MI355X. R5: fusion round.
//  - softmax stats fused into gather (wave-per-dst, two-phase, weights
//    recomputed inline; wbuf eliminated)
//  - attention coefficients fused into GEMM epilogues (block tile = one head)
//  - scan phase C writes rowptr AND cursor (memcpy eliminated)
// ---------------------------------------------------------------------------

#define NEG_SLOPE 0.2f
#define SM_EPS 1e-16f
#define SCAN_CHUNK 2048

typedef __bf16 bf16x8 __attribute__((ext_vector_type(8)));
typedef float f32x4 __attribute__((ext_vector_type(4)));

__device__ __forceinline__ float bf2f(unsigned short u) {
  union { unsigned int i; float f; } v; v.i = ((unsigned int)u) << 16; return v.f;
}
__device__ __forceinline__ unsigned short f2bf(float f) {
  union { float f; unsigned int i; } v; v.f = f;
  unsigned int lsb = (v.i >> 16) & 1u;
  v.i += 0x7fffu + lsb;  // RNE
  return (unsigned short)(v.i >> 16);
}
__device__ __forceinline__ void bf2x(unsigned int u, float& f0, float& f1) {
  union { unsigned int i; float f; } a, b;
  a.i = u << 16; b.i = u & 0xffff0000u;
  f0 = a.f; f1 = b.f;
}

// --- edge dtype detection: int64 arrays read as int32 have zero odd words ---
__global__ void detect_i64_kernel(const int* __restrict__ ei, int* __restrict__ flag) {
  if (blockIdx.x == 0 && threadIdx.x == 0) {
    int orv = 0;
    for (int k = 0; k < 64; ++k) orv |= ei[2 * k + 1];
    *flag = (orv == 0) ? 1 : 0;
  }
}

__device__ __forceinline__ int load_idx(const int* __restrict__ ei, int logical, int is64) {
  return is64 ? ei[2 * logical] : ei[logical];
}

// --- CSR build -------------------------------------------------------------
__global__ void deg_kernel(const int* __restrict__ ei, int E, const int* __restrict__ flag,
                           int* __restrict__ deg) {
  int i = blockIdx.x * blockDim.x + threadIdx.x;
  if (i < E) {
    int d = load_idx(ei, E + i, *flag);
    atomicAdd(&deg[d], 1);
  }
}

__global__ __launch_bounds__(256) void scan_phaseA(const int* __restrict__ deg,
                                                   int* __restrict__ bsum, int N) {
  int t = threadIdx.x;
  int base = blockIdx.x * SCAN_CHUNK + t * 8;
  int s = 0;
#pragma unroll
  for (int i = 0; i < 8; ++i) {
    int idx = base + i;
    if (idx < N) s += deg[idx] + 1;
  }
  __shared__ int red[256];
  red[t] = s;
  __syncthreads();
  for (int d = 128; d > 0; d >>= 1) {
    if (t < d) red[t] += red[t + d];
    __syncthreads();
  }
  if (t == 0) bsum[blockIdx.x] = red[0];
}

__global__ void scan_phaseB(int* __restrict__ bsum, int nb) {
  __shared__ int sh[256];
  int t = threadIdx.x;
  int v = (t < nb) ? bsum[t] : 0;
  sh[t] = v;
  __syncthreads();
  for (int d = 1; d < 256; d <<= 1) {
    int u = (t >= d) ? sh[t - d] : 0;
    __syncthreads();
    sh[t] += u;
    __syncthreads();
  }
  if (t < nb) bsum[t] = sh[t] - v;  // exclusive
}

// phase C: local scan + offset -> rowptr AND cursor (scatter start positions)
__global__ __launch_bounds__(256) void scan_phaseC(const int* __restrict__ deg,
                                                   const int* __restrict__ bsum,
                                                   int* __restrict__ rowptr,
                                                   int* __restrict__ cursor, int N) {
  int t = threadIdx.x;
  int base = blockIdx.x * SCAN_CHUNK + t * 8;
  int v[8];
  int s = 0;
#pragma unroll
  for (int i = 0; i < 8; ++i) {
    int idx = base + i;
    v[i] = (idx < N) ? deg[idx] + 1 : 0;
    s += v[i];
  }
  __shared__ int sh[256];
  sh[t] = s;
  __syncthreads();
  for (int d = 1; d < 256; d <<= 1) {
    int u = (t >= d) ? sh[t - d] : 0;
    __syncthreads();
    sh[t] += u;
    __syncthreads();
  }
  int run = bsum[blockIdx.x] + sh[t] - s;
#pragma unroll
  for (int i = 0; i < 8; ++i) {
    int idx = base + i;
    if (idx < N) { rowptr[idx] = run; cursor[idx] = run; }
    run += v[i];
  }
  if (base < N && base + 8 >= N) rowptr[N] = run;
}

__global__ void scatter_kernel(const int* __restrict__ ei, int E, int N,
                               const int* __restrict__ flag,
                               int* __restrict__ cursor, int* __restrict__ colA) {
  int i = blockIdx.x * blockDim.x + threadIdx.x;
  int is64 = *flag;
  if (i < E) {
    int s = load_idx(ei, i, is64);
    int d = load_idx(ei, E + i, is64);
    int pos = atomicAdd(&cursor[d], 1);
    colA[pos] = s;
  } else if (i < E + N) {
    int n = i - E;
    int pos = atomicAdd(&cursor[n], 1);
    colA[pos] = n;
  }
}

// --- weight transpose + bf16 cast: Wt[n][k] = bf16(W[k][n]) ----------------
__global__ void wt_bf16_kernel(const float* __restrict__ W, unsigned short* __restrict__ Wt,
                               int K, int N) {
  int idx = blockIdx.x * 256 + threadIdx.x;
  if (idx < K * N) {
    int k = idx / N, n = idx - k * N;
    Wt[(size_t)n * K + k] = f2bf(W[idx]);
  }
}

// --- layer-1 GEMM + attn coefs: [N,3]@[3,256], wave = head ----------------
__global__ void gemm_k3_attn(const float* __restrict__ x, const float* __restrict__ W,
                             const float* __restrict__ a_src, const float* __restrict__ a_dst,
                             unsigned short* __restrict__ h, float* __restrict__ asv,
                             float* __restrict__ adv, int N) {
  int n = blockIdx.x;
  int t = threadIdx.x;
  float x0 = x[n * 3 + 0], x1 = x[n * 3 + 1], x2 = x[n * 3 + 2];
  float val = x0 * W[t] + x1 * W[256 + t] + x2 * W[512 + t];
  h[(size_t)n * 256 + t] = f2bf(val);
  float vs = val * a_src[t];
  float vd = val * a_dst[t];
#pragma unroll
  for (int off = 1; off < 64; off <<= 1) {
    vs += __shfl_xor(vs, off);
    vd += __shfl_xor(vd, off);
  }
  if ((t & 63) == 0) {
    asv[(size_t)n * 4 + (t >> 6)] = vs;
    adv[(size_t)n * 4 + (t >> 6)] = vd;
  }
}

// --- bf16 MFMA GEMM + fused attn epilogue ----------------------------------
// C[M,BNglobal] = A @ Bt^T. Requires BN == head channel count; hh = blockIdx.x
// (ATT_H==1 -> hh=0). a_src/a_dst indexed [hh*BN + col_in_block].
template <int WR, int WC, int ATT_H>
__global__ __launch_bounds__(64 * WR * WC) void gemm_mfma(
    const unsigned short* __restrict__ A, const unsigned short* __restrict__ Bt,
    unsigned short* __restrict__ C, const float* __restrict__ a_src,
    const float* __restrict__ a_dst, float* __restrict__ asv, float* __restrict__ adv,
    int M, int N, int K) {
  constexpr int BM = 32 * WR, BN = 32 * WC, BK = 64;
  constexpr int T = 64 * WR * WC;
  constexpr int RPP = T / 8;
  __shared__ unsigned short As[BM][BK + 8];
  __shared__ unsigned short Bs[BN][BK + 8];
  __shared__ float shs[WC][BM][2];
  const int bm = blockIdx.y * BM, bn = blockIdx.x * BN;
  const int tid = threadIdx.x, wid = tid >> 6, lane = tid & 63;
  const int wr = wid / WC, wc = wid % WC;
  const int lrow = lane & 15, lkh = lane >> 4;
  const int srow = tid >> 3, scol = (tid & 7) * 8;
  f32x4 acc[2][2] = {};
  for (int k0 = 0; k0 < K; k0 += BK) {
#pragma unroll
    for (int r0 = 0; r0 < BM; r0 += RPP) {
      int r = r0 + srow, gr = bm + r;
      uint4 v = make_uint4(0u, 0u, 0u, 0u);
      if (gr < M) v = *(const uint4*)(A + (size_t)gr * K + k0 + scol);
      *(uint4*)(&As[r][scol]) = v;
    }
#pragma unroll
    for (int r0 = 0; r0 < BN; r0 += RPP) {
      int r = r0 + srow;
      if (r < BN) {
        int gn = bn + r;
        uint4 v = *(const uint4*)(Bt + (size_t)gn * K + k0 + scol);
        *(uint4*)(&Bs[r][scol]) = v;
      }
    }
    __syncthreads();
#pragma unroll
    for (int kk = 0; kk < 2; ++kk) {
      bf16x8 a0 = *(const bf16x8*)(&As[wr * 32 + lrow][kk * 32 + lkh * 8]);
      bf16x8 a1 = *(const bf16x8*)(&As[wr * 32 + 16 + lrow][kk * 32 + lkh * 8]);
      bf16x8 b0 = *(const bf16x8*)(&Bs[wc * 32 + lrow][kk * 32 + lkh * 8]);
      bf16x8 b1 = *(const bf16x8*)(&Bs[wc * 32 + 16 + lrow][kk * 32 + lkh * 8]);
      acc[0][0] = __builtin_amdgcn_mfma_f32_16x16x32_bf16(a0, b0, acc[0][0], 0, 0, 0);
      acc[0][1] = __builtin_amdgcn_mfma_f32_16x16x32_bf16(a0, b1, acc[0][1], 0, 0, 0);
      acc[1][0] = __builtin_amdgcn_mfma_f32_16x16x32_bf16(a1, b0, acc[1][0], 0, 0, 0);
      acc[1][1] = __builtin_amdgcn_mfma_f32_16x16x32_bf16(a1, b1, acc[1][1], 0, 0, 0);
    }
    __syncthreads();
  }
  // C write: col = lane&15, row = (lane>>4)*4 + q
#pragma unroll
  for (int m = 0; m < 2; ++m) {
#pragma unroll
    for (int q = 0; q < 4; ++q) {
      int grow = bm + wr * 32 + m * 16 + lkh * 4 + q;
      if (grow < M) {
#pragma unroll
        for (int n = 0; n < 2; ++n) {
          int gcol = bn + wc * 32 + n * 16 + lrow;
          C[(size_t)grow * N + gcol] = f2bf(acc[m][n][q]);
        }
      }
    }
  }
  // fused attention-coefficient epilogue (full dot per block: BN == C_head)
  const int hh = (ATT_H == 1) ? 0 : (int)blockIdx.x;
  float asl[2], adl[2];
#pragma unroll
  for (int n = 0; n < 2; ++n) {
    int c = wc * 32 + n * 16 + lrow;
    asl[n] = a_src[hh * BN + c];
    adl[n] = a_dst[hh * BN + c];
  }
#pragma unroll
  for (int m = 0; m < 2; ++m) {
#pragma unroll
    for (int q = 0; q < 4; ++q) {
      float ps = acc[m][0][q] * asl[0] + acc[m][1][q] * asl[1];
      float pd = acc[m][0][q] * adl[0] + acc[m][1][q] * adl[1];
#pragma unroll
      for (int off = 1; off < 16; off <<= 1) {
        ps += __shfl_xor(ps, off);
        pd += __shfl_xor(pd, off);
      }
      int r = wr * 32 + m * 16 + lkh * 4 + q;
      if constexpr (WC == 1) {
        if (lrow == 0) {
          int grow = bm + r;
          if (grow < M) {
            asv[(size_t)grow * ATT_H + hh] = ps;
            adv[(size_t)grow * ATT_H + hh] = pd;
          }
        }
      } else {
        if (lrow == 0) { shs[wc][r][0] = ps; shs[wc][r][1] = pd; }
      }
    }
  }
  if constexpr (WC > 1) {
    __syncthreads();
    if (tid < BM) {
      int grow = bm + tid;
      if (grow < M) {
        float vs = 0.f, vd = 0.f;
#pragma unroll
        for (int w = 0; w < WC; ++w) { vs += shs[w][tid][0]; vd += shs[w][tid][1]; }
        asv[(size_t)grow * ATT_H + hh] = vs;
        adv[(size_t)grow * ATT_H + hh] = vd;
      }
    }
  }
}

// --- fused softmax + gather, H=4 C=64: wave per dst ------------------------
template <bool RELU>
__global__ __launch_bounds__(256) void gat_fused256(
    const unsigned short* __restrict__ hbuf, const float* __restrict__ asv,
    const float* __restrict__ adv, const int* __restrict__ rowptr,
    const int* __restrict__ colA, const float* __restrict__ bias,
    unsigned short* __restrict__ outb, int N) {
  int wv = threadIdx.x >> 6;
  int d = blockIdx.x * 4 + wv;
  if (d >= N) return;
  int lane = threadIdx.x & 63;
  int r0 = rowptr[d], r1 = rowptr[d + 1];
  int len = r1 - r0;
  // phase 1: online softmax stats. lane = el*4 + h4 (16 edges x 4 heads)
  int el = lane >> 2, h4 = lane & 3;
  float ad = adv[(size_t)d * 4 + h4];
  float m = -1e30f, s = 0.f;
  for (int base = 0; base < len; base += 16) {
    int e = base + el;
    float alpha = -1e30f;
    if (e < len) {
      int sc = colA[r0 + e];
      float a = asv[(size_t)sc * 4 + h4] + ad;
      alpha = (a > 0.f) ? a : NEG_SLOPE * a;
    }
    float mx = alpha;
#pragma unroll
    for (int off = 4; off < 64; off <<= 1) mx = fmaxf(mx, __shfl_xor(mx, off));
    float mn = fmaxf(m, mx);
    float ex = (e < len) ? __expf(alpha - mn) : 0.f;
#pragma unroll
    for (int off = 4; off < 64; off <<= 1) ex += __shfl_xor(ex, off);
    s = s * __expf(m - mn) + ex;
    m = mn;
  }
  // redistribute stats to gather layout: lane owns channels [lane*4, lane*4+3]
  int hh = lane >> 4;
  float m_h = __shfl(m, hh);
  float s_h = __shfl(s, hh);
  float ad_h = __shfl(ad, hh);
  float inv = 1.f / (s_h + SM_EPS);
  float acc0 = 0.f, acc1 = 0.f, acc2 = 0.f, acc3 = 0.f;
#pragma unroll 2
  for (int e = 0; e < len; ++e) {
    int sc = colA[r0 + e];
    float a = asv[(size_t)sc * 4 + hh] + ad_h;
    a = (a > 0.f) ? a : NEG_SLOPE * a;
    float w = __expf(a - m_h) * inv;
    uint2 hv = *(const uint2*)(hbuf + (size_t)sc * 256 + lane * 4);
    float f0, f1, f2, f3;
    bf2x(hv.x, f0, f1);
    bf2x(hv.y, f2, f3);
    acc0 += w * f0; acc1 += w * f1; acc2 += w * f2; acc3 += w * f3;
  }
  float b0 = bias[lane * 4 + 0], b1 = bias[lane * 4 + 1];
  float b2 = bias[lane * 4 + 2], b3 = bias[lane * 4 + 3];
  acc0 += b0; acc1 += b1; acc2 += b2; acc3 += b3;
  if (RELU) {
    acc0 = fmaxf(acc0, 0.f); acc1 = fmaxf(acc1, 0.f);
    acc2 = fmaxf(acc2, 0.f); acc3 = fmaxf(acc3, 0.f);
  }
  unsigned short o[4] = {f2bf(acc0), f2bf(acc1), f2bf(acc2), f2bf(acc3)};
  *(uint2*)(outb + (size_t)d * 256 + lane * 4) = *(uint2*)o;
}

// --- fused softmax + gather, H=1 C=32 (layer 3), fp32 out ------------------
__global__ __launch_bounds__(256) void gat_fused32(
    const unsigned short* __restrict__ hbuf, const float* __restrict__ asv,
    const float* __restrict__ adv, const int* __restrict__ rowptr,
    const int* __restrict__ colA, const float* __restrict__ bias,
    float* __restrict__ out, int N) {
  int wv = threadIdx.x >> 6;
  int d = blockIdx.x * 4 + wv;
  if (d >= N) return;
  int lane = threadIdx.x & 63;
  int r0 = rowptr[d], r1 = rowptr[d + 1];
  int len = r1 - r0;
  float ad = adv[d];
  // phase 1: 64 edges per chunk
  float m = -1e30f, s = 0.f;
  for (int base = 0; base < len; base += 64) {
    int e = base + lane;
    float alpha = -1e30f;
    if (e < len) {
      int sc = colA[r0 + e];
      float a = asv[sc] + ad;
      alpha = (a > 0.f) ? a : NEG_SLOPE * a;
    }
    float mx = alpha;
#pragma unroll
    for (int off = 1; off < 64; off <<= 1) mx = fmaxf(mx, __shfl_xor(mx, off));
    float mn = fmaxf(m, mx);
    float ex = (e < len) ? __expf(alpha - mn) : 0.f;
#pragma unroll
    for (int off = 1; off < 64; off <<= 1) ex += __shfl_xor(ex, off);
    s = s * __expf(m - mn) + ex;
    m = mn;
  }
  float inv = 1.f / (s + SM_EPS);
  // phase 2: 2 edges in flight (half-wave per edge), c = lane&31
  int half = lane >> 5, c = lane & 31;
  float acc = 0.f;
  for (int e0 = 0; e0 < len; e0 += 2) {
    int e = e0 + half;
    if (e < len) {
      int sc = colA[r0 + e];
      float a = asv[sc] + ad;
      a = (a > 0.f) ? a : NEG_SLOPE * a;
      float w = __expf(a - m) * inv;
      acc += w * bf2f(hbuf[(size_t)sc * 32 + c]);
    }
  }
  acc += __shfl_xor(acc, 32);
  if (half == 0) out[(size_t)d * 32 + c] = acc + bias[c];
}

// ---------------------------------------------------------------------------
extern "C" void kernel_launch(void* const* d_in, const int* in_sizes, int n_in,
                              void* d_out, int out_size, void* d_ws, size_t ws_size,
                              hipStream_t stream) {
  const float* x   = (const float*)d_in[0];
  const int*   ei  = (const int*)d_in[1];
  const float* W1  = (const float*)d_in[2];
  const float* as1 = (const float*)d_in[3];
  const float* ad1 = (const float*)d_in[4];
  const float* b1  = (const float*)d_in[5];
  const float* W2  = (const float*)d_in[6];
  const float* as2 = (const float*)d_in[7];
  const float* ad2 = (const float*)d_in[8];
  const float* b2  = (const float*)d_in[9];
  const float* W3  = (const float*)d_in[10];
  const float* as3 = (const float*)d_in[11];
  const float* ad3 = (const float*)d_in[12];
  const float* b3  = (const float*)d_in[13];
  float* out = (float*)d_out;

  const int N = in_sizes[0] / 3;
  const int E = in_sizes[1] / 2;
  const int ET = E + N;  // with self loops

  char* ws = (char*)d_ws;
  size_t off = 0;
  auto alloc = [&](size_t bytes) -> void* {
    void* p = ws + off;
    off = (off + bytes + 255) & ~(size_t)255;
    return p;
  };
  unsigned short* bufA = (unsigned short*)alloc((size_t)N * 256 * 2);
  unsigned short* bufB = (unsigned short*)alloc((size_t)N * 256 * 2);
  unsigned short* w2t  = (unsigned short*)alloc((size_t)256 * 256 * 2);
  unsigned short* w3t  = (unsigned short*)alloc((size_t)32 * 256 * 2);
  float* asbuf  = (float*)alloc((size_t)N * 4 * 4);
  float* adbuf  = (float*)alloc((size_t)N * 4 * 4);
  int*   rowptr = (int*)alloc((size_t)(N + 1) * 4);
  int*   cursor = (int*)alloc((size_t)N * 4);
  int*   colA   = (int*)alloc((size_t)ET * 4);
  int*   bsum   = (int*)alloc(1024);
  int*   dflag  = (int*)alloc(256);
  (void)ws_size;

  const int nScanB = (N + SCAN_CHUNK - 1) / SCAN_CHUNK;

  // --- CSR build + weight prep ---
  detect_i64_kernel<<<1, 64, 0, stream>>>(ei, dflag);
  hipMemsetAsync(cursor, 0, (size_t)N * 4, stream);
  wt_bf16_kernel<<<(256 * 256 + 255) / 256, 256, 0, stream>>>(W2, w2t, 256, 256);
  wt_bf16_kernel<<<(256 * 32 + 255) / 256, 256, 0, stream>>>(W3, w3t, 256, 32);
  deg_kernel<<<(E + 255) / 256, 256, 0, stream>>>(ei, E, dflag, cursor);
  scan_phaseA<<<nScanB, 256, 0, stream>>>(cursor, bsum, N);
  scan_phaseB<<<1, 256, 0, stream>>>(bsum, nScanB);
  scan_phaseC<<<nScanB, 256, 0, stream>>>(cursor, bsum, rowptr, cursor, N);
  scatter_kernel<<<(ET + 255) / 256, 256, 0, stream>>>(ei, E, N, dflag, cursor, colA);

  const int nb4 = (N + 3) / 4;

  // --- layer 1: GEMM+attn -> bufA ; fused agg -> bufB (relu) ---
  gemm_k3_attn<<<N, 256, 0, stream>>>(x, W1, as1, ad1, bufA, asbuf, adbuf, N);
  gat_fused256<true><<<nb4, 256, 0, stream>>>(bufA, asbuf, adbuf, rowptr, colA, b1, bufB, N);

  // --- layer 2: MFMA GEMM+attn -> bufA ; fused agg -> bufB (relu) ---
  {
    dim3 grid(256 / 64, (N + 63) / 64);
    gemm_mfma<2, 2, 4><<<grid, 256, 0, stream>>>(bufB, w2t, bufA, as2, ad2, asbuf, adbuf,
                                                 N, 256, 256);
  }
  gat_fused256<true><<<nb4, 256, 0, stream>>>(bufA, asbuf, adbuf, rowptr, colA, b2, bufB, N);

  // --- layer 3: MFMA GEMM+attn -> bufA[0:N*32] ; fused agg -> out ---
  {
    dim3 grid(1, (N + 127) / 128);
    gemm_mfma<4, 1, 1><<<grid, 256, 0, stream>>>(bufB, w3t, bufA, as3, ad3, asbuf, adbuf,
                                                 N, 32, 256);
  }
  gat_fused32<<<nb4, 256, 0, stream>>>(bufA, asbuf, adbuf, rowptr, colA, b3, out, N);
}

// Round 6
// 580.257 us; speedup vs baseline: 2.3137x; 1.0572x over previous
//
#include <hip/hip_runtime.h>

// ---------------------------------------------------------------------------
// GAT 3-layer forward on MI355X. R6: single-pass online-softmax gather.
//  - stats lane layout (h4*16+el) aligned with gather head -> running m/s
//    live in the right lanes; no redistribution
//  - per-edge weight computed ONCE per (edge,head), distributed via bpermute
//  - acc rescaled by exp(m_old-m_new) per chunk (online softmax)
// ---------------------------------------------------------------------------

#define NEG_SLOPE 0.2f
#define SM_EPS 1e-16f
#define SCAN_CHUNK 2048

typedef __bf16 bf16x8 __attribute__((ext_vector_type(8)));
typedef float f32x4 __attribute__((ext_vector_type(4)));

__device__ __forceinline__ float bf2f(unsigned short u) {
  union { unsigned int i; float f; } v; v.i = ((unsigned int)u) << 16; return v.f;
}
__device__ __forceinline__ unsigned short f2bf(float f) {
  union { float f; unsigned int i; } v; v.f = f;
  unsigned int lsb = (v.i >> 16) & 1u;
  v.i += 0x7fffu + lsb;  // RNE
  return (unsigned short)(v.i >> 16);
}
__device__ __forceinline__ void bf2x(unsigned int u, float& f0, float& f1) {
  union { unsigned int i; float f; } a, b;
  a.i = u << 16; b.i = u & 0xffff0000u;
  f0 = a.f; f1 = b.f;
}

// --- edge dtype detection: int64 arrays read as int32 have zero odd words ---
__global__ void detect_i64_kernel(const int* __restrict__ ei, int* __restrict__ flag) {
  if (blockIdx.x == 0 && threadIdx.x == 0) {
    int orv = 0;
    for (int k = 0; k < 64; ++k) orv |= ei[2 * k + 1];
    *flag = (orv == 0) ? 1 : 0;
  }
}

__device__ __forceinline__ int load_idx(const int* __restrict__ ei, int logical, int is64) {
  return is64 ? ei[2 * logical] : ei[logical];
}

// --- CSR build -------------------------------------------------------------
__global__ void deg_kernel(const int* __restrict__ ei, int E, const int* __restrict__ flag,
                           int* __restrict__ deg) {
  int i = blockIdx.x * blockDim.x + threadIdx.x;
  if (i < E) {
    int d = load_idx(ei, E + i, *flag);
    atomicAdd(&deg[d], 1);
  }
}

__global__ __launch_bounds__(256) void scan_phaseA(const int* __restrict__ deg,
                                                   int* __restrict__ bsum, int N) {
  int t = threadIdx.x;
  int base = blockIdx.x * SCAN_CHUNK + t * 8;
  int s = 0;
#pragma unroll
  for (int i = 0; i < 8; ++i) {
    int idx = base + i;
    if (idx < N) s += deg[idx] + 1;
  }
  __shared__ int red[256];
  red[t] = s;
  __syncthreads();
  for (int d = 128; d > 0; d >>= 1) {
    if (t < d) red[t] += red[t + d];
    __syncthreads();
  }
  if (t == 0) bsum[blockIdx.x] = red[0];
}

__global__ void scan_phaseB(int* __restrict__ bsum, int nb) {
  __shared__ int sh[256];
  int t = threadIdx.x;
  int v = (t < nb) ? bsum[t] : 0;
  sh[t] = v;
  __syncthreads();
  for (int d = 1; d < 256; d <<= 1) {
    int u = (t >= d) ? sh[t - d] : 0;
    __syncthreads();
    sh[t] += u;
    __syncthreads();
  }
  if (t < nb) bsum[t] = sh[t] - v;  // exclusive
}

// phase C: local scan + offset -> rowptr AND cursor (scatter start positions)
__global__ __launch_bounds__(256) void scan_phaseC(const int* __restrict__ deg,
                                                   const int* __restrict__ bsum,
                                                   int* __restrict__ rowptr,
                                                   int* __restrict__ cursor, int N) {
  int t = threadIdx.x;
  int base = blockIdx.x * SCAN_CHUNK + t * 8;
  int v[8];
  int s = 0;
#pragma unroll
  for (int i = 0; i < 8; ++i) {
    int idx = base + i;
    v[i] = (idx < N) ? deg[idx] + 1 : 0;
    s += v[i];
  }
  __shared__ int sh[256];
  sh[t] = s;
  __syncthreads();
  for (int d = 1; d < 256; d <<= 1) {
    int u = (t >= d) ? sh[t - d] : 0;
    __syncthreads();
    sh[t] += u;
    __syncthreads();
  }
  int run = bsum[blockIdx.x] + sh[t] - s;
#pragma unroll
  for (int i = 0; i < 8; ++i) {
    int idx = base + i;
    if (idx < N) { rowptr[idx] = run; cursor[idx] = run; }
    run += v[i];
  }
  if (base < N && base + 8 >= N) rowptr[N] = run;
}

__global__ void scatter_kernel(const int* __restrict__ ei, int E, int N,
                               const int* __restrict__ flag,
                               int* __restrict__ cursor, int* __restrict__ colA) {
  int i = blockIdx.x * blockDim.x + threadIdx.x;
  int is64 = *flag;
  if (i < E) {
    int s = load_idx(ei, i, is64);
    int d = load_idx(ei, E + i, is64);
    int pos = atomicAdd(&cursor[d], 1);
    colA[pos] = s;
  } else if (i < E + N) {
    int n = i - E;
    int pos = atomicAdd(&cursor[n], 1);
    colA[pos] = n;
  }
}

// --- weight transpose + bf16 cast: Wt[n][k] = bf16(W[k][n]) ----------------
__global__ void wt_bf16_kernel(const float* __restrict__ W, unsigned short* __restrict__ Wt,
                               int K, int N) {
  int idx = blockIdx.x * 256 + threadIdx.x;
  if (idx < K * N) {
    int k = idx / N, n = idx - k * N;
    Wt[(size_t)n * K + k] = f2bf(W[idx]);
  }
}

// --- layer-1 GEMM + attn coefs: [N,3]@[3,256], wave = head ----------------
__global__ void gemm_k3_attn(const float* __restrict__ x, const float* __restrict__ W,
                             const float* __restrict__ a_src, const float* __restrict__ a_dst,
                             unsigned short* __restrict__ h, float* __restrict__ asv,
                             float* __restrict__ adv, int N) {
  int n = blockIdx.x;
  int t = threadIdx.x;
  float x0 = x[n * 3 + 0], x1 = x[n * 3 + 1], x2 = x[n * 3 + 2];
  float val = x0 * W[t] + x1 * W[256 + t] + x2 * W[512 + t];
  h[(size_t)n * 256 + t] = f2bf(val);
  float vs = val * a_src[t];
  float vd = val * a_dst[t];
#pragma unroll
  for (int off = 1; off < 64; off <<= 1) {
    vs += __shfl_xor(vs, off);
    vd += __shfl_xor(vd, off);
  }
  if ((t & 63) == 0) {
    asv[(size_t)n * 4 + (t >> 6)] = vs;
    adv[(size_t)n * 4 + (t >> 6)] = vd;
  }
}

// --- bf16 MFMA GEMM + fused attn epilogue ----------------------------------
template <int WR, int WC, int ATT_H>
__global__ __launch_bounds__(64 * WR * WC) void gemm_mfma(
    const unsigned short* __restrict__ A, const unsigned short* __restrict__ Bt,
    unsigned short* __restrict__ C, const float* __restrict__ a_src,
    const float* __restrict__ a_dst, float* __restrict__ asv, float* __restrict__ adv,
    int M, int N, int K) {
  constexpr int BM = 32 * WR, BN = 32 * WC, BK = 64;
  constexpr int T = 64 * WR * WC;
  constexpr int RPP = T / 8;
  __shared__ unsigned short As[BM][BK + 8];
  __shared__ unsigned short Bs[BN][BK + 8];
  __shared__ float shs[WC][BM][2];
  const int bm = blockIdx.y * BM, bn = blockIdx.x * BN;
  const int tid = threadIdx.x, wid = tid >> 6, lane = tid & 63;
  const int wr = wid / WC, wc = wid % WC;
  const int lrow = lane & 15, lkh = lane >> 4;
  const int srow = tid >> 3, scol = (tid & 7) * 8;
  f32x4 acc[2][2] = {};
  for (int k0 = 0; k0 < K; k0 += BK) {
#pragma unroll
    for (int r0 = 0; r0 < BM; r0 += RPP) {
      int r = r0 + srow, gr = bm + r;
      uint4 v = make_uint4(0u, 0u, 0u, 0u);
      if (gr < M) v = *(const uint4*)(A + (size_t)gr * K + k0 + scol);
      *(uint4*)(&As[r][scol]) = v;
    }
#pragma unroll
    for (int r0 = 0; r0 < BN; r0 += RPP) {
      int r = r0 + srow;
      if (r < BN) {
        int gn = bn + r;
        uint4 v = *(const uint4*)(Bt + (size_t)gn * K + k0 + scol);
        *(uint4*)(&Bs[r][scol]) = v;
      }
    }
    __syncthreads();
#pragma unroll
    for (int kk = 0; kk < 2; ++kk) {
      bf16x8 a0 = *(const bf16x8*)(&As[wr * 32 + lrow][kk * 32 + lkh * 8]);
      bf16x8 a1 = *(const bf16x8*)(&As[wr * 32 + 16 + lrow][kk * 32 + lkh * 8]);
      bf16x8 b0 = *(const bf16x8*)(&Bs[wc * 32 + lrow][kk * 32 + lkh * 8]);
      bf16x8 b1 = *(const bf16x8*)(&Bs[wc * 32 + 16 + lrow][kk * 32 + lkh * 8]);
      acc[0][0] = __builtin_amdgcn_mfma_f32_16x16x32_bf16(a0, b0, acc[0][0], 0, 0, 0);
      acc[0][1] = __builtin_amdgcn_mfma_f32_16x16x32_bf16(a0, b1, acc[0][1], 0, 0, 0);
      acc[1][0] = __builtin_amdgcn_mfma_f32_16x16x32_bf16(a1, b0, acc[1][0], 0, 0, 0);
      acc[1][1] = __builtin_amdgcn_mfma_f32_16x16x32_bf16(a1, b1, acc[1][1], 0, 0, 0);
    }
    __syncthreads();
  }
  // C write: col = lane&15, row = (lane>>4)*4 + q
#pragma unroll
  for (int m = 0; m < 2; ++m) {
#pragma unroll
    for (int q = 0; q < 4; ++q) {
      int grow = bm + wr * 32 + m * 16 + lkh * 4 + q;
      if (grow < M) {
#pragma unroll
        for (int n = 0; n < 2; ++n) {
          int gcol = bn + wc * 32 + n * 16 + lrow;
          C[(size_t)grow * N + gcol] = f2bf(acc[m][n][q]);
        }
      }
    }
  }
  // fused attention-coefficient epilogue (full dot per block: BN == C_head)
  const int hh = (ATT_H == 1) ? 0 : (int)blockIdx.x;
  float asl[2], adl[2];
#pragma unroll
  for (int n = 0; n < 2; ++n) {
    int c = wc * 32 + n * 16 + lrow;
    asl[n] = a_src[hh * BN + c];
    adl[n] = a_dst[hh * BN + c];
  }
#pragma unroll
  for (int m = 0; m < 2; ++m) {
#pragma unroll
    for (int q = 0; q < 4; ++q) {
      float ps = acc[m][0][q] * asl[0] + acc[m][1][q] * asl[1];
      float pd = acc[m][0][q] * adl[0] + acc[m][1][q] * adl[1];
#pragma unroll
      for (int off = 1; off < 16; off <<= 1) {
        ps += __shfl_xor(ps, off);
        pd += __shfl_xor(pd, off);
      }
      int r = wr * 32 + m * 16 + lkh * 4 + q;
      if constexpr (WC == 1) {
        if (lrow == 0) {
          int grow = bm + r;
          if (grow < M) {
            asv[(size_t)grow * ATT_H + hh] = ps;
            adv[(size_t)grow * ATT_H + hh] = pd;
          }
        }
      } else {
        if (lrow == 0) { shs[wc][r][0] = ps; shs[wc][r][1] = pd; }
      }
    }
  }
  if constexpr (WC > 1) {
    __syncthreads();
    if (tid < BM) {
      int grow = bm + tid;
      if (grow < M) {
        float vs = 0.f, vd = 0.f;
#pragma unroll
        for (int w = 0; w < WC; ++w) { vs += shs[w][tid][0]; vd += shs[w][tid][1]; }
        asv[(size_t)grow * ATT_H + hh] = vs;
        adv[(size_t)grow * ATT_H + hh] = vd;
      }
    }
  }
}

// --- single-pass fused softmax+gather, H=4 C=64: wave per dst --------------
// lane = h4*16 + el : stats for head h4 over 16-edge chunks; h4 == gather head
template <bool RELU>
__global__ __launch_bounds__(256) void gat_fused256(
    const unsigned short* __restrict__ hbuf, const float* __restrict__ asv,
    const float* __restrict__ adv, const int* __restrict__ rowptr,
    const int* __restrict__ colA, const float* __restrict__ bias,
    unsigned short* __restrict__ outb, int N) {
  int wv = threadIdx.x >> 6;
  int d = blockIdx.x * 4 + wv;
  if (d >= N) return;
  int lane = threadIdx.x & 63;
  int h4 = lane >> 4, el = lane & 15;
  int r0 = rowptr[d], r1 = rowptr[d + 1];
  int len = r1 - r0;
  float ad = adv[(size_t)d * 4 + h4];
  float m = -1e30f, s = 0.f;
  float acc0 = 0.f, acc1 = 0.f, acc2 = 0.f, acc3 = 0.f;
  const int loff = lane * 4;  // channel block owned by this lane
  for (int base = 0; base < len; base += 16) {
    int rem = len - base; if (rem > 16) rem = 16;
    // weight computation for 16 edges x 4 heads (one lane each)
    int sc = 0;
    float alpha = -1e30f;
    if (el < rem) {
      sc = colA[r0 + base + el];
      float a = asv[(size_t)sc * 4 + h4] + ad;
      alpha = (a > 0.f) ? a : NEG_SLOPE * a;
    }
    float mx = alpha;
#pragma unroll
    for (int off = 1; off < 16; off <<= 1) mx = fmaxf(mx, __shfl_xor(mx, off));
    float mn = fmaxf(m, mx);
    float scale = __expf(m - mn);
    float w = (el < rem) ? __expf(alpha - mn) : 0.f;
    float cs = w;
#pragma unroll
    for (int off = 1; off < 16; off <<= 1) cs += __shfl_xor(cs, off);
    s = s * scale + cs;
    m = mn;
    acc0 *= scale; acc1 *= scale; acc2 *= scale; acc3 *= scale;
    // gather: per edge, weight/src pulled from lane (h4*16 + e2)
    int srcbase = lane & 48;  // h4*16
#pragma unroll 4
    for (int e2 = 0; e2 < rem; ++e2) {
      float w_e = __shfl(w, srcbase | e2);
      int sc_e = __shfl(sc, srcbase | e2);
      uint2 hv = *(const uint2*)(hbuf + (size_t)sc_e * 256 + loff);
      float f0, f1, f2, f3;
      bf2x(hv.x, f0, f1);
      bf2x(hv.y, f2, f3);
      acc0 += w_e * f0; acc1 += w_e * f1; acc2 += w_e * f2; acc3 += w_e * f3;
    }
  }
  float inv = 1.f / (s + SM_EPS);
  acc0 = acc0 * inv + bias[loff + 0];
  acc1 = acc1 * inv + bias[loff + 1];
  acc2 = acc2 * inv + bias[loff + 2];
  acc3 = acc3 * inv + bias[loff + 3];
  if (RELU) {
    acc0 = fmaxf(acc0, 0.f); acc1 = fmaxf(acc1, 0.f);
    acc2 = fmaxf(acc2, 0.f); acc3 = fmaxf(acc3, 0.f);
  }
  unsigned short o[4] = {f2bf(acc0), f2bf(acc1), f2bf(acc2), f2bf(acc3)};
  *(uint2*)(outb + (size_t)d * 256 + loff) = *(uint2*)o;
}

// --- single-pass fused softmax+gather, H=1 C=32 (layer 3), fp32 out --------
// stats: lane = edge (64/chunk). gather: 4 edges in flight (16 lanes each).
__global__ __launch_bounds__(256) void gat_fused32(
    const unsigned short* __restrict__ hbuf, const float* __restrict__ asv,
    const float* __restrict__ adv, const int* __restrict__ rowptr,
    const int* __restrict__ colA, const float* __restrict__ bias,
    float* __restrict__ out, int N) {
  int wv = threadIdx.x >> 6;
  int d = blockIdx.x * 4 + wv;
  if (d >= N) return;
  int lane = threadIdx.x & 63;
  int q = lane >> 4, cp = lane & 15;  // edge slot / channel pair
  int r0 = rowptr[d], r1 = rowptr[d + 1];
  int len = r1 - r0;
  float ad = adv[d];
  float m = -1e30f, s = 0.f;
  float acc0 = 0.f, acc1 = 0.f;
  for (int base = 0; base < len; base += 64) {
    int rem = len - base; if (rem > 64) rem = 64;
    int sc = 0;
    float alpha = -1e30f;
    if (lane < rem) {
      sc = colA[r0 + base + lane];
      float a = asv[sc] + ad;
      alpha = (a > 0.f) ? a : NEG_SLOPE * a;
    }
    float mx = alpha;
#pragma unroll
    for (int off = 1; off < 64; off <<= 1) mx = fmaxf(mx, __shfl_xor(mx, off));
    float mn = fmaxf(m, mx);
    float scale = __expf(m - mn);
    float w = (lane < rem) ? __expf(alpha - mn) : 0.f;
    float cs = w;
#pragma unroll
    for (int off = 1; off < 64; off <<= 1) cs += __shfl_xor(cs, off);
    s = s * scale + cs;
    m = mn;
    acc0 *= scale; acc1 *= scale;
#pragma unroll 2
    for (int e2 = 0; e2 < rem; e2 += 4) {
      int e = e2 + q;                 // w==0 for e>=rem, so no guard needed
      float w_e = __shfl(w, e & 63);
      int sc_e = __shfl(sc, e & 63);
      unsigned int hv = *(const unsigned int*)(hbuf + (size_t)sc_e * 32 + cp * 2);
      float f0, f1;
      bf2x(hv, f0, f1);
      acc0 += w_e * f0; acc1 += w_e * f1;
    }
  }
  // reduce the 4 edge-slot groups (lane bits 4..5)
  acc0 += __shfl_xor(acc0, 16); acc0 += __shfl_xor(acc0, 32);
  acc1 += __shfl_xor(acc1, 16); acc1 += __shfl_xor(acc1, 32);
  if (q == 0) {
    float inv = 1.f / (s + SM_EPS);
    float2 o;
    o.x = acc0 * inv + bias[cp * 2 + 0];
    o.y = acc1 * inv + bias[cp * 2 + 1];
    *(float2*)(out + (size_t)d * 32 + cp * 2) = o;
  }
}

// ---------------------------------------------------------------------------
extern "C" void kernel_launch(void* const* d_in, const int* in_sizes, int n_in,
                              void* d_out, int out_size, void* d_ws, size_t ws_size,
                              hipStream_t stream) {
  const float* x   = (const float*)d_in[0];
  const int*   ei  = (const int*)d_in[1];
  const float* W1  = (const float*)d_in[2];
  const float* as1 = (const float*)d_in[3];
  const float* ad1 = (const float*)d_in[4];
  const float* b1  = (const float*)d_in[5];
  const float* W2  = (const float*)d_in[6];
  const float* as2 = (const float*)d_in[7];
  const float* ad2 = (const float*)d_in[8];
  const float* b2  = (const float*)d_in[9];
  const float* W3  = (const float*)d_in[10];
  const float* as3 = (const float*)d_in[11];
  const float* ad3 = (const float*)d_in[12];
  const float* b3  = (const float*)d_in[13];
  float* out = (float*)d_out;

  const int N = in_sizes[0] / 3;
  const int E = in_sizes[1] / 2;
  const int ET = E + N;  // with self loops

  char* ws = (char*)d_ws;
  size_t off = 0;
  auto alloc = [&](size_t bytes) -> void* {
    void* p = ws + off;
    off = (off + bytes + 255) & ~(size_t)255;
    return p;
  };
  unsigned short* bufA = (unsigned short*)alloc((size_t)N * 256 * 2);
  unsigned short* bufB = (unsigned short*)alloc((size_t)N * 256 * 2);
  unsigned short* w2t  = (unsigned short*)alloc((size_t)256 * 256 * 2);
  unsigned short* w3t  = (unsigned short*)alloc((size_t)32 * 256 * 2);
  float* asbuf  = (float*)alloc((size_t)N * 4 * 4);
  float* adbuf  = (float*)alloc((size_t)N * 4 * 4);
  int*   rowptr = (int*)alloc((size_t)(N + 1) * 4);
  int*   cursor = (int*)alloc((size_t)N * 4);
  int*   colA   = (int*)alloc((size_t)ET * 4);
  int*   bsum   = (int*)alloc(1024);
  int*   dflag  = (int*)alloc(256);
  (void)ws_size;

  const int nScanB = (N + SCAN_CHUNK - 1) / SCAN_CHUNK;

  // --- CSR build + weight prep ---
  detect_i64_kernel<<<1, 64, 0, stream>>>(ei, dflag);
  hipMemsetAsync(cursor, 0, (size_t)N * 4, stream);
  wt_bf16_kernel<<<(256 * 256 + 255) / 256, 256, 0, stream>>>(W2, w2t, 256, 256);
  wt_bf16_kernel<<<(256 * 32 + 255) / 256, 256, 0, stream>>>(W3, w3t, 256, 32);
  deg_kernel<<<(E + 255) / 256, 256, 0, stream>>>(ei, E, dflag, cursor);
  scan_phaseA<<<nScanB, 256, 0, stream>>>(cursor, bsum, N);
  scan_phaseB<<<1, 256, 0, stream>>>(bsum, nScanB);
  scan_phaseC<<<nScanB, 256, 0, stream>>>(cursor, bsum, rowptr, cursor, N);
  scatter_kernel<<<(ET + 255) / 256, 256, 0, stream>>>(ei, E, N, dflag, cursor, colA);

  const int nb4 = (N + 3) / 4;

  // --- layer 1: GEMM+attn -> bufA ; fused agg -> bufB (relu) ---
  gemm_k3_attn<<<N, 256, 0, stream>>>(x, W1, as1, ad1, bufA, asbuf, adbuf, N);
  gat_fused256<true><<<nb4, 256, 0, stream>>>(bufA, asbuf, adbuf, rowptr, colA, b1, bufB, N);

  // --- layer 2: MFMA GEMM+attn -> bufA ; fused agg -> bufB (relu) ---
  {
    dim3 grid(256 / 64, (N + 63) / 64);
    gemm_mfma<2, 2, 4><<<grid, 256, 0, stream>>>(bufB, w2t, bufA, as2, ad2, asbuf, adbuf,
                                                 N, 256, 256);
  }
  gat_fused256<true><<<nb4, 256, 0, stream>>>(bufA, asbuf, adbuf, rowptr, colA, b2, bufB, N);

  // --- layer 3: MFMA GEMM+attn -> bufA[0:N*32] ; fused agg -> out ---
  {
    dim3 grid(1, (N + 127) / 128);
    gemm_mfma<4, 1, 1><<<grid, 256, 0, stream>>>(bufB, w3t, bufA, as3, ad3, asbuf, adbuf,
                                                 N, 32, 256);
  }
  gat_fused32<<<nb4, 256, 0, stream>>>(bufA, asbuf, adbuf, rowptr, colA, b3, out, N);
}

// Round 7
// 541.750 us; speedup vs baseline: 2.4782x; 1.0711x over previous
//
#include <hip/hip_runtime.h>

// ---------------------------------------------------------------------------
// GAT 3-layer forward on MI355X. R7: single-pass online-softmax gather with
// wide loads — two 32-lane groups per wave, each loading a full 512B edge row
// as uint4 (8 ch/lane), 2 edges in flight; cross-group combine at the end.
// ---------------------------------------------------------------------------

#define NEG_SLOPE 0.2f
#define SM_EPS 1e-16f
#define SCAN_CHUNK 2048

typedef __bf16 bf16x8 __attribute__((ext_vector_type(8)));
typedef float f32x4 __attribute__((ext_vector_type(4)));

__device__ __forceinline__ float bf2f(unsigned short u) {
  union { unsigned int i; float f; } v; v.i = ((unsigned int)u) << 16; return v.f;
}
__device__ __forceinline__ unsigned short f2bf(float f) {
  union { float f; unsigned int i; } v; v.f = f;
  unsigned int lsb = (v.i >> 16) & 1u;
  v.i += 0x7fffu + lsb;  // RNE
  return (unsigned short)(v.i >> 16);
}
__device__ __forceinline__ void bf2x(unsigned int u, float& f0, float& f1) {
  union { unsigned int i; float f; } a, b;
  a.i = u << 16; b.i = u & 0xffff0000u;
  f0 = a.f; f1 = b.f;
}

// --- edge dtype detection: int64 arrays read as int32 have zero odd words ---
__global__ void detect_i64_kernel(const int* __restrict__ ei, int* __restrict__ flag) {
  if (blockIdx.x == 0 && threadIdx.x == 0) {
    int orv = 0;
    for (int k = 0; k < 64; ++k) orv |= ei[2 * k + 1];
    *flag = (orv == 0) ? 1 : 0;
  }
}

__device__ __forceinline__ int load_idx(const int* __restrict__ ei, int logical, int is64) {
  return is64 ? ei[2 * logical] : ei[logical];
}

// --- CSR build -------------------------------------------------------------
__global__ void deg_kernel(const int* __restrict__ ei, int E, const int* __restrict__ flag,
                           int* __restrict__ deg) {
  int i = blockIdx.x * blockDim.x + threadIdx.x;
  if (i < E) {
    int d = load_idx(ei, E + i, *flag);
    atomicAdd(&deg[d], 1);
  }
}

__global__ __launch_bounds__(256) void scan_phaseA(const int* __restrict__ deg,
                                                   int* __restrict__ bsum, int N) {
  int t = threadIdx.x;
  int base = blockIdx.x * SCAN_CHUNK + t * 8;
  int s = 0;
#pragma unroll
  for (int i = 0; i < 8; ++i) {
    int idx = base + i;
    if (idx < N) s += deg[idx] + 1;
  }
  __shared__ int red[256];
  red[t] = s;
  __syncthreads();
  for (int d = 128; d > 0; d >>= 1) {
    if (t < d) red[t] += red[t + d];
    __syncthreads();
  }
  if (t == 0) bsum[blockIdx.x] = red[0];
}

__global__ void scan_phaseB(int* __restrict__ bsum, int nb) {
  __shared__ int sh[256];
  int t = threadIdx.x;
  int v = (t < nb) ? bsum[t] : 0;
  sh[t] = v;
  __syncthreads();
  for (int d = 1; d < 256; d <<= 1) {
    int u = (t >= d) ? sh[t - d] : 0;
    __syncthreads();
    sh[t] += u;
    __syncthreads();
  }
  if (t < nb) bsum[t] = sh[t] - v;  // exclusive
}

// phase C: local scan + offset -> rowptr AND cursor (scatter start positions)
__global__ __launch_bounds__(256) void scan_phaseC(const int* __restrict__ deg,
                                                   const int* __restrict__ bsum,
                                                   int* __restrict__ rowptr,
                                                   int* __restrict__ cursor, int N) {
  int t = threadIdx.x;
  int base = blockIdx.x * SCAN_CHUNK + t * 8;
  int v[8];
  int s = 0;
#pragma unroll
  for (int i = 0; i < 8; ++i) {
    int idx = base + i;
    v[i] = (idx < N) ? deg[idx] + 1 : 0;
    s += v[i];
  }
  __shared__ int sh[256];
  sh[t] = s;
  __syncthreads();
  for (int d = 1; d < 256; d <<= 1) {
    int u = (t >= d) ? sh[t - d] : 0;
    __syncthreads();
    sh[t] += u;
    __syncthreads();
  }
  int run = bsum[blockIdx.x] + sh[t] - s;
#pragma unroll
  for (int i = 0; i < 8; ++i) {
    int idx = base + i;
    if (idx < N) { rowptr[idx] = run; cursor[idx] = run; }
    run += v[i];
  }
  if (base < N && base + 8 >= N) rowptr[N] = run;
}

__global__ void scatter_kernel(const int* __restrict__ ei, int E, int N,
                               const int* __restrict__ flag,
                               int* __restrict__ cursor, int* __restrict__ colA) {
  int i = blockIdx.x * blockDim.x + threadIdx.x;
  int is64 = *flag;
  if (i < E) {
    int s = load_idx(ei, i, is64);
    int d = load_idx(ei, E + i, is64);
    int pos = atomicAdd(&cursor[d], 1);
    colA[pos] = s;
  } else if (i < E + N) {
    int n = i - E;
    int pos = atomicAdd(&cursor[n], 1);
    colA[pos] = n;
  }
}

// --- weight transpose + bf16 cast: Wt[n][k] = bf16(W[k][n]) ----------------
__global__ void wt_bf16_kernel(const float* __restrict__ W, unsigned short* __restrict__ Wt,
                               int K, int N) {
  int idx = blockIdx.x * 256 + threadIdx.x;
  if (idx < K * N) {
    int k = idx / N, n = idx - k * N;
    Wt[(size_t)n * K + k] = f2bf(W[idx]);
  }
}

// --- layer-1 GEMM + attn coefs: [N,3]@[3,256], wave = head ----------------
__global__ void gemm_k3_attn(const float* __restrict__ x, const float* __restrict__ W,
                             const float* __restrict__ a_src, const float* __restrict__ a_dst,
                             unsigned short* __restrict__ h, float* __restrict__ asv,
                             float* __restrict__ adv, int N) {
  int n = blockIdx.x;
  int t = threadIdx.x;
  float x0 = x[n * 3 + 0], x1 = x[n * 3 + 1], x2 = x[n * 3 + 2];
  float val = x0 * W[t] + x1 * W[256 + t] + x2 * W[512 + t];
  h[(size_t)n * 256 + t] = f2bf(val);
  float vs = val * a_src[t];
  float vd = val * a_dst[t];
#pragma unroll
  for (int off = 1; off < 64; off <<= 1) {
    vs += __shfl_xor(vs, off);
    vd += __shfl_xor(vd, off);
  }
  if ((t & 63) == 0) {
    asv[(size_t)n * 4 + (t >> 6)] = vs;
    adv[(size_t)n * 4 + (t >> 6)] = vd;
  }
}

// --- bf16 MFMA GEMM + fused attn epilogue ----------------------------------
template <int WR, int WC, int ATT_H>
__global__ __launch_bounds__(64 * WR * WC) void gemm_mfma(
    const unsigned short* __restrict__ A, const unsigned short* __restrict__ Bt,
    unsigned short* __restrict__ C, const float* __restrict__ a_src,
    const float* __restrict__ a_dst, float* __restrict__ asv, float* __restrict__ adv,
    int M, int N, int K) {
  constexpr int BM = 32 * WR, BN = 32 * WC, BK = 64;
  constexpr int T = 64 * WR * WC;
  constexpr int RPP = T / 8;
  __shared__ unsigned short As[BM][BK + 8];
  __shared__ unsigned short Bs[BN][BK + 8];
  __shared__ float shs[WC][BM][2];
  const int bm = blockIdx.y * BM, bn = blockIdx.x * BN;
  const int tid = threadIdx.x, wid = tid >> 6, lane = tid & 63;
  const int wr = wid / WC, wc = wid % WC;
  const int lrow = lane & 15, lkh = lane >> 4;
  const int srow = tid >> 3, scol = (tid & 7) * 8;
  f32x4 acc[2][2] = {};
  for (int k0 = 0; k0 < K; k0 += BK) {
#pragma unroll
    for (int r0 = 0; r0 < BM; r0 += RPP) {
      int r = r0 + srow, gr = bm + r;
      uint4 v = make_uint4(0u, 0u, 0u, 0u);
      if (gr < M) v = *(const uint4*)(A + (size_t)gr * K + k0 + scol);
      *(uint4*)(&As[r][scol]) = v;
    }
#pragma unroll
    for (int r0 = 0; r0 < BN; r0 += RPP) {
      int r = r0 + srow;
      if (r < BN) {
        int gn = bn + r;
        uint4 v = *(const uint4*)(Bt + (size_t)gn * K + k0 + scol);
        *(uint4*)(&Bs[r][scol]) = v;
      }
    }
    __syncthreads();
#pragma unroll
    for (int kk = 0; kk < 2; ++kk) {
      bf16x8 a0 = *(const bf16x8*)(&As[wr * 32 + lrow][kk * 32 + lkh * 8]);
      bf16x8 a1 = *(const bf16x8*)(&As[wr * 32 + 16 + lrow][kk * 32 + lkh * 8]);
      bf16x8 b0 = *(const bf16x8*)(&Bs[wc * 32 + lrow][kk * 32 + lkh * 8]);
      bf16x8 b1 = *(const bf16x8*)(&Bs[wc * 32 + 16 + lrow][kk * 32 + lkh * 8]);
      acc[0][0] = __builtin_amdgcn_mfma_f32_16x16x32_bf16(a0, b0, acc[0][0], 0, 0, 0);
      acc[0][1] = __builtin_amdgcn_mfma_f32_16x16x32_bf16(a0, b1, acc[0][1], 0, 0, 0);
      acc[1][0] = __builtin_amdgcn_mfma_f32_16x16x32_bf16(a1, b0, acc[1][0], 0, 0, 0);
      acc[1][1] = __builtin_amdgcn_mfma_f32_16x16x32_bf16(a1, b1, acc[1][1], 0, 0, 0);
    }
    __syncthreads();
  }
  // C write: col = lane&15, row = (lane>>4)*4 + q
#pragma unroll
  for (int m = 0; m < 2; ++m) {
#pragma unroll
    for (int q = 0; q < 4; ++q) {
      int grow = bm + wr * 32 + m * 16 + lkh * 4 + q;
      if (grow < M) {
#pragma unroll
        for (int n = 0; n < 2; ++n) {
          int gcol = bn + wc * 32 + n * 16 + lrow;
          C[(size_t)grow * N + gcol] = f2bf(acc[m][n][q]);
        }
      }
    }
  }
  // fused attention-coefficient epilogue (full dot per block: BN == C_head)
  const int hh = (ATT_H == 1) ? 0 : (int)blockIdx.x;
  float asl[2], adl[2];
#pragma unroll
  for (int n = 0; n < 2; ++n) {
    int c = wc * 32 + n * 16 + lrow;
    asl[n] = a_src[hh * BN + c];
    adl[n] = a_dst[hh * BN + c];
  }
#pragma unroll
  for (int m = 0; m < 2; ++m) {
#pragma unroll
    for (int q = 0; q < 4; ++q) {
      float ps = acc[m][0][q] * asl[0] + acc[m][1][q] * asl[1];
      float pd = acc[m][0][q] * adl[0] + acc[m][1][q] * adl[1];
#pragma unroll
      for (int off = 1; off < 16; off <<= 1) {
        ps += __shfl_xor(ps, off);
        pd += __shfl_xor(pd, off);
      }
      int r = wr * 32 + m * 16 + lkh * 4 + q;
      if constexpr (WC == 1) {
        if (lrow == 0) {
          int grow = bm + r;
          if (grow < M) {
            asv[(size_t)grow * ATT_H + hh] = ps;
            adv[(size_t)grow * ATT_H + hh] = pd;
          }
        }
      } else {
        if (lrow == 0) { shs[wc][r][0] = ps; shs[wc][r][1] = pd; }
      }
    }
  }
  if constexpr (WC > 1) {
    __syncthreads();
    if (tid < BM) {
      int grow = bm + tid;
      if (grow < M) {
        float vs = 0.f, vd = 0.f;
#pragma unroll
        for (int w = 0; w < WC; ++w) { vs += shs[w][tid][0]; vd += shs[w][tid][1]; }
        asv[(size_t)grow * ATT_H + hh] = vs;
        adv[(size_t)grow * ATT_H + hh] = vd;
      }
    }
  }
}

// --- single-pass fused softmax+gather, H=4 C=64: wave per dst --------------
// stats lanes: lane = h4*16 + el (16 edges x 4 heads per chunk).
// gather: two 32-lane groups, each loads a full 512B edge row (uint4,
// 8 ch/lane), 2 edges in flight; cross-group shfl_xor(32) combine at end.
template <bool RELU>
__global__ __launch_bounds__(256) void gat_fused256(
    const unsigned short* __restrict__ hbuf, const float* __restrict__ asv,
    const float* __restrict__ adv, const int* __restrict__ rowptr,
    const int* __restrict__ colA, const float* __restrict__ bias,
    unsigned short* __restrict__ outb, int N) {
  int wv = threadIdx.x >> 6;
  int d = blockIdx.x * 4 + wv;
  if (d >= N) return;
  int lane = threadIdx.x & 63;
  int h4 = lane >> 4, el = lane & 15;       // stats role
  int g = lane >> 5, c32 = lane & 31;       // gather role: group, channel slot
  int hh = c32 >> 3;                        // head owning channels [c32*8 ..]
  int r0 = rowptr[d], r1 = rowptr[d + 1];
  int len = r1 - r0;
  float ad = adv[(size_t)d * 4 + h4];
  float m = -1e30f, s = 0.f;
  float acc[8] = {};
  const int hsrc = hh * 16;                 // stat lane base for this head
  for (int base = 0; base < len; base += 16) {
    int rem = len - base; if (rem > 16) rem = 16;
    // weights for 16 edges x 4 heads (one per stat lane)
    int sc = 0;
    float alpha = -1e30f;
    if (el < rem) {
      sc = colA[r0 + base + el];
      float a = asv[(size_t)sc * 4 + h4] + ad;
      alpha = (a > 0.f) ? a : NEG_SLOPE * a;
    }
    float mx = alpha;
#pragma unroll
    for (int off = 1; off < 16; off <<= 1) mx = fmaxf(mx, __shfl_xor(mx, off));
    float mn = fmaxf(m, mx);
    float scale = __expf(m - mn);
    float w = (el < rem) ? __expf(alpha - mn) : 0.f;
    float cs = w;
#pragma unroll
    for (int off = 1; off < 16; off <<= 1) cs += __shfl_xor(cs, off);
    s = s * scale + cs;
    m = mn;
    // rescale acc by this head's scale
    float scale_h = __shfl(scale, hsrc);
#pragma unroll
    for (int j = 0; j < 8; ++j) acc[j] *= scale_h;
    // gather: group g takes edges e2+g; 2 edges in flight across the wave
    for (int e2 = 0; e2 < rem; e2 += 2) {
      int e = e2 + g;                       // e==rem (odd rem, g=1) -> w_e=0
      float w_e = __shfl(w, hsrc + (e & 15));
      int sc_e = __shfl(sc, hsrc + (e & 15));
      uint4 hv = *(const uint4*)(hbuf + (size_t)sc_e * 256 + c32 * 8);
      float f0, f1;
      bf2x(hv.x, f0, f1); acc[0] += w_e * f0; acc[1] += w_e * f1;
      bf2x(hv.y, f0, f1); acc[2] += w_e * f0; acc[3] += w_e * f1;
      bf2x(hv.z, f0, f1); acc[4] += w_e * f0; acc[5] += w_e * f1;
      bf2x(hv.w, f0, f1); acc[6] += w_e * f0; acc[7] += w_e * f1;
    }
  }
  // combine the two groups (lanes L and L+32 hold the same channels)
#pragma unroll
  for (int j = 0; j < 8; ++j) acc[j] += __shfl_xor(acc[j], 32);
  float inv = 1.f / (__shfl(s, hsrc) + SM_EPS);
  if (g == 0) {
    unsigned short o[8];
#pragma unroll
    for (int j = 0; j < 8; ++j) {
      float v = acc[j] * inv + bias[c32 * 8 + j];
      if (RELU) v = fmaxf(v, 0.f);
      o[j] = f2bf(v);
    }
    *(uint4*)(outb + (size_t)d * 256 + c32 * 8) = *(uint4*)o;
  }
}

// --- single-pass fused softmax+gather, H=1 C=32 (layer 3), fp32 out --------
__global__ __launch_bounds__(256) void gat_fused32(
    const unsigned short* __restrict__ hbuf, const float* __restrict__ asv,
    const float* __restrict__ adv, const int* __restrict__ rowptr,
    const int* __restrict__ colA, const float* __restrict__ bias,
    float* __restrict__ out, int N) {
  int wv = threadIdx.x >> 6;
  int d = blockIdx.x * 4 + wv;
  if (d >= N) return;
  int lane = threadIdx.x & 63;
  int q = lane >> 4, cp = lane & 15;  // edge slot / channel pair
  int r0 = rowptr[d], r1 = rowptr[d + 1];
  int len = r1 - r0;
  float ad = adv[d];
  float m = -1e30f, s = 0.f;
  float acc0 = 0.f, acc1 = 0.f;
  for (int base = 0; base < len; base += 64) {
    int rem = len - base; if (rem > 64) rem = 64;
    int sc = 0;
    float alpha = -1e30f;
    if (lane < rem) {
      sc = colA[r0 + base + lane];
      float a = asv[sc] + ad;
      alpha = (a > 0.f) ? a : NEG_SLOPE * a;
    }
    float mx = alpha;
#pragma unroll
    for (int off = 1; off < 64; off <<= 1) mx = fmaxf(mx, __shfl_xor(mx, off));
    float mn = fmaxf(m, mx);
    float scale = __expf(m - mn);
    float w = (lane < rem) ? __expf(alpha - mn) : 0.f;
    float cs = w;
#pragma unroll
    for (int off = 1; off < 64; off <<= 1) cs += __shfl_xor(cs, off);
    s = s * scale + cs;
    m = mn;
    acc0 *= scale; acc1 *= scale;
#pragma unroll 2
    for (int e2 = 0; e2 < rem; e2 += 4) {
      int e = e2 + q;                 // w==0 for e>=rem, so no guard needed
      float w_e = __shfl(w, e & 63);
      int sc_e = __shfl(sc, e & 63);
      unsigned int hv = *(const unsigned int*)(hbuf + (size_t)sc_e * 32 + cp * 2);
      float f0, f1;
      bf2x(hv, f0, f1);
      acc0 += w_e * f0; acc1 += w_e * f1;
    }
  }
  // reduce the 4 edge-slot groups (lane bits 4..5)
  acc0 += __shfl_xor(acc0, 16); acc0 += __shfl_xor(acc0, 32);
  acc1 += __shfl_xor(acc1, 16); acc1 += __shfl_xor(acc1, 32);
  if (q == 0) {
    float inv = 1.f / (s + SM_EPS);
    float2 o;
    o.x = acc0 * inv + bias[cp * 2 + 0];
    o.y = acc1 * inv + bias[cp * 2 + 1];
    *(float2*)(out + (size_t)d * 32 + cp * 2) = o;
  }
}

// ---------------------------------------------------------------------------
extern "C" void kernel_launch(void* const* d_in, const int* in_sizes, int n_in,
                              void* d_out, int out_size, void* d_ws, size_t ws_size,
                              hipStream_t stream) {
  const float* x   = (const float*)d_in[0];
  const int*   ei  = (const int*)d_in[1];
  const float* W1  = (const float*)d_in[2];
  const float* as1 = (const float*)d_in[3];
  const float* ad1 = (const float*)d_in[4];
  const float* b1  = (const float*)d_in[5];
  const float* W2  = (const float*)d_in[6];
  const float* as2 = (const float*)d_in[7];
  const float* ad2 = (const float*)d_in[8];
  const float* b2  = (const float*)d_in[9];
  const float* W3  = (const float*)d_in[10];
  const float* as3 = (const float*)d_in[11];
  const float* ad3 = (const float*)d_in[12];
  const float* b3  = (const float*)d_in[13];
  float* out = (float*)d_out;

  const int N = in_sizes[0] / 3;
  const int E = in_sizes[1] / 2;
  const int ET = E + N;  // with self loops

  char* ws = (char*)d_ws;
  size_t off = 0;
  auto alloc = [&](size_t bytes) -> void* {
    void* p = ws + off;
    off = (off + bytes + 255) & ~(size_t)255;
    return p;
  };
  unsigned short* bufA = (unsigned short*)alloc((size_t)N * 256 * 2);
  unsigned short* bufB = (unsigned short*)alloc((size_t)N * 256 * 2);
  unsigned short* w2t  = (unsigned short*)alloc((size_t)256 * 256 * 2);
  unsigned short* w3t  = (unsigned short*)alloc((size_t)32 * 256 * 2);
  float* asbuf  = (float*)alloc((size_t)N * 4 * 4);
  float* adbuf  = (float*)alloc((size_t)N * 4 * 4);
  int*   rowptr = (int*)alloc((size_t)(N + 1) * 4);
  int*   cursor = (int*)alloc((size_t)N * 4);
  int*   colA   = (int*)alloc((size_t)ET * 4);
  int*   bsum   = (int*)alloc(1024);
  int*   dflag  = (int*)alloc(256);
  (void)ws_size;

  const int nScanB = (N + SCAN_CHUNK - 1) / SCAN_CHUNK;

  // --- CSR build + weight prep ---
  detect_i64_kernel<<<1, 64, 0, stream>>>(ei, dflag);
  hipMemsetAsync(cursor, 0, (size_t)N * 4, stream);
  wt_bf16_kernel<<<(256 * 256 + 255) / 256, 256, 0, stream>>>(W2, w2t, 256, 256);
  wt_bf16_kernel<<<(256 * 32 + 255) / 256, 256, 0, stream>>>(W3, w3t, 256, 32);
  deg_kernel<<<(E + 255) / 256, 256, 0, stream>>>(ei, E, dflag, cursor);
  scan_phaseA<<<nScanB, 256, 0, stream>>>(cursor, bsum, N);
  scan_phaseB<<<1, 256, 0, stream>>>(bsum, nScanB);
  scan_phaseC<<<nScanB, 256, 0, stream>>>(cursor, bsum, rowptr, cursor, N);
  scatter_kernel<<<(ET + 255) / 256, 256, 0, stream>>>(ei, E, N, dflag, cursor, colA);

  const int nb4 = (N + 3) / 4;

  // --- layer 1: GEMM+attn -> bufA ; fused agg -> bufB (relu) ---
  gemm_k3_attn<<<N, 256, 0, stream>>>(x, W1, as1, ad1, bufA, asbuf, adbuf, N);
  gat_fused256<true><<<nb4, 256, 0, stream>>>(bufA, asbuf, adbuf, rowptr, colA, b1, bufB, N);

  // --- layer 2: MFMA GEMM+attn -> bufA ; fused agg -> bufB (relu) ---
  {
    dim3 grid(256 / 64, (N + 63) / 64);
    gemm_mfma<2, 2, 4><<<grid, 256, 0, stream>>>(bufB, w2t, bufA, as2, ad2, asbuf, adbuf,
                                                 N, 256, 256);
  }
  gat_fused256<true><<<nb4, 256, 0, stream>>>(bufA, asbuf, adbuf, rowptr, colA, b2, bufB, N);

  // --- layer 3: MFMA GEMM+attn -> bufA[0:N*32] ; fused agg -> out ---
  {
    dim3 grid(1, (N + 127) / 128);
    gemm_mfma<4, 1, 1><<<grid, 256, 0, stream>>>(bufB, w3t, bufA, as3, ad3, asbuf, adbuf,
                                                 N, 32, 256);
  }
  gat_fused32<<<nb4, 256, 0, stream>>>(bufA, asbuf, adbuf, rowptr, colA, b3, out, N);
}

// Round 8
// 526.747 us; speedup vs baseline: 2.5488x; 1.0285x over previous
//
#include <hip/hip_runtime.h>

// ---------------------------------------------------------------------------
// GAT 3-layer forward on MI355X. R8:
//  - layer-2 GEMM: full-width BN=256 tile (A read once), wave==head,
//    wave-local attn epilogue, 32 MFMA/wave per K-step
//  - gat_fused256: gather loop unrolled x2 (4 edges in flight per wave)
// ---------------------------------------------------------------------------

#define NEG_SLOPE 0.2f
#define SM_EPS 1e-16f
#define SCAN_CHUNK 2048

typedef __bf16 bf16x8 __attribute__((ext_vector_type(8)));
typedef float f32x4 __attribute__((ext_vector_type(4)));

__device__ __forceinline__ float bf2f(unsigned short u) {
  union { unsigned int i; float f; } v; v.i = ((unsigned int)u) << 16; return v.f;
}
__device__ __forceinline__ unsigned short f2bf(float f) {
  union { float f; unsigned int i; } v; v.f = f;
  unsigned int lsb = (v.i >> 16) & 1u;
  v.i += 0x7fffu + lsb;  // RNE
  return (unsigned short)(v.i >> 16);
}
__device__ __forceinline__ void bf2x(unsigned int u, float& f0, float& f1) {
  union { unsigned int i; float f; } a, b;
  a.i = u << 16; b.i = u & 0xffff0000u;
  f0 = a.f; f1 = b.f;
}

// --- edge dtype detection: int64 arrays read as int32 have zero odd words ---
__global__ void detect_i64_kernel(const int* __restrict__ ei, int* __restrict__ flag) {
  if (blockIdx.x == 0 && threadIdx.x == 0) {
    int orv = 0;
    for (int k = 0; k < 64; ++k) orv |= ei[2 * k + 1];
    *flag = (orv == 0) ? 1 : 0;
  }
}

__device__ __forceinline__ int load_idx(const int* __restrict__ ei, int logical, int is64) {
  return is64 ? ei[2 * logical] : ei[logical];
}

// --- CSR build -------------------------------------------------------------
__global__ void deg_kernel(const int* __restrict__ ei, int E, const int* __restrict__ flag,
                           int* __restrict__ deg) {
  int i = blockIdx.x * blockDim.x + threadIdx.x;
  if (i < E) {
    int d = load_idx(ei, E + i, *flag);
    atomicAdd(&deg[d], 1);
  }
}

__global__ __launch_bounds__(256) void scan_phaseA(const int* __restrict__ deg,
                                                   int* __restrict__ bsum, int N) {
  int t = threadIdx.x;
  int base = blockIdx.x * SCAN_CHUNK + t * 8;
  int s = 0;
#pragma unroll
  for (int i = 0; i < 8; ++i) {
    int idx = base + i;
    if (idx < N) s += deg[idx] + 1;
  }
  __shared__ int red[256];
  red[t] = s;
  __syncthreads();
  for (int d = 128; d > 0; d >>= 1) {
    if (t < d) red[t] += red[t + d];
    __syncthreads();
  }
  if (t == 0) bsum[blockIdx.x] = red[0];
}

__global__ void scan_phaseB(int* __restrict__ bsum, int nb) {
  __shared__ int sh[256];
  int t = threadIdx.x;
  int v = (t < nb) ? bsum[t] : 0;
  sh[t] = v;
  __syncthreads();
  for (int d = 1; d < 256; d <<= 1) {
    int u = (t >= d) ? sh[t - d] : 0;
    __syncthreads();
    sh[t] += u;
    __syncthreads();
  }
  if (t < nb) bsum[t] = sh[t] - v;  // exclusive
}

// phase C: local scan + offset -> rowptr AND cursor (scatter start positions)
__global__ __launch_bounds__(256) void scan_phaseC(const int* __restrict__ deg,
                                                   const int* __restrict__ bsum,
                                                   int* __restrict__ rowptr,
                                                   int* __restrict__ cursor, int N) {
  int t = threadIdx.x;
  int base = blockIdx.x * SCAN_CHUNK + t * 8;
  int v[8];
  int s = 0;
#pragma unroll
  for (int i = 0; i < 8; ++i) {
    int idx = base + i;
    v[i] = (idx < N) ? deg[idx] + 1 : 0;
    s += v[i];
  }
  __shared__ int sh[256];
  sh[t] = s;
  __syncthreads();
  for (int d = 1; d < 256; d <<= 1) {
    int u = (t >= d) ? sh[t - d] : 0;
    __syncthreads();
    sh[t] += u;
    __syncthreads();
  }
  int run = bsum[blockIdx.x] + sh[t] - s;
#pragma unroll
  for (int i = 0; i < 8; ++i) {
    int idx = base + i;
    if (idx < N) { rowptr[idx] = run; cursor[idx] = run; }
    run += v[i];
  }
  if (base < N && base + 8 >= N) rowptr[N] = run;
}

__global__ void scatter_kernel(const int* __restrict__ ei, int E, int N,
                               const int* __restrict__ flag,
                               int* __restrict__ cursor, int* __restrict__ colA) {
  int i = blockIdx.x * blockDim.x + threadIdx.x;
  int is64 = *flag;
  if (i < E) {
    int s = load_idx(ei, i, is64);
    int d = load_idx(ei, E + i, is64);
    int pos = atomicAdd(&cursor[d], 1);
    colA[pos] = s;
  } else if (i < E + N) {
    int n = i - E;
    int pos = atomicAdd(&cursor[n], 1);
    colA[pos] = n;
  }
}

// --- weight transpose + bf16 cast: Wt[n][k] = bf16(W[k][n]) ----------------
__global__ void wt_bf16_kernel(const float* __restrict__ W, unsigned short* __restrict__ Wt,
                               int K, int N) {
  int idx = blockIdx.x * 256 + threadIdx.x;
  if (idx < K * N) {
    int k = idx / N, n = idx - k * N;
    Wt[(size_t)n * K + k] = f2bf(W[idx]);
  }
}

// --- layer-1 GEMM + attn coefs: [N,3]@[3,256], wave = head ----------------
__global__ void gemm_k3_attn(const float* __restrict__ x, const float* __restrict__ W,
                             const float* __restrict__ a_src, const float* __restrict__ a_dst,
                             unsigned short* __restrict__ h, float* __restrict__ asv,
                             float* __restrict__ adv, int N) {
  int n = blockIdx.x;
  int t = threadIdx.x;
  float x0 = x[n * 3 + 0], x1 = x[n * 3 + 1], x2 = x[n * 3 + 2];
  float val = x0 * W[t] + x1 * W[256 + t] + x2 * W[512 + t];
  h[(size_t)n * 256 + t] = f2bf(val);
  float vs = val * a_src[t];
  float vd = val * a_dst[t];
#pragma unroll
  for (int off = 1; off < 64; off <<= 1) {
    vs += __shfl_xor(vs, off);
    vd += __shfl_xor(vd, off);
  }
  if ((t & 63) == 0) {
    asv[(size_t)n * 4 + (t >> 6)] = vs;
    adv[(size_t)n * 4 + (t >> 6)] = vd;
  }
}

// --- layer-2 GEMM: [M,256]@[256,256], BM=64 x BN=256 full width ------------
// 4 waves, wave w computes 64 rows x cols [w*64, w*64+64) == head w.
// Fused attn epilogue is wave-local (head w, no LDS combine).
__global__ __launch_bounds__(256) void gemm_mfma_w256(
    const unsigned short* __restrict__ A, const unsigned short* __restrict__ Bt,
    unsigned short* __restrict__ C, const float* __restrict__ a_src,
    const float* __restrict__ a_dst, float* __restrict__ asv, float* __restrict__ adv,
    int M, int K) {
  constexpr int BM = 64, BK = 64;
  __shared__ unsigned short As[BM][BK + 8];
  __shared__ unsigned short Bs[256][BK + 8];
  const int bm = blockIdx.x * BM;
  const int tid = threadIdx.x, wid = tid >> 6, lane = tid & 63;
  const int lrow = lane & 15, lkh = lane >> 4;
  const int srow = tid >> 3, scol = (tid & 7) * 8;  // 32 rows x 64 cols per pass
  f32x4 acc[4][4] = {};
  for (int k0 = 0; k0 < K; k0 += BK) {
#pragma unroll
    for (int r0 = 0; r0 < BM; r0 += 32) {
      int r = r0 + srow, gr = bm + r;
      uint4 v = make_uint4(0u, 0u, 0u, 0u);
      if (gr < M) v = *(const uint4*)(A + (size_t)gr * K + k0 + scol);
      *(uint4*)(&As[r][scol]) = v;
    }
#pragma unroll
    for (int r0 = 0; r0 < 256; r0 += 32) {
      int r = r0 + srow;
      uint4 v = *(const uint4*)(Bt + (size_t)r * K + k0 + scol);
      *(uint4*)(&Bs[r][scol]) = v;
    }
    __syncthreads();
#pragma unroll
    for (int kk = 0; kk < 2; ++kk) {
      bf16x8 a[4], b[4];
#pragma unroll
      for (int m = 0; m < 4; ++m)
        a[m] = *(const bf16x8*)(&As[m * 16 + lrow][kk * 32 + lkh * 8]);
#pragma unroll
      for (int n = 0; n < 4; ++n)
        b[n] = *(const bf16x8*)(&Bs[wid * 64 + n * 16 + lrow][kk * 32 + lkh * 8]);
#pragma unroll
      for (int m = 0; m < 4; ++m)
#pragma unroll
        for (int n = 0; n < 4; ++n)
          acc[m][n] = __builtin_amdgcn_mfma_f32_16x16x32_bf16(a[m], b[n], acc[m][n], 0, 0, 0);
    }
    __syncthreads();
  }
  // attn coef vectors for this wave's head (head == wid)
  float asl[4], adl[4];
#pragma unroll
  for (int n = 0; n < 4; ++n) {
    int c = wid * 64 + n * 16 + lrow;
    asl[n] = a_src[c];
    adl[n] = a_dst[c];
  }
  // C write (col = lane&15, row = (lane>>4)*4 + q) + wave-local attn reduce
#pragma unroll
  for (int m = 0; m < 4; ++m) {
#pragma unroll
    for (int q = 0; q < 4; ++q) {
      int grow = bm + m * 16 + lkh * 4 + q;
      float ps = 0.f, pd = 0.f;
#pragma unroll
      for (int n = 0; n < 4; ++n) {
        ps += acc[m][n][q] * asl[n];
        pd += acc[m][n][q] * adl[n];
      }
      if (grow < M) {
#pragma unroll
        for (int n = 0; n < 4; ++n)
          C[(size_t)grow * 256 + wid * 64 + n * 16 + lrow] = f2bf(acc[m][n][q]);
      }
#pragma unroll
      for (int off = 1; off < 16; off <<= 1) {
        ps += __shfl_xor(ps, off);
        pd += __shfl_xor(pd, off);
      }
      if (lrow == 0 && grow < M) {
        asv[(size_t)grow * 4 + wid] = ps;
        adv[(size_t)grow * 4 + wid] = pd;
      }
    }
  }
}

// --- layer-3 GEMM: BM=128 x BN=32 (full width), fused attn (H=1) -----------
template <int WR, int WC, int ATT_H>
__global__ __launch_bounds__(64 * WR * WC) void gemm_mfma(
    const unsigned short* __restrict__ A, const unsigned short* __restrict__ Bt,
    unsigned short* __restrict__ C, const float* __restrict__ a_src,
    const float* __restrict__ a_dst, float* __restrict__ asv, float* __restrict__ adv,
    int M, int N, int K) {
  constexpr int BM = 32 * WR, BN = 32 * WC, BK = 64;
  constexpr int T = 64 * WR * WC;
  constexpr int RPP = T / 8;
  __shared__ unsigned short As[BM][BK + 8];
  __shared__ unsigned short Bs[BN][BK + 8];
  const int bm = blockIdx.y * BM, bn = blockIdx.x * BN;
  const int tid = threadIdx.x, wid = tid >> 6, lane = tid & 63;
  const int wr = wid / WC, wc = wid % WC;
  const int lrow = lane & 15, lkh = lane >> 4;
  const int srow = tid >> 3, scol = (tid & 7) * 8;
  f32x4 acc[2][2] = {};
  for (int k0 = 0; k0 < K; k0 += BK) {
#pragma unroll
    for (int r0 = 0; r0 < BM; r0 += RPP) {
      int r = r0 + srow, gr = bm + r;
      uint4 v = make_uint4(0u, 0u, 0u, 0u);
      if (gr < M) v = *(const uint4*)(A + (size_t)gr * K + k0 + scol);
      *(uint4*)(&As[r][scol]) = v;
    }
#pragma unroll
    for (int r0 = 0; r0 < BN; r0 += RPP) {
      int r = r0 + srow;
      if (r < BN) {
        int gn = bn + r;
        uint4 v = *(const uint4*)(Bt + (size_t)gn * K + k0 + scol);
        *(uint4*)(&Bs[r][scol]) = v;
      }
    }
    __syncthreads();
#pragma unroll
    for (int kk = 0; kk < 2; ++kk) {
      bf16x8 a0 = *(const bf16x8*)(&As[wr * 32 + lrow][kk * 32 + lkh * 8]);
      bf16x8 a1 = *(const bf16x8*)(&As[wr * 32 + 16 + lrow][kk * 32 + lkh * 8]);
      bf16x8 b0 = *(const bf16x8*)(&Bs[wc * 32 + lrow][kk * 32 + lkh * 8]);
      bf16x8 b1 = *(const bf16x8*)(&Bs[wc * 32 + 16 + lrow][kk * 32 + lkh * 8]);
      acc[0][0] = __builtin_amdgcn_mfma_f32_16x16x32_bf16(a0, b0, acc[0][0], 0, 0, 0);
      acc[0][1] = __builtin_amdgcn_mfma_f32_16x16x32_bf16(a0, b1, acc[0][1], 0, 0, 0);
      acc[1][0] = __builtin_amdgcn_mfma_f32_16x16x32_bf16(a1, b0, acc[1][0], 0, 0, 0);
      acc[1][1] = __builtin_amdgcn_mfma_f32_16x16x32_bf16(a1, b1, acc[1][1], 0, 0, 0);
    }
    __syncthreads();
  }
#pragma unroll
  for (int m = 0; m < 2; ++m) {
#pragma unroll
    for (int q = 0; q < 4; ++q) {
      int grow = bm + wr * 32 + m * 16 + lkh * 4 + q;
      if (grow < M) {
#pragma unroll
        for (int n = 0; n < 2; ++n) {
          int gcol = bn + wc * 32 + n * 16 + lrow;
          C[(size_t)grow * N + gcol] = f2bf(acc[m][n][q]);
        }
      }
    }
  }
  const int hh = (ATT_H == 1) ? 0 : (int)blockIdx.x;
  float asl[2], adl[2];
#pragma unroll
  for (int n = 0; n < 2; ++n) {
    int c = wc * 32 + n * 16 + lrow;
    asl[n] = a_src[hh * BN + c];
    adl[n] = a_dst[hh * BN + c];
  }
#pragma unroll
  for (int m = 0; m < 2; ++m) {
#pragma unroll
    for (int q = 0; q < 4; ++q) {
      float ps = acc[m][0][q] * asl[0] + acc[m][1][q] * asl[1];
      float pd = acc[m][0][q] * adl[0] + acc[m][1][q] * adl[1];
#pragma unroll
      for (int off = 1; off < 16; off <<= 1) {
        ps += __shfl_xor(ps, off);
        pd += __shfl_xor(pd, off);
      }
      int grow = bm + wr * 32 + m * 16 + lkh * 4 + q;
      if (lrow == 0 && grow < M) {
        asv[(size_t)grow * ATT_H + hh] = ps;
        adv[(size_t)grow * ATT_H + hh] = pd;
      }
    }
  }
}

// --- single-pass fused softmax+gather, H=4 C=64: wave per dst --------------
// stats lanes: lane = h4*16 + el. gather: two 32-lane groups x uint4,
// bulk loop unrolled x2 (4 edges in flight per wave).
template <bool RELU>
__global__ __launch_bounds__(256) void gat_fused256(
    const unsigned short* __restrict__ hbuf, const float* __restrict__ asv,
    const float* __restrict__ adv, const int* __restrict__ rowptr,
    const int* __restrict__ colA, const float* __restrict__ bias,
    unsigned short* __restrict__ outb, int N) {
  int wv = threadIdx.x >> 6;
  int d = blockIdx.x * 4 + wv;
  if (d >= N) return;
  int lane = threadIdx.x & 63;
  int h4 = lane >> 4, el = lane & 15;       // stats role
  int g = lane >> 5, c32 = lane & 31;       // gather role
  int hh = c32 >> 3;
  int r0 = rowptr[d], r1 = rowptr[d + 1];
  int len = r1 - r0;
  float ad = adv[(size_t)d * 4 + h4];
  float m = -1e30f, s = 0.f;
  float acc[8] = {};
  const int hsrc = hh * 16;
  for (int base = 0; base < len; base += 16) {
    int rem = len - base; if (rem > 16) rem = 16;
    int sc = 0;
    float alpha = -1e30f;
    if (el < rem) {
      sc = colA[r0 + base + el];
      float a = asv[(size_t)sc * 4 + h4] + ad;
      alpha = (a > 0.f) ? a : NEG_SLOPE * a;
    }
    float mx = alpha;
#pragma unroll
    for (int off = 1; off < 16; off <<= 1) mx = fmaxf(mx, __shfl_xor(mx, off));
    float mn = fmaxf(m, mx);
    float scale = __expf(m - mn);
    float w = (el < rem) ? __expf(alpha - mn) : 0.f;
    float cs = w;
#pragma unroll
    for (int off = 1; off < 16; off <<= 1) cs += __shfl_xor(cs, off);
    s = s * scale + cs;
    m = mn;
    float scale_h = __shfl(scale, hsrc);
#pragma unroll
    for (int j = 0; j < 8; ++j) acc[j] *= scale_h;
    // bulk: 2 edges per group in flight (4 per wave)
    int e2 = 0;
    for (; e2 + 4 <= rem; e2 += 4) {
      int ea = e2 + g, eb = e2 + 2 + g;
      float wa = __shfl(w, hsrc + ea);
      int sa = __shfl(sc, hsrc + ea);
      float wb = __shfl(w, hsrc + eb);
      int sb = __shfl(sc, hsrc + eb);
      uint4 hva = *(const uint4*)(hbuf + (size_t)sa * 256 + c32 * 8);
      uint4 hvb = *(const uint4*)(hbuf + (size_t)sb * 256 + c32 * 8);
      float f0, f1;
      bf2x(hva.x, f0, f1); acc[0] += wa * f0; acc[1] += wa * f1;
      bf2x(hva.y, f0, f1); acc[2] += wa * f0; acc[3] += wa * f1;
      bf2x(hva.z, f0, f1); acc[4] += wa * f0; acc[5] += wa * f1;
      bf2x(hva.w, f0, f1); acc[6] += wa * f0; acc[7] += wa * f1;
      bf2x(hvb.x, f0, f1); acc[0] += wb * f0; acc[1] += wb * f1;
      bf2x(hvb.y, f0, f1); acc[2] += wb * f0; acc[3] += wb * f1;
      bf2x(hvb.z, f0, f1); acc[4] += wb * f0; acc[5] += wb * f1;
      bf2x(hvb.w, f0, f1); acc[6] += wb * f0; acc[7] += wb * f1;
    }
    for (; e2 < rem; e2 += 2) {
      int e = e2 + g;                        // e may exceed rem-1 -> w_e = 0
      float w_e = __shfl(w, hsrc + (e & 15));
      int sc_e = __shfl(sc, hsrc + (e & 15));
      uint4 hv = *(const uint4*)(hbuf + (size_t)sc_e * 256 + c32 * 8);
      float f0, f1;
      bf2x(hv.x, f0, f1); acc[0] += w_e * f0; acc[1] += w_e * f1;
      bf2x(hv.y, f0, f1); acc[2] += w_e * f0; acc[3] += w_e * f1;
      bf2x(hv.z, f0, f1); acc[4] += w_e * f0; acc[5] += w_e * f1;
      bf2x(hv.w, f0, f1); acc[6] += w_e * f0; acc[7] += w_e * f1;
    }
  }
#pragma unroll
  for (int j = 0; j < 8; ++j) acc[j] += __shfl_xor(acc[j], 32);
  float inv = 1.f / (__shfl(s, hsrc) + SM_EPS);
  if (g == 0) {
    unsigned short o[8];
#pragma unroll
    for (int j = 0; j < 8; ++j) {
      float v = acc[j] * inv + bias[c32 * 8 + j];
      if (RELU) v = fmaxf(v, 0.f);
      o[j] = f2bf(v);
    }
    *(uint4*)(outb + (size_t)d * 256 + c32 * 8) = *(uint4*)o;
  }
}

// --- single-pass fused softmax+gather, H=1 C=32 (layer 3), fp32 out --------
__global__ __launch_bounds__(256) void gat_fused32(
    const unsigned short* __restrict__ hbuf, const float* __restrict__ asv,
    const float* __restrict__ adv, const int* __restrict__ rowptr,
    const int* __restrict__ colA, const float* __restrict__ bias,
    float* __restrict__ out, int N) {
  int wv = threadIdx.x >> 6;
  int d = blockIdx.x * 4 + wv;
  if (d >= N) return;
  int lane = threadIdx.x & 63;
  int q = lane >> 4, cp = lane & 15;  // edge slot / channel pair
  int r0 = rowptr[d], r1 = rowptr[d + 1];
  int len = r1 - r0;
  float ad = adv[d];
  float m = -1e30f, s = 0.f;
  float acc0 = 0.f, acc1 = 0.f;
  for (int base = 0; base < len; base += 64) {
    int rem = len - base; if (rem > 64) rem = 64;
    int sc = 0;
    float alpha = -1e30f;
    if (lane < rem) {
      sc = colA[r0 + base + lane];
      float a = asv[sc] + ad;
      alpha = (a > 0.f) ? a : NEG_SLOPE * a;
    }
    float mx = alpha;
#pragma unroll
    for (int off = 1; off < 64; off <<= 1) mx = fmaxf(mx, __shfl_xor(mx, off));
    float mn = fmaxf(m, mx);
    float scale = __expf(m - mn);
    float w = (lane < rem) ? __expf(alpha - mn) : 0.f;
    float cs = w;
#pragma unroll
    for (int off = 1; off < 64; off <<= 1) cs += __shfl_xor(cs, off);
    s = s * scale + cs;
    m = mn;
    acc0 *= scale; acc1 *= scale;
#pragma unroll 2
    for (int e2 = 0; e2 < rem; e2 += 4) {
      int e = e2 + q;                 // w==0 for e>=rem, so no guard needed
      float w_e = __shfl(w, e & 63);
      int sc_e = __shfl(sc, e & 63);
      unsigned int hv = *(const unsigned int*)(hbuf + (size_t)sc_e * 32 + cp * 2);
      float f0, f1;
      bf2x(hv, f0, f1);
      acc0 += w_e * f0; acc1 += w_e * f1;
    }
  }
  acc0 += __shfl_xor(acc0, 16); acc0 += __shfl_xor(acc0, 32);
  acc1 += __shfl_xor(acc1, 16); acc1 += __shfl_xor(acc1, 32);
  if (q == 0) {
    float inv = 1.f / (s + SM_EPS);
    float2 o;
    o.x = acc0 * inv + bias[cp * 2 + 0];
    o.y = acc1 * inv + bias[cp * 2 + 1];
    *(float2*)(out + (size_t)d * 32 + cp * 2) = o;
  }
}

// ---------------------------------------------------------------------------
extern "C" void kernel_launch(void* const* d_in, const int* in_sizes, int n_in,
                              void* d_out, int out_size, void* d_ws, size_t ws_size,
                              hipStream_t stream) {
  const float* x   = (const float*)d_in[0];
  const int*   ei  = (const int*)d_in[1];
  const float* W1  = (const float*)d_in[2];
  const float* as1 = (const float*)d_in[3];
  const float* ad1 = (const float*)d_in[4];
  const float* b1  = (const float*)d_in[5];
  const float* W2  = (const float*)d_in[6];
  const float* as2 = (const float*)d_in[7];
  const float* ad2 = (const float*)d_in[8];
  const float* b2  = (const float*)d_in[9];
  const float* W3  = (const float*)d_in[10];
  const float* as3 = (const float*)d_in[11];
  const float* ad3 = (const float*)d_in[12];
  const float* b3  = (const float*)d_in[13];
  float* out = (float*)d_out;

  const int N = in_sizes[0] / 3;
  const int E = in_sizes[1] / 2;
  const int ET = E + N;  // with self loops

  char* ws = (char*)d_ws;
  size_t off = 0;
  auto alloc = [&](size_t bytes) -> void* {
    void* p = ws + off;
    off = (off + bytes + 255) & ~(size_t)255;
    return p;
  };
  unsigned short* bufA = (unsigned short*)alloc((size_t)N * 256 * 2);
  unsigned short* bufB = (unsigned short*)alloc((size_t)N * 256 * 2);
  unsigned short* w2t  = (unsigned short*)alloc((size_t)256 * 256 * 2);
  unsigned short* w3t  = (unsigned short*)alloc((size_t)32 * 256 * 2);
  float* asbuf  = (float*)alloc((size_t)N * 4 * 4);
  float* adbuf  = (float*)alloc((size_t)N * 4 * 4);
  int*   rowptr = (int*)alloc((size_t)(N + 1) * 4);
  int*   cursor = (int*)alloc((size_t)N * 4);
  int*   colA   = (int*)alloc((size_t)ET * 4);
  int*   bsum   = (int*)alloc(1024);
  int*   dflag  = (int*)alloc(256);
  (void)ws_size;

  const int nScanB = (N + SCAN_CHUNK - 1) / SCAN_CHUNK;

  // --- CSR build + weight prep ---
  detect_i64_kernel<<<1, 64, 0, stream>>>(ei, dflag);
  hipMemsetAsync(cursor, 0, (size_t)N * 4, stream);
  wt_bf16_kernel<<<(256 * 256 + 255) / 256, 256, 0, stream>>>(W2, w2t, 256, 256);
  wt_bf16_kernel<<<(256 * 32 + 255) / 256, 256, 0, stream>>>(W3, w3t, 256, 32);
  deg_kernel<<<(E + 255) / 256, 256, 0, stream>>>(ei, E, dflag, cursor);
  scan_phaseA<<<nScanB, 256, 0, stream>>>(cursor, bsum, N);
  scan_phaseB<<<1, 256, 0, stream>>>(bsum, nScanB);
  scan_phaseC<<<nScanB, 256, 0, stream>>>(cursor, bsum, rowptr, cursor, N);
  scatter_kernel<<<(ET + 255) / 256, 256, 0, stream>>>(ei, E, N, dflag, cursor, colA);

  const int nb4 = (N + 3) / 4;

  // --- layer 1: GEMM+attn -> bufA ; fused agg -> bufB (relu) ---
  gemm_k3_attn<<<N, 256, 0, stream>>>(x, W1, as1, ad1, bufA, asbuf, adbuf, N);
  gat_fused256<true><<<nb4, 256, 0, stream>>>(bufA, asbuf, adbuf, rowptr, colA, b1, bufB, N);

  // --- layer 2: full-width MFMA GEMM+attn -> bufA ; fused agg -> bufB ---
  gemm_mfma_w256<<<(N + 63) / 64, 256, 0, stream>>>(bufB, w2t, bufA, as2, ad2,
                                                    asbuf, adbuf, N, 256);
  gat_fused256<true><<<nb4, 256, 0, stream>>>(bufA, asbuf, adbuf, rowptr, colA, b2, bufB, N);

  // --- layer 3: MFMA GEMM+attn -> bufA[0:N*32] ; fused agg -> out ---
  {
    dim3 grid(1, (N + 127) / 128);
    gemm_mfma<4, 1, 1><<<grid, 256, 0, stream>>>(bufB, w3t, bufA, as3, ad3, asbuf, adbuf,
                                                 N, 32, 256);
  }
  gat_fused32<<<nb4, 256, 0, stream>>>(bufA, asbuf, adbuf, rowptr, colA, b3, out, N);
}

// Round 9
// 501.958 us; speedup vs baseline: 2.6746x; 1.0494x over previous
//
#include <hip/hip_runtime.h>

// ---------------------------------------------------------------------------
// GAT 3-layer forward on MI355X. R9: tail optimization.
//  - gat_fused32: 8 edges in flight (8 slots x 8 lanes x uint2)
//  - gemm_k3_attn: wave-per-row
//  - non-temporal stores for agg outputs (keep h rows in L2 for the gather)
//  - merged weight-transpose launch
// ---------------------------------------------------------------------------

#define NEG_SLOPE 0.2f
#define SM_EPS 1e-16f
#define SCAN_CHUNK 2048

typedef __bf16 bf16x8 __attribute__((ext_vector_type(8)));
typedef float f32x4 __attribute__((ext_vector_type(4)));
typedef unsigned int u32x4 __attribute__((ext_vector_type(4)));
typedef float f32x4v __attribute__((ext_vector_type(4)));

__device__ __forceinline__ float bf2f(unsigned short u) {
  union { unsigned int i; float f; } v; v.i = ((unsigned int)u) << 16; return v.f;
}
__device__ __forceinline__ unsigned short f2bf(float f) {
  union { float f; unsigned int i; } v; v.f = f;
  unsigned int lsb = (v.i >> 16) & 1u;
  v.i += 0x7fffu + lsb;  // RNE
  return (unsigned short)(v.i >> 16);
}
__device__ __forceinline__ void bf2x(unsigned int u, float& f0, float& f1) {
  union { unsigned int i; float f; } a, b;
  a.i = u << 16; b.i = u & 0xffff0000u;
  f0 = a.f; f1 = b.f;
}

// --- edge dtype detection: int64 arrays read as int32 have zero odd words ---
__global__ void detect_i64_kernel(const int* __restrict__ ei, int* __restrict__ flag) {
  if (blockIdx.x == 0 && threadIdx.x == 0) {
    int orv = 0;
    for (int k = 0; k < 64; ++k) orv |= ei[2 * k + 1];
    *flag = (orv == 0) ? 1 : 0;
  }
}

__device__ __forceinline__ int load_idx(const int* __restrict__ ei, int logical, int is64) {
  return is64 ? ei[2 * logical] : ei[logical];
}

// --- CSR build -------------------------------------------------------------
__global__ void deg_kernel(const int* __restrict__ ei, int E, const int* __restrict__ flag,
                           int* __restrict__ deg) {
  int i = blockIdx.x * blockDim.x + threadIdx.x;
  if (i < E) {
    int d = load_idx(ei, E + i, *flag);
    atomicAdd(&deg[d], 1);
  }
}

__global__ __launch_bounds__(256) void scan_phaseA(const int* __restrict__ deg,
                                                   int* __restrict__ bsum, int N) {
  int t = threadIdx.x;
  int base = blockIdx.x * SCAN_CHUNK + t * 8;
  int s = 0;
#pragma unroll
  for (int i = 0; i < 8; ++i) {
    int idx = base + i;
    if (idx < N) s += deg[idx] + 1;
  }
  __shared__ int red[256];
  red[t] = s;
  __syncthreads();
  for (int d = 128; d > 0; d >>= 1) {
    if (t < d) red[t] += red[t + d];
    __syncthreads();
  }
  if (t == 0) bsum[blockIdx.x] = red[0];
}

__global__ void scan_phaseB(int* __restrict__ bsum, int nb) {
  __shared__ int sh[256];
  int t = threadIdx.x;
  int v = (t < nb) ? bsum[t] : 0;
  sh[t] = v;
  __syncthreads();
  for (int d = 1; d < 256; d <<= 1) {
    int u = (t >= d) ? sh[t - d] : 0;
    __syncthreads();
    sh[t] += u;
    __syncthreads();
  }
  if (t < nb) bsum[t] = sh[t] - v;  // exclusive
}

// phase C: local scan + offset -> rowptr AND cursor (scatter start positions)
__global__ __launch_bounds__(256) void scan_phaseC(const int* __restrict__ deg,
                                                   const int* __restrict__ bsum,
                                                   int* __restrict__ rowptr,
                                                   int* __restrict__ cursor, int N) {
  int t = threadIdx.x;
  int base = blockIdx.x * SCAN_CHUNK + t * 8;
  int v[8];
  int s = 0;
#pragma unroll
  for (int i = 0; i < 8; ++i) {
    int idx = base + i;
    v[i] = (idx < N) ? deg[idx] + 1 : 0;
    s += v[i];
  }
  __shared__ int sh[256];
  sh[t] = s;
  __syncthreads();
  for (int d = 1; d < 256; d <<= 1) {
    int u = (t >= d) ? sh[t - d] : 0;
    __syncthreads();
    sh[t] += u;
    __syncthreads();
  }
  int run = bsum[blockIdx.x] + sh[t] - s;
#pragma unroll
  for (int i = 0; i < 8; ++i) {
    int idx = base + i;
    if (idx < N) { rowptr[idx] = run; cursor[idx] = run; }
    run += v[i];
  }
  if (base < N && base + 8 >= N) rowptr[N] = run;
}

__global__ void scatter_kernel(const int* __restrict__ ei, int E, int N,
                               const int* __restrict__ flag,
                               int* __restrict__ cursor, int* __restrict__ colA) {
  int i = blockIdx.x * blockDim.x + threadIdx.x;
  int is64 = *flag;
  if (i < E) {
    int s = load_idx(ei, i, is64);
    int d = load_idx(ei, E + i, is64);
    int pos = atomicAdd(&cursor[d], 1);
    colA[pos] = s;
  } else if (i < E + N) {
    int n = i - E;
    int pos = atomicAdd(&cursor[n], 1);
    colA[pos] = n;
  }
}

// --- merged weight transpose + bf16 cast for W2 (256x256) and W3 (256x32) --
__global__ void wt_bf16_both(const float* __restrict__ W2, const float* __restrict__ W3,
                             unsigned short* __restrict__ w2t, unsigned short* __restrict__ w3t) {
  int idx = blockIdx.x * 256 + threadIdx.x;
  if (idx < 256 * 256) {
    int k = idx >> 8, n = idx & 255;
    w2t[(size_t)n * 256 + k] = f2bf(W2[idx]);
  } else {
    int j = idx - 256 * 256;
    if (j < 256 * 32) {
      int k = j >> 5, n = j & 31;
      w3t[(size_t)n * 256 + k] = f2bf(W3[j]);
    }
  }
}

// --- layer-1 GEMM + attn coefs: [N,3]@[3,256], wave per row ----------------
__global__ __launch_bounds__(256) void gemm_k3_attn(
    const float* __restrict__ x, const float* __restrict__ W,
    const float* __restrict__ a_src, const float* __restrict__ a_dst,
    unsigned short* __restrict__ h, float* __restrict__ asv,
    float* __restrict__ adv, int N) {
  int wv = threadIdx.x >> 6, lane = threadIdx.x & 63;
  int n = blockIdx.x * 4 + wv;
  if (n >= N) return;
  float x0 = x[n * 3 + 0], x1 = x[n * 3 + 1], x2 = x[n * 3 + 2];
  float vs = 0.f, vd = 0.f;
  unsigned short o[4];
#pragma unroll
  for (int j = 0; j < 4; ++j) {
    int c = lane * 4 + j;
    float val = x0 * W[c] + x1 * W[256 + c] + x2 * W[512 + c];
    o[j] = f2bf(val);
    vs += val * a_src[c];
    vd += val * a_dst[c];
  }
  *(uint2*)(h + (size_t)n * 256 + lane * 4) = *(uint2*)o;
#pragma unroll
  for (int off = 1; off < 16; off <<= 1) {
    vs += __shfl_xor(vs, off);
    vd += __shfl_xor(vd, off);
  }
  if ((lane & 15) == 0) {
    asv[(size_t)n * 4 + (lane >> 4)] = vs;
    adv[(size_t)n * 4 + (lane >> 4)] = vd;
  }
}

// --- layer-2 GEMM: [M,256]@[256,256], BM=64 x BN=256 full width ------------
__global__ __launch_bounds__(256) void gemm_mfma_w256(
    const unsigned short* __restrict__ A, const unsigned short* __restrict__ Bt,
    unsigned short* __restrict__ C, const float* __restrict__ a_src,
    const float* __restrict__ a_dst, float* __restrict__ asv, float* __restrict__ adv,
    int M, int K) {
  constexpr int BM = 64, BK = 64;
  __shared__ unsigned short As[BM][BK + 8];
  __shared__ unsigned short Bs[256][BK + 8];
  const int bm = blockIdx.x * BM;
  const int tid = threadIdx.x, wid = tid >> 6, lane = tid & 63;
  const int lrow = lane & 15, lkh = lane >> 4;
  const int srow = tid >> 3, scol = (tid & 7) * 8;  // 32 rows x 64 cols per pass
  f32x4 acc[4][4] = {};
  for (int k0 = 0; k0 < K; k0 += BK) {
#pragma unroll
    for (int r0 = 0; r0 < BM; r0 += 32) {
      int r = r0 + srow, gr = bm + r;
      uint4 v = make_uint4(0u, 0u, 0u, 0u);
      if (gr < M) v = *(const uint4*)(A + (size_t)gr * K + k0 + scol);
      *(uint4*)(&As[r][scol]) = v;
    }
#pragma unroll
    for (int r0 = 0; r0 < 256; r0 += 32) {
      int r = r0 + srow;
      uint4 v = *(const uint4*)(Bt + (size_t)r * K + k0 + scol);
      *(uint4*)(&Bs[r][scol]) = v;
    }
    __syncthreads();
#pragma unroll
    for (int kk = 0; kk < 2; ++kk) {
      bf16x8 a[4], b[4];
#pragma unroll
      for (int m = 0; m < 4; ++m)
        a[m] = *(const bf16x8*)(&As[m * 16 + lrow][kk * 32 + lkh * 8]);
#pragma unroll
      for (int n = 0; n < 4; ++n)
        b[n] = *(const bf16x8*)(&Bs[wid * 64 + n * 16 + lrow][kk * 32 + lkh * 8]);
#pragma unroll
      for (int m = 0; m < 4; ++m)
#pragma unroll
        for (int n = 0; n < 4; ++n)
          acc[m][n] = __builtin_amdgcn_mfma_f32_16x16x32_bf16(a[m], b[n], acc[m][n], 0, 0, 0);
    }
    __syncthreads();
  }
  float asl[4], adl[4];
#pragma unroll
  for (int n = 0; n < 4; ++n) {
    int c = wid * 64 + n * 16 + lrow;
    asl[n] = a_src[c];
    adl[n] = a_dst[c];
  }
#pragma unroll
  for (int m = 0; m < 4; ++m) {
#pragma unroll
    for (int q = 0; q < 4; ++q) {
      int grow = bm + m * 16 + lkh * 4 + q;
      float ps = 0.f, pd = 0.f;
#pragma unroll
      for (int n = 0; n < 4; ++n) {
        ps += acc[m][n][q] * asl[n];
        pd += acc[m][n][q] * adl[n];
      }
      if (grow < M) {
#pragma unroll
        for (int n = 0; n < 4; ++n)
          C[(size_t)grow * 256 + wid * 64 + n * 16 + lrow] = f2bf(acc[m][n][q]);
      }
#pragma unroll
      for (int off = 1; off < 16; off <<= 1) {
        ps += __shfl_xor(ps, off);
        pd += __shfl_xor(pd, off);
      }
      if (lrow == 0 && grow < M) {
        asv[(size_t)grow * 4 + wid] = ps;
        adv[(size_t)grow * 4 + wid] = pd;
      }
    }
  }
}

// --- layer-3 GEMM: BM=128 x BN=32 (full width), fused attn (H=1) -----------
template <int WR, int WC, int ATT_H>
__global__ __launch_bounds__(64 * WR * WC) void gemm_mfma(
    const unsigned short* __restrict__ A, const unsigned short* __restrict__ Bt,
    unsigned short* __restrict__ C, const float* __restrict__ a_src,
    const float* __restrict__ a_dst, float* __restrict__ asv, float* __restrict__ adv,
    int M, int N, int K) {
  constexpr int BM = 32 * WR, BN = 32 * WC, BK = 64;
  constexpr int T = 64 * WR * WC;
  constexpr int RPP = T / 8;
  __shared__ unsigned short As[BM][BK + 8];
  __shared__ unsigned short Bs[BN][BK + 8];
  const int bm = blockIdx.y * BM, bn = blockIdx.x * BN;
  const int tid = threadIdx.x, wid = tid >> 6, lane = tid & 63;
  const int wr = wid / WC, wc = wid % WC;
  const int lrow = lane & 15, lkh = lane >> 4;
  const int srow = tid >> 3, scol = (tid & 7) * 8;
  f32x4 acc[2][2] = {};
  for (int k0 = 0; k0 < K; k0 += BK) {
#pragma unroll
    for (int r0 = 0; r0 < BM; r0 += RPP) {
      int r = r0 + srow, gr = bm + r;
      uint4 v = make_uint4(0u, 0u, 0u, 0u);
      if (gr < M) v = *(const uint4*)(A + (size_t)gr * K + k0 + scol);
      *(uint4*)(&As[r][scol]) = v;
    }
#pragma unroll
    for (int r0 = 0; r0 < BN; r0 += RPP) {
      int r = r0 + srow;
      if (r < BN) {
        int gn = bn + r;
        uint4 v = *(const uint4*)(Bt + (size_t)gn * K + k0 + scol);
        *(uint4*)(&Bs[r][scol]) = v;
      }
    }
    __syncthreads();
#pragma unroll
    for (int kk = 0; kk < 2; ++kk) {
      bf16x8 a0 = *(const bf16x8*)(&As[wr * 32 + lrow][kk * 32 + lkh * 8]);
      bf16x8 a1 = *(const bf16x8*)(&As[wr * 32 + 16 + lrow][kk * 32 + lkh * 8]);
      bf16x8 b0 = *(const bf16x8*)(&Bs[wc * 32 + lrow][kk * 32 + lkh * 8]);
      bf16x8 b1 = *(const bf16x8*)(&Bs[wc * 32 + 16 + lrow][kk * 32 + lkh * 8]);
      acc[0][0] = __builtin_amdgcn_mfma_f32_16x16x32_bf16(a0, b0, acc[0][0], 0, 0, 0);
      acc[0][1] = __builtin_amdgcn_mfma_f32_16x16x32_bf16(a0, b1, acc[0][1], 0, 0, 0);
      acc[1][0] = __builtin_amdgcn_mfma_f32_16x16x32_bf16(a1, b0, acc[1][0], 0, 0, 0);
      acc[1][1] = __builtin_amdgcn_mfma_f32_16x16x32_bf16(a1, b1, acc[1][1], 0, 0, 0);
    }
    __syncthreads();
  }
#pragma unroll
  for (int m = 0; m < 2; ++m) {
#pragma unroll
    for (int q = 0; q < 4; ++q) {
      int grow = bm + wr * 32 + m * 16 + lkh * 4 + q;
      if (grow < M) {
#pragma unroll
        for (int n = 0; n < 2; ++n) {
          int gcol = bn + wc * 32 + n * 16 + lrow;
          C[(size_t)grow * N + gcol] = f2bf(acc[m][n][q]);
        }
      }
    }
  }
  const int hh = (ATT_H == 1) ? 0 : (int)blockIdx.x;
  float asl[2], adl[2];
#pragma unroll
  for (int n = 0; n < 2; ++n) {
    int c = wc * 32 + n * 16 + lrow;
    asl[n] = a_src[hh * BN + c];
    adl[n] = a_dst[hh * BN + c];
  }
#pragma unroll
  for (int m = 0; m < 2; ++m) {
#pragma unroll
    for (int q = 0; q < 4; ++q) {
      float ps = acc[m][0][q] * asl[0] + acc[m][1][q] * asl[1];
      float pd = acc[m][0][q] * adl[0] + acc[m][1][q] * adl[1];
#pragma unroll
      for (int off = 1; off < 16; off <<= 1) {
        ps += __shfl_xor(ps, off);
        pd += __shfl_xor(pd, off);
      }
      int grow = bm + wr * 32 + m * 16 + lkh * 4 + q;
      if (lrow == 0 && grow < M) {
        asv[(size_t)grow * ATT_H + hh] = ps;
        adv[(size_t)grow * ATT_H + hh] = pd;
      }
    }
  }
}

// --- single-pass fused softmax+gather, H=4 C=64: wave per dst --------------
template <bool RELU>
__global__ __launch_bounds__(256) void gat_fused256(
    const unsigned short* __restrict__ hbuf, const float* __restrict__ asv,
    const float* __restrict__ adv, const int* __restrict__ rowptr,
    const int* __restrict__ colA, const float* __restrict__ bias,
    unsigned short* __restrict__ outb, int N) {
  int wv = threadIdx.x >> 6;
  int d = blockIdx.x * 4 + wv;
  if (d >= N) return;
  int lane = threadIdx.x & 63;
  int h4 = lane >> 4, el = lane & 15;       // stats role
  int g = lane >> 5, c32 = lane & 31;       // gather role
  int hh = c32 >> 3;
  int r0 = rowptr[d], r1 = rowptr[d + 1];
  int len = r1 - r0;
  float ad = adv[(size_t)d * 4 + h4];
  float m = -1e30f, s = 0.f;
  float acc[8] = {};
  const int hsrc = hh * 16;
  for (int base = 0; base < len; base += 16) {
    int rem = len - base; if (rem > 16) rem = 16;
    int sc = 0;
    float alpha = -1e30f;
    if (el < rem) {
      sc = colA[r0 + base + el];
      float a = asv[(size_t)sc * 4 + h4] + ad;
      alpha = (a > 0.f) ? a : NEG_SLOPE * a;
    }
    float mx = alpha;
#pragma unroll
    for (int off = 1; off < 16; off <<= 1) mx = fmaxf(mx, __shfl_xor(mx, off));
    float mn = fmaxf(m, mx);
    float scale = __expf(m - mn);
    float w = (el < rem) ? __expf(alpha - mn) : 0.f;
    float cs = w;
#pragma unroll
    for (int off = 1; off < 16; off <<= 1) cs += __shfl_xor(cs, off);
    s = s * scale + cs;
    m = mn;
    float scale_h = __shfl(scale, hsrc);
#pragma unroll
    for (int j = 0; j < 8; ++j) acc[j] *= scale_h;
    int e2 = 0;
    for (; e2 + 4 <= rem; e2 += 4) {
      int ea = e2 + g, eb = e2 + 2 + g;
      float wa = __shfl(w, hsrc + ea);
      int sa = __shfl(sc, hsrc + ea);
      float wb = __shfl(w, hsrc + eb);
      int sb = __shfl(sc, hsrc + eb);
      uint4 hva = *(const uint4*)(hbuf + (size_t)sa * 256 + c32 * 8);
      uint4 hvb = *(const uint4*)(hbuf + (size_t)sb * 256 + c32 * 8);
      float f0, f1;
      bf2x(hva.x, f0, f1); acc[0] += wa * f0; acc[1] += wa * f1;
      bf2x(hva.y, f0, f1); acc[2] += wa * f0; acc[3] += wa * f1;
      bf2x(hva.z, f0, f1); acc[4] += wa * f0; acc[5] += wa * f1;
      bf2x(hva.w, f0, f1); acc[6] += wa * f0; acc[7] += wa * f1;
      bf2x(hvb.x, f0, f1); acc[0] += wb * f0; acc[1] += wb * f1;
      bf2x(hvb.y, f0, f1); acc[2] += wb * f0; acc[3] += wb * f1;
      bf2x(hvb.z, f0, f1); acc[4] += wb * f0; acc[5] += wb * f1;
      bf2x(hvb.w, f0, f1); acc[6] += wb * f0; acc[7] += wb * f1;
    }
    for (; e2 < rem; e2 += 2) {
      int e = e2 + g;
      float w_e = __shfl(w, hsrc + (e & 15));
      int sc_e = __shfl(sc, hsrc + (e & 15));
      uint4 hv = *(const uint4*)(hbuf + (size_t)sc_e * 256 + c32 * 8);
      float f0, f1;
      bf2x(hv.x, f0, f1); acc[0] += w_e * f0; acc[1] += w_e * f1;
      bf2x(hv.y, f0, f1); acc[2] += w_e * f0; acc[3] += w_e * f1;
      bf2x(hv.z, f0, f1); acc[4] += w_e * f0; acc[5] += w_e * f1;
      bf2x(hv.w, f0, f1); acc[6] += w_e * f0; acc[7] += w_e * f1;
    }
  }
#pragma unroll
  for (int j = 0; j < 8; ++j) acc[j] += __shfl_xor(acc[j], 32);
  float inv = 1.f / (__shfl(s, hsrc) + SM_EPS);
  if (g == 0) {
    unsigned short o[8];
#pragma unroll
    for (int j = 0; j < 8; ++j) {
      float v = acc[j] * inv + bias[c32 * 8 + j];
      if (RELU) v = fmaxf(v, 0.f);
      o[j] = f2bf(v);
    }
    // non-temporal: outb is streamed once by the next GEMM; keep h in L2
    __builtin_nontemporal_store(*(u32x4*)o, (u32x4*)(outb + (size_t)d * 256 + c32 * 8));
  }
}

// --- single-pass fused softmax+gather, H=1 C=32 (layer 3), fp32 out --------
// stats: lane = edge (64/chunk). gather: 8 slots x 8 lanes x uint2 (8 edges in flight)
__global__ __launch_bounds__(256) void gat_fused32(
    const unsigned short* __restrict__ hbuf, const float* __restrict__ asv,
    const float* __restrict__ adv, const int* __restrict__ rowptr,
    const int* __restrict__ colA, const float* __restrict__ bias,
    float* __restrict__ out, int N) {
  int wv = threadIdx.x >> 6;
  int d = blockIdx.x * 4 + wv;
  if (d >= N) return;
  int lane = threadIdx.x & 63;
  int slot = lane >> 3, ci = lane & 7;  // 8 edge slots; lane covers ch [ci*4, ci*4+4)
  int r0 = rowptr[d], r1 = rowptr[d + 1];
  int len = r1 - r0;
  float ad = adv[d];
  float m = -1e30f, s = 0.f;
  float a0 = 0.f, a1 = 0.f, a2 = 0.f, a3 = 0.f;
  for (int base = 0; base < len; base += 64) {
    int rem = len - base; if (rem > 64) rem = 64;
    int sc = 0;
    float alpha = -1e30f;
    if (lane < rem) {
      sc = colA[r0 + base + lane];
      float a = asv[sc] + ad;
      alpha = (a > 0.f) ? a : NEG_SLOPE * a;
    }
    float mx = alpha;
#pragma unroll
    for (int off = 1; off < 64; off <<= 1) mx = fmaxf(mx, __shfl_xor(mx, off));
    float mn = fmaxf(m, mx);
    float scale = __expf(m - mn);
    float w = (lane < rem) ? __expf(alpha - mn) : 0.f;
    float cs = w;
#pragma unroll
    for (int off = 1; off < 64; off <<= 1) cs += __shfl_xor(cs, off);
    s = s * scale + cs;
    m = mn;
    a0 *= scale; a1 *= scale; a2 *= scale; a3 *= scale;
    for (int e2 = 0; e2 < rem; e2 += 8) {
      int e = e2 + slot;              // e <= 63 always; w==0 for e>=rem
      float w_e = __shfl(w, e);
      int sc_e = __shfl(sc, e);
      uint2 hv = *(const uint2*)(hbuf + (size_t)sc_e * 32 + ci * 4);
      float f0, f1;
      bf2x(hv.x, f0, f1); a0 += w_e * f0; a1 += w_e * f1;
      bf2x(hv.y, f0, f1); a2 += w_e * f0; a3 += w_e * f1;
    }
  }
  // reduce across the 8 edge slots (lane bits 3..5)
#pragma unroll
  for (int off = 8; off < 64; off <<= 1) {
    a0 += __shfl_xor(a0, off);
    a1 += __shfl_xor(a1, off);
    a2 += __shfl_xor(a2, off);
    a3 += __shfl_xor(a3, off);
  }
  if (slot == 0) {
    float inv = 1.f / (s + SM_EPS);
    f32x4v o;
    o.x = a0 * inv + bias[ci * 4 + 0];
    o.y = a1 * inv + bias[ci * 4 + 1];
    o.z = a2 * inv + bias[ci * 4 + 2];
    o.w = a3 * inv + bias[ci * 4 + 3];
    __builtin_nontemporal_store(o, (f32x4v*)(out + (size_t)d * 32 + ci * 4));
  }
}

// ---------------------------------------------------------------------------
extern "C" void kernel_launch(void* const* d_in, const int* in_sizes, int n_in,
                              void* d_out, int out_size, void* d_ws, size_t ws_size,
                              hipStream_t stream) {
  const float* x   = (const float*)d_in[0];
  const int*   ei  = (const int*)d_in[1];
  const float* W1  = (const float*)d_in[2];
  const float* as1 = (const float*)d_in[3];
  const float* ad1 = (const float*)d_in[4];
  const float* b1  = (const float*)d_in[5];
  const float* W2  = (const float*)d_in[6];
  const float* as2 = (const float*)d_in[7];
  const float* ad2 = (const float*)d_in[8];
  const float* b2  = (const float*)d_in[9];
  const float* W3  = (const float*)d_in[10];
  const float* as3 = (const float*)d_in[11];
  const float* ad3 = (const float*)d_in[12];
  const float* b3  = (const float*)d_in[13];
  float* out = (float*)d_out;

  const int N = in_sizes[0] / 3;
  const int E = in_sizes[1] / 2;
  const int ET = E + N;  // with self loops

  char* ws = (char*)d_ws;
  size_t off = 0;
  auto alloc = [&](size_t bytes) -> void* {
    void* p = ws + off;
    off = (off + bytes + 255) & ~(size_t)255;
    return p;
  };
  unsigned short* bufA = (unsigned short*)alloc((size_t)N * 256 * 2);
  unsigned short* bufB = (unsigned short*)alloc((size_t)N * 256 * 2);
  unsigned short* w2t  = (unsigned short*)alloc((size_t)256 * 256 * 2);
  unsigned short* w3t  = (unsigned short*)alloc((size_t)32 * 256 * 2);
  float* asbuf  = (float*)alloc((size_t)N * 4 * 4);
  float* adbuf  = (float*)alloc((size_t)N * 4 * 4);
  int*   rowptr = (int*)alloc((size_t)(N + 1) * 4);
  int*   cursor = (int*)alloc((size_t)N * 4);
  int*   colA   = (int*)alloc((size_t)ET * 4);
  int*   bsum   = (int*)alloc(1024);
  int*   dflag  = (int*)alloc(256);
  (void)ws_size;

  const int nScanB = (N + SCAN_CHUNK - 1) / SCAN_CHUNK;

  // --- CSR build + weight prep ---
  detect_i64_kernel<<<1, 64, 0, stream>>>(ei, dflag);
  hipMemsetAsync(cursor, 0, (size_t)N * 4, stream);
  wt_bf16_both<<<(256 * 256 + 256 * 32 + 255) / 256, 256, 0, stream>>>(W2, W3, w2t, w3t);
  deg_kernel<<<(E + 255) / 256, 256, 0, stream>>>(ei, E, dflag, cursor);
  scan_phaseA<<<nScanB, 256, 0, stream>>>(cursor, bsum, N);
  scan_phaseB<<<1, 256, 0, stream>>>(bsum, nScanB);
  scan_phaseC<<<nScanB, 256, 0, stream>>>(cursor, bsum, rowptr, cursor, N);
  scatter_kernel<<<(ET + 255) / 256, 256, 0, stream>>>(ei, E, N, dflag, cursor, colA);

  const int nb4 = (N + 3) / 4;

  // --- layer 1: GEMM+attn -> bufA ; fused agg -> bufB (relu) ---
  gemm_k3_attn<<<nb4, 256, 0, stream>>>(x, W1, as1, ad1, bufA, asbuf, adbuf, N);
  gat_fused256<true><<<nb4, 256, 0, stream>>>(bufA, asbuf, adbuf, rowptr, colA, b1, bufB, N);

  // --- layer 2: full-width MFMA GEMM+attn -> bufA ; fused agg -> bufB ---
  gemm_mfma_w256<<<(N + 63) / 64, 256, 0, stream>>>(bufB, w2t, bufA, as2, ad2,
                                                    asbuf, adbuf, N, 256);
  gat_fused256<true><<<nb4, 256, 0, stream>>>(bufA, asbuf, adbuf, rowptr, colA, b2, bufB, N);

  // --- layer 3: MFMA GEMM+attn -> bufA[0:N*32] ; fused agg -> out ---
  {
    dim3 grid(1, (N + 127) / 128);
    gemm_mfma<4, 1, 1><<<grid, 256, 0, stream>>>(bufB, w3t, bufA, as3, ad3, asbuf, adbuf,
                                                 N, 32, 256);
  }
  gat_fused32<<<nb4, 256, 0, stream>>>(bufA, asbuf, adbuf, rowptr, colA, b3, out, N);
}

// Round 10
// 488.329 us; speedup vs baseline: 2.7493x; 1.0279x over previous
//
#include <hip/hip_runtime.h>

// ---------------------------------------------------------------------------
// GAT 3-layer forward on MI355X. R10: layer-1 aggregation commuted with W1.
//   agg(w_e * (x W1)) == (agg w_e x) W1  -> gather 12 B/edge instead of 512.
//   Attention coefs via precomputed  A1s = W1 a_src1 (3x4),  A2s = W2 a_src2
//   (256x4): asv1 = x*A1s, asv2 = h1*A2s -- no full-h epilogues needed.
// Layers 2/3 keep GEMM-first order (gather-first would 4x the VALU).
// ---------------------------------------------------------------------------

#define NEG_SLOPE 0.2f
#define SM_EPS 1e-16f
#define SCAN_CHUNK 2048

typedef __bf16 bf16x8 __attribute__((ext_vector_type(8)));
typedef float f32x4 __attribute__((ext_vector_type(4)));
typedef unsigned int u32x4 __attribute__((ext_vector_type(4)));

__device__ __forceinline__ float bf2f(unsigned short u) {
  union { unsigned int i; float f; } v; v.i = ((unsigned int)u) << 16; return v.f;
}
__device__ __forceinline__ unsigned short f2bf(float f) {
  union { float f; unsigned int i; } v; v.f = f;
  unsigned int lsb = (v.i >> 16) & 1u;
  v.i += 0x7fffu + lsb;  // RNE
  return (unsigned short)(v.i >> 16);
}
__device__ __forceinline__ void bf2x(unsigned int u, float& f0, float& f1) {
  union { unsigned int i; float f; } a, b;
  a.i = u << 16; b.i = u & 0xffff0000u;
  f0 = a.f; f1 = b.f;
}

// --- edge dtype detection: int64 arrays read as int32 have zero odd words ---
__global__ void detect_i64_kernel(const int* __restrict__ ei, int* __restrict__ flag) {
  if (blockIdx.x == 0 && threadIdx.x == 0) {
    int orv = 0;
    for (int k = 0; k < 64; ++k) orv |= ei[2 * k + 1];
    *flag = (orv == 0) ? 1 : 0;
  }
}

__device__ __forceinline__ int load_idx(const int* __restrict__ ei, int logical, int is64) {
  return is64 ? ei[2 * logical] : ei[logical];
}

// --- CSR build -------------------------------------------------------------
__global__ void deg_kernel(const int* __restrict__ ei, int E, const int* __restrict__ flag,
                           int* __restrict__ deg) {
  int i = blockIdx.x * blockDim.x + threadIdx.x;
  if (i < E) {
    int d = load_idx(ei, E + i, *flag);
    atomicAdd(&deg[d], 1);
  }
}

__global__ __launch_bounds__(256) void scan_phaseA(const int* __restrict__ deg,
                                                   int* __restrict__ bsum, int N) {
  int t = threadIdx.x;
  int base = blockIdx.x * SCAN_CHUNK + t * 8;
  int s = 0;
#pragma unroll
  for (int i = 0; i < 8; ++i) {
    int idx = base + i;
    if (idx < N) s += deg[idx] + 1;
  }
  __shared__ int red[256];
  red[t] = s;
  __syncthreads();
  for (int d = 128; d > 0; d >>= 1) {
    if (t < d) red[t] += red[t + d];
    __syncthreads();
  }
  if (t == 0) bsum[blockIdx.x] = red[0];
}

// phase C: block offset computed from raw bsum (phaseB folded in);
// local scan + offset -> rowptr AND cursor
__global__ __launch_bounds__(256) void scan_phaseC(const int* __restrict__ deg,
                                                   const int* __restrict__ bsum,
                                                   int* __restrict__ rowptr,
                                                   int* __restrict__ cursor, int N) {
  int t = threadIdx.x;
  __shared__ int blkoff;
  if (t == 0) {
    int o = 0;
    for (int i = 0; i < (int)blockIdx.x; ++i) o += bsum[i];
    blkoff = o;
  }
  int base = blockIdx.x * SCAN_CHUNK + t * 8;
  int v[8];
  int s = 0;
#pragma unroll
  for (int i = 0; i < 8; ++i) {
    int idx = base + i;
    v[i] = (idx < N) ? deg[idx] + 1 : 0;
    s += v[i];
  }
  __shared__ int sh[256];
  sh[t] = s;
  __syncthreads();
  for (int d = 1; d < 256; d <<= 1) {
    int u = (t >= d) ? sh[t - d] : 0;
    __syncthreads();
    sh[t] += u;
    __syncthreads();
  }
  int run = blkoff + sh[t] - s;
#pragma unroll
  for (int i = 0; i < 8; ++i) {
    int idx = base + i;
    if (idx < N) { rowptr[idx] = run; cursor[idx] = run; }
    run += v[i];
  }
  if (base < N && base + 8 >= N) rowptr[N] = run;
}

__global__ void scatter_kernel(const int* __restrict__ ei, int E, int N,
                               const int* __restrict__ flag,
                               int* __restrict__ cursor, int* __restrict__ colA) {
  int i = blockIdx.x * blockDim.x + threadIdx.x;
  int is64 = *flag;
  if (i < E) {
    int s = load_idx(ei, i, is64);
    int d = load_idx(ei, E + i, is64);
    int pos = atomicAdd(&cursor[d], 1);
    colA[pos] = s;
  } else if (i < E + N) {
    int n = i - E;
    int pos = atomicAdd(&cursor[n], 1);
    colA[pos] = n;
  }
}

// --- merged weight transpose + bf16 cast for W2 (256x256) and W3 (256x32) --
__global__ void wt_bf16_both(const float* __restrict__ W2, const float* __restrict__ W3,
                             unsigned short* __restrict__ w2t, unsigned short* __restrict__ w3t) {
  int idx = blockIdx.x * 256 + threadIdx.x;
  if (idx < 256 * 256) {
    int k = idx >> 8, n = idx & 255;
    w2t[(size_t)n * 256 + k] = f2bf(W2[idx]);
  } else {
    int j = idx - 256 * 256;
    if (j < 256 * 32) {
      int k = j >> 5, n = j & 31;
      w3t[(size_t)n * 256 + k] = f2bf(W3[j]);
    }
  }
}

// --- prep small attention matrices ----------------------------------------
// A1s[k*4+h] = sum_c W1[k,h*64+c]*a_src1[h,c]   (3x4)   k<3
// A2s[c*4+h] = sum_cc W2[c,h*64+cc]*a_src2[h,cc] (256x4)
__global__ __launch_bounds__(256) void prep_small(
    const float* __restrict__ W1, const float* __restrict__ as1, const float* __restrict__ ad1,
    const float* __restrict__ W2, const float* __restrict__ as2, const float* __restrict__ ad2,
    float* __restrict__ A1s, float* __restrict__ A1d,
    float* __restrict__ A2s, float* __restrict__ A2d) {
  int c = threadIdx.x;  // 0..255
#pragma unroll
  for (int h = 0; h < 4; ++h) {
    float vs = 0.f, vd = 0.f;
    const float* wrow = W2 + (size_t)c * 256 + h * 64;
    const float* s2 = as2 + h * 64;
    const float* d2 = ad2 + h * 64;
    for (int cc = 0; cc < 64; ++cc) {
      float w = wrow[cc];
      vs += w * s2[cc];
      vd += w * d2[cc];
    }
    A2s[c * 4 + h] = vs;
    A2d[c * 4 + h] = vd;
  }
  if (c < 3) {
#pragma unroll
    for (int h = 0; h < 4; ++h) {
      float vs = 0.f, vd = 0.f;
      const float* wrow = W1 + (size_t)c * 256 + h * 64;
      const float* s1 = as1 + h * 64;
      const float* d1 = ad1 + h * 64;
      for (int cc = 0; cc < 64; ++cc) {
        float w = wrow[cc];
        vs += w * s1[cc];
        vd += w * d1[cc];
      }
      A1s[c * 4 + h] = vs;
      A1d[c * 4 + h] = vd;
    }
  }
}

// --- k1: asv1[n,h] = x[n,:]*A1s[:,h] ---------------------------------------
__global__ __launch_bounds__(256) void k1_asv1(const float* __restrict__ x,
                                               const float* __restrict__ A1s,
                                               const float* __restrict__ A1d,
                                               float* __restrict__ asv, float* __restrict__ adv,
                                               int N) {
  int n = blockIdx.x * 256 + threadIdx.x;
  if (n >= N) return;
  float x0 = x[n * 3 + 0], x1 = x[n * 3 + 1], x2 = x[n * 3 + 2];
  f32x4 s, d;
#pragma unroll
  for (int h = 0; h < 4; ++h) {
    s[h] = x0 * A1s[h] + x1 * A1s[4 + h] + x2 * A1s[8 + h];
    d[h] = x0 * A1d[h] + x1 * A1d[4 + h] + x2 * A1d[8 + h];
  }
  *(f32x4*)(asv + (size_t)n * 4) = s;
  *(f32x4*)(adv + (size_t)n * 4) = d;
}

// --- k2: layer-1 aggregation of RAW x (3 floats) per head ------------------
// wave per dst; lane = h4*16+el. Each stat lane gathers its own edge's x row.
// Output agg1[n][h][k] (already normalized by 1/s), [N][12] fp32.
__global__ __launch_bounds__(256) void k2_aggx(
    const float* __restrict__ x, const float* __restrict__ asv,
    const float* __restrict__ adv, const int* __restrict__ rowptr,
    const int* __restrict__ colA, float* __restrict__ agg, int N) {
  int wv = threadIdx.x >> 6;
  int d = blockIdx.x * 4 + wv;
  if (d >= N) return;
  int lane = threadIdx.x & 63;
  int h4 = lane >> 4, el = lane & 15;
  int r0 = rowptr[d], r1 = rowptr[d + 1];
  int len = r1 - r0;
  float ad = adv[(size_t)d * 4 + h4];
  float m = -1e30f, s = 0.f;
  float ax = 0.f, ay = 0.f, az = 0.f;
  for (int base = 0; base < len; base += 16) {
    int rem = len - base; if (rem > 16) rem = 16;
    int sc = 0;
    float alpha = -1e30f;
    if (el < rem) {
      sc = colA[r0 + base + el];
      float a = asv[(size_t)sc * 4 + h4] + ad;
      alpha = (a > 0.f) ? a : NEG_SLOPE * a;
    }
    float mx = alpha;
#pragma unroll
    for (int off = 1; off < 16; off <<= 1) mx = fmaxf(mx, __shfl_xor(mx, off));
    float mn = fmaxf(m, mx);
    float scale = __expf(m - mn);
    float w = (el < rem) ? __expf(alpha - mn) : 0.f;
    float cs = w;
#pragma unroll
    for (int off = 1; off < 16; off <<= 1) cs += __shfl_xor(cs, off);
    s = s * scale + cs;
    m = mn;
    ax *= scale; ay *= scale; az *= scale;
    if (el < rem) {
      ax += w * x[(size_t)sc * 3 + 0];
      ay += w * x[(size_t)sc * 3 + 1];
      az += w * x[(size_t)sc * 3 + 2];
    }
  }
  // reduce payload over the 16 lanes of this head group
#pragma unroll
  for (int off = 1; off < 16; off <<= 1) {
    ax += __shfl_xor(ax, off);
    ay += __shfl_xor(ay, off);
    az += __shfl_xor(az, off);
  }
  if (el == 0) {
    float inv = 1.f / (s + SM_EPS);
    agg[(size_t)d * 12 + h4 * 3 + 0] = ax * inv;
    agg[(size_t)d * 12 + h4 * 3 + 1] = ay * inv;
    agg[(size_t)d * 12 + h4 * 3 + 2] = az * inv;
  }
}

// --- k3: h1 = relu(agg1 @ W1-blocks + b1) -> bf16; epilogue asv2/adv2 ------
// wave per row; lane owns channels [lane*4, lane*4+4), head hb = lane>>4.
__global__ __launch_bounds__(256) void k3_expand(
    const float* __restrict__ agg, const float* __restrict__ W1,
    const float* __restrict__ b1, const float* __restrict__ A2s,
    const float* __restrict__ A2d, unsigned short* __restrict__ h,
    float* __restrict__ asv, float* __restrict__ adv, int N) {
  int wv = threadIdx.x >> 6, lane = threadIdx.x & 63;
  int n = blockIdx.x * 4 + wv;
  if (n >= N) return;
  int hb = lane >> 4;
  float a0 = agg[(size_t)n * 12 + hb * 3 + 0];
  float a1 = agg[(size_t)n * 12 + hb * 3 + 1];
  float a2 = agg[(size_t)n * 12 + hb * 3 + 2];
  float vs[4] = {}, vd[4] = {};
  unsigned short o[4];
#pragma unroll
  for (int j = 0; j < 4; ++j) {
    int c = lane * 4 + j;
    float val = a0 * W1[c] + a1 * W1[256 + c] + a2 * W1[512 + c] + b1[c];
    val = fmaxf(val, 0.f);
    o[j] = f2bf(val);
#pragma unroll
    for (int h2 = 0; h2 < 4; ++h2) {
      vs[h2] += val * A2s[c * 4 + h2];
      vd[h2] += val * A2d[c * 4 + h2];
    }
  }
  *(uint2*)(h + (size_t)n * 256 + lane * 4) = *(uint2*)o;
#pragma unroll
  for (int off = 1; off < 64; off <<= 1) {
#pragma unroll
    for (int h2 = 0; h2 < 4; ++h2) {
      vs[h2] += __shfl_xor(vs[h2], off);
      vd[h2] += __shfl_xor(vd[h2], off);
    }
  }
  if (lane == 0) {
    f32x4 s, d;
#pragma unroll
    for (int h2 = 0; h2 < 4; ++h2) { s[h2] = vs[h2]; d[h2] = vd[h2]; }
    *(f32x4*)(asv + (size_t)n * 4) = s;
    *(f32x4*)(adv + (size_t)n * 4) = d;
  }
}

// --- layer-2 GEMM: [M,256]@[256,256], BM=64 x BN=256 (no attn epilogue) ----
__global__ __launch_bounds__(256) void gemm_mfma_w256(
    const unsigned short* __restrict__ A, const unsigned short* __restrict__ Bt,
    unsigned short* __restrict__ C, int M, int K) {
  constexpr int BM = 64, BK = 64;
  __shared__ unsigned short As[BM][BK + 8];
  __shared__ unsigned short Bs[256][BK + 8];
  const int bm = blockIdx.x * BM;
  const int tid = threadIdx.x, wid = tid >> 6, lane = tid & 63;
  const int lrow = lane & 15, lkh = lane >> 4;
  const int srow = tid >> 3, scol = (tid & 7) * 8;
  f32x4 acc[4][4] = {};
  for (int k0 = 0; k0 < K; k0 += BK) {
#pragma unroll
    for (int r0 = 0; r0 < BM; r0 += 32) {
      int r = r0 + srow, gr = bm + r;
      uint4 v = make_uint4(0u, 0u, 0u, 0u);
      if (gr < M) v = *(const uint4*)(A + (size_t)gr * K + k0 + scol);
      *(uint4*)(&As[r][scol]) = v;
    }
#pragma unroll
    for (int r0 = 0; r0 < 256; r0 += 32) {
      int r = r0 + srow;
      uint4 v = *(const uint4*)(Bt + (size_t)r * K + k0 + scol);
      *(uint4*)(&Bs[r][scol]) = v;
    }
    __syncthreads();
#pragma unroll
    for (int kk = 0; kk < 2; ++kk) {
      bf16x8 a[4], b[4];
#pragma unroll
      for (int m = 0; m < 4; ++m)
        a[m] = *(const bf16x8*)(&As[m * 16 + lrow][kk * 32 + lkh * 8]);
#pragma unroll
      for (int n = 0; n < 4; ++n)
        b[n] = *(const bf16x8*)(&Bs[wid * 64 + n * 16 + lrow][kk * 32 + lkh * 8]);
#pragma unroll
      for (int m = 0; m < 4; ++m)
#pragma unroll
        for (int n = 0; n < 4; ++n)
          acc[m][n] = __builtin_amdgcn_mfma_f32_16x16x32_bf16(a[m], b[n], acc[m][n], 0, 0, 0);
    }
    __syncthreads();
  }
#pragma unroll
  for (int m = 0; m < 4; ++m) {
#pragma unroll
    for (int q = 0; q < 4; ++q) {
      int grow = bm + m * 16 + lkh * 4 + q;
      if (grow < M) {
#pragma unroll
        for (int n = 0; n < 4; ++n)
          C[(size_t)grow * 256 + wid * 64 + n * 16 + lrow] = f2bf(acc[m][n][q]);
      }
    }
  }
}

// --- layer-3 GEMM: BM=128 x BN=32 (full width), fused attn (H=1) -----------
template <int WR, int WC, int ATT_H>
__global__ __launch_bounds__(64 * WR * WC) void gemm_mfma(
    const unsigned short* __restrict__ A, const unsigned short* __restrict__ Bt,
    unsigned short* __restrict__ C, const float* __restrict__ a_src,
    const float* __restrict__ a_dst, float* __restrict__ asv, float* __restrict__ adv,
    int M, int N, int K) {
  constexpr int BM = 32 * WR, BN = 32 * WC, BK = 64;
  constexpr int T = 64 * WR * WC;
  constexpr int RPP = T / 8;
  __shared__ unsigned short As[BM][BK + 8];
  __shared__ unsigned short Bs[BN][BK + 8];
  const int bm = blockIdx.y * BM, bn = blockIdx.x * BN;
  const int tid = threadIdx.x, wid = tid >> 6, lane = tid & 63;
  const int wr = wid / WC, wc = wid % WC;
  const int lrow = lane & 15, lkh = lane >> 4;
  const int srow = tid >> 3, scol = (tid & 7) * 8;
  f32x4 acc[2][2] = {};
  for (int k0 = 0; k0 < K; k0 += BK) {
#pragma unroll
    for (int r0 = 0; r0 < BM; r0 += RPP) {
      int r = r0 + srow, gr = bm + r;
      uint4 v = make_uint4(0u, 0u, 0u, 0u);
      if (gr < M) v = *(const uint4*)(A + (size_t)gr * K + k0 + scol);
      *(uint4*)(&As[r][scol]) = v;
    }
#pragma unroll
    for (int r0 = 0; r0 < BN; r0 += RPP) {
      int r = r0 + srow;
      if (r < BN) {
        int gn = bn + r;
        uint4 v = *(const uint4*)(Bt + (size_t)gn * K + k0 + scol);
        *(uint4*)(&Bs[r][scol]) = v;
      }
    }
    __syncthreads();
#pragma unroll
    for (int kk = 0; kk < 2; ++kk) {
      bf16x8 a0 = *(const bf16x8*)(&As[wr * 32 + lrow][kk * 32 + lkh * 8]);
      bf16x8 a1 = *(const bf16x8*)(&As[wr * 32 + 16 + lrow][kk * 32 + lkh * 8]);
      bf16x8 b0 = *(const bf16x8*)(&Bs[wc * 32 + lrow][kk * 32 + lkh * 8]);
      bf16x8 b1 = *(const bf16x8*)(&Bs[wc * 32 + 16 + lrow][kk * 32 + lkh * 8]);
      acc[0][0] = __builtin_amdgcn_mfma_f32_16x16x32_bf16(a0, b0, acc[0][0], 0, 0, 0);
      acc[0][1] = __builtin_amdgcn_mfma_f32_16x16x32_bf16(a0, b1, acc[0][1], 0, 0, 0);
      acc[1][0] = __builtin_amdgcn_mfma_f32_16x16x32_bf16(a1, b0, acc[1][0], 0, 0, 0);
      acc[1][1] = __builtin_amdgcn_mfma_f32_16x16x32_bf16(a1, b1, acc[1][1], 0, 0, 0);
    }
    __syncthreads();
  }
#pragma unroll
  for (int m = 0; m < 2; ++m) {
#pragma unroll
    for (int q = 0; q < 4; ++q) {
      int grow = bm + wr * 32 + m * 16 + lkh * 4 + q;
      if (grow < M) {
#pragma unroll
        for (int n = 0; n < 2; ++n) {
          int gcol = bn + wc * 32 + n * 16 + lrow;
          C[(size_t)grow * N + gcol] = f2bf(acc[m][n][q]);
        }
      }
    }
  }
  const int hh = (ATT_H == 1) ? 0 : (int)blockIdx.x;
  float asl[2], adl[2];
#pragma unroll
  for (int n = 0; n < 2; ++n) {
    int c = wc * 32 + n * 16 + lrow;
    asl[n] = a_src[hh * BN + c];
    adl[n] = a_dst[hh * BN + c];
  }
#pragma unroll
  for (int m = 0; m < 2; ++m) {
#pragma unroll
    for (int q = 0; q < 4; ++q) {
      float ps = acc[m][0][q] * asl[0] + acc[m][1][q] * asl[1];
      float pd = acc[m][0][q] * adl[0] + acc[m][1][q] * adl[1];
#pragma unroll
      for (int off = 1; off < 16; off <<= 1) {
        ps += __shfl_xor(ps, off);
        pd += __shfl_xor(pd, off);
      }
      int grow = bm + wr * 32 + m * 16 + lkh * 4 + q;
      if (lrow == 0 && grow < M) {
        asv[(size_t)grow * ATT_H + hh] = ps;
        adv[(size_t)grow * ATT_H + hh] = pd;
      }
    }
  }
}

// --- single-pass fused softmax+gather, H=4 C=64: wave per dst --------------
template <bool RELU>
__global__ __launch_bounds__(256) void gat_fused256(
    const unsigned short* __restrict__ hbuf, const float* __restrict__ asv,
    const float* __restrict__ adv, const int* __restrict__ rowptr,
    const int* __restrict__ colA, const float* __restrict__ bias,
    unsigned short* __restrict__ outb, int N) {
  int wv = threadIdx.x >> 6;
  int d = blockIdx.x * 4 + wv;
  if (d >= N) return;
  int lane = threadIdx.x & 63;
  int h4 = lane >> 4, el = lane & 15;       // stats role
  int g = lane >> 5, c32 = lane & 31;       // gather role
  int hh = c32 >> 3;
  int r0 = rowptr[d], r1 = rowptr[d + 1];
  int len = r1 - r0;
  float ad = adv[(size_t)d * 4 + h4];
  float m = -1e30f, s = 0.f;
  float acc[8] = {};
  const int hsrc = hh * 16;
  for (int base = 0; base < len; base += 16) {
    int rem = len - base; if (rem > 16) rem = 16;
    int sc = 0;
    float alpha = -1e30f;
    if (el < rem) {
      sc = colA[r0 + base + el];
      float a = asv[(size_t)sc * 4 + h4] + ad;
      alpha = (a > 0.f) ? a : NEG_SLOPE * a;
    }
    float mx = alpha;
#pragma unroll
    for (int off = 1; off < 16; off <<= 1) mx = fmaxf(mx, __shfl_xor(mx, off));
    float mn = fmaxf(m, mx);
    float scale = __expf(m - mn);
    float w = (el < rem) ? __expf(alpha - mn) : 0.f;
    float cs = w;
#pragma unroll
    for (int off = 1; off < 16; off <<= 1) cs += __shfl_xor(cs, off);
    s = s * scale + cs;
    m = mn;
    float scale_h = __shfl(scale, hsrc);
#pragma unroll
    for (int j = 0; j < 8; ++j) acc[j] *= scale_h;
    int e2 = 0;
    for (; e2 + 4 <= rem; e2 += 4) {
      int ea = e2 + g, eb = e2 + 2 + g;
      float wa = __shfl(w, hsrc + ea);
      int sa = __shfl(sc, hsrc + ea);
      float wb = __shfl(w, hsrc + eb);
      int sb = __shfl(sc, hsrc + eb);
      uint4 hva = *(const uint4*)(hbuf + (size_t)sa * 256 + c32 * 8);
      uint4 hvb = *(const uint4*)(hbuf + (size_t)sb * 256 + c32 * 8);
      float f0, f1;
      bf2x(hva.x, f0, f1); acc[0] += wa * f0; acc[1] += wa * f1;
      bf2x(hva.y, f0, f1); acc[2] += wa * f0; acc[3] += wa * f1;
      bf2x(hva.z, f0, f1); acc[4] += wa * f0; acc[5] += wa * f1;
      bf2x(hva.w, f0, f1); acc[6] += wa * f0; acc[7] += wa * f1;
      bf2x(hvb.x, f0, f1); acc[0] += wb * f0; acc[1] += wb * f1;
      bf2x(hvb.y, f0, f1); acc[2] += wb * f0; acc[3] += wb * f1;
      bf2x(hvb.z, f0, f1); acc[4] += wb * f0; acc[5] += wb * f1;
      bf2x(hvb.w, f0, f1); acc[6] += wb * f0; acc[7] += wb * f1;
    }
    for (; e2 < rem; e2 += 2) {
      int e = e2 + g;
      float w_e = __shfl(w, hsrc + (e & 15));
      int sc_e = __shfl(sc, hsrc + (e & 15));
      uint4 hv = *(const uint4*)(hbuf + (size_t)sc_e * 256 + c32 * 8);
      float f0, f1;
      bf2x(hv.x, f0, f1); acc[0] += w_e * f0; acc[1] += w_e * f1;
      bf2x(hv.y, f0, f1); acc[2] += w_e * f0; acc[3] += w_e * f1;
      bf2x(hv.z, f0, f1); acc[4] += w_e * f0; acc[5] += w_e * f1;
      bf2x(hv.w, f0, f1); acc[6] += w_e * f0; acc[7] += w_e * f1;
    }
  }
#pragma unroll
  for (int j = 0; j < 8; ++j) acc[j] += __shfl_xor(acc[j], 32);
  float inv = 1.f / (__shfl(s, hsrc) + SM_EPS);
  if (g == 0) {
    unsigned short o[8];
#pragma unroll
    for (int j = 0; j < 8; ++j) {
      float v = acc[j] * inv + bias[c32 * 8 + j];
      if (RELU) v = fmaxf(v, 0.f);
      o[j] = f2bf(v);
    }
    __builtin_nontemporal_store(*(u32x4*)o, (u32x4*)(outb + (size_t)d * 256 + c32 * 8));
  }
}

// --- single-pass fused softmax+gather, H=1 C=32 (layer 3), fp32 out --------
__global__ __launch_bounds__(256) void gat_fused32(
    const unsigned short* __restrict__ hbuf, const float* __restrict__ asv,
    const float* __restrict__ adv, const int* __restrict__ rowptr,
    const int* __restrict__ colA, const float* __restrict__ bias,
    float* __restrict__ out, int N) {
  int wv = threadIdx.x >> 6;
  int d = blockIdx.x * 4 + wv;
  if (d >= N) return;
  int lane = threadIdx.x & 63;
  int slot = lane >> 3, ci = lane & 7;
  int r0 = rowptr[d], r1 = rowptr[d + 1];
  int len = r1 - r0;
  float ad = adv[d];
  float m = -1e30f, s = 0.f;
  float a0 = 0.f, a1 = 0.f, a2 = 0.f, a3 = 0.f;
  for (int base = 0; base < len; base += 64) {
    int rem = len - base; if (rem > 64) rem = 64;
    int sc = 0;
    float alpha = -1e30f;
    if (lane < rem) {
      sc = colA[r0 + base + lane];
      float a = asv[sc] + ad;
      alpha = (a > 0.f) ? a : NEG_SLOPE * a;
    }
    float mx = alpha;
#pragma unroll
    for (int off = 1; off < 64; off <<= 1) mx = fmaxf(mx, __shfl_xor(mx, off));
    float mn = fmaxf(m, mx);
    float scale = __expf(m - mn);
    float w = (lane < rem) ? __expf(alpha - mn) : 0.f;
    float cs = w;
#pragma unroll
    for (int off = 1; off < 64; off <<= 1) cs += __shfl_xor(cs, off);
    s = s * scale + cs;
    m = mn;
    a0 *= scale; a1 *= scale; a2 *= scale; a3 *= scale;
    for (int e2 = 0; e2 < rem; e2 += 8) {
      int e = e2 + slot;
      float w_e = __shfl(w, e);
      int sc_e = __shfl(sc, e);
      uint2 hv = *(const uint2*)(hbuf + (size_t)sc_e * 32 + ci * 4);
      float f0, f1;
      bf2x(hv.x, f0, f1); a0 += w_e * f0; a1 += w_e * f1;
      bf2x(hv.y, f0, f1); a2 += w_e * f0; a3 += w_e * f1;
    }
  }
#pragma unroll
  for (int off = 8; off < 64; off <<= 1) {
    a0 += __shfl_xor(a0, off);
    a1 += __shfl_xor(a1, off);
    a2 += __shfl_xor(a2, off);
    a3 += __shfl_xor(a3, off);
  }
  if (slot == 0) {
    float inv = 1.f / (s + SM_EPS);
    f32x4 o;
    o.x = a0 * inv + bias[ci * 4 + 0];
    o.y = a1 * inv + bias[ci * 4 + 1];
    o.z = a2 * inv + bias[ci * 4 + 2];
    o.w = a3 * inv + bias[ci * 4 + 3];
    __builtin_nontemporal_store(o, (f32x4*)(out + (size_t)d * 32 + ci * 4));
  }
}

// ---------------------------------------------------------------------------
extern "C" void kernel_launch(void* const* d_in, const int* in_sizes, int n_in,
                              void* d_out, int out_size, void* d_ws, size_t ws_size,
                              hipStream_t stream) {
  const float* x   = (const float*)d_in[0];
  const int*   ei  = (const int*)d_in[1];
  const float* W1  = (const float*)d_in[2];
  const float* as1 = (const float*)d_in[3];
  const float* ad1 = (const float*)d_in[4];
  const float* b1  = (const float*)d_in[5];
  const float* W2  = (const float*)d_in[6];
  const float* as2 = (const float*)d_in[7];
  const float* ad2 = (const float*)d_in[8];
  const float* b2  = (const float*)d_in[9];
  const float* W3  = (const float*)d_in[10];
  const float* as3 = (const float*)d_in[11];
  const float* ad3 = (const float*)d_in[12];
  const float* b3  = (const float*)d_in[13];
  float* out = (float*)d_out;

  const int N = in_sizes[0] / 3;
  const int E = in_sizes[1] / 2;
  const int ET = E + N;  // with self loops

  char* ws = (char*)d_ws;
  size_t off = 0;
  auto alloc = [&](size_t bytes) -> void* {
    void* p = ws + off;
    off = (off + bytes + 255) & ~(size_t)255;
    return p;
  };
  unsigned short* bufA = (unsigned short*)alloc((size_t)N * 256 * 2);
  unsigned short* bufB = (unsigned short*)alloc((size_t)N * 256 * 2);
  unsigned short* w2t  = (unsigned short*)alloc((size_t)256 * 256 * 2);
  unsigned short* w3t  = (unsigned short*)alloc((size_t)32 * 256 * 2);
  float* asbuf  = (float*)alloc((size_t)N * 4 * 4);
  float* adbuf  = (float*)alloc((size_t)N * 4 * 4);
  float* aggbuf = (float*)alloc((size_t)N * 12 * 4);
  int*   rowptr = (int*)alloc((size_t)(N + 1) * 4);
  int*   cursor = (int*)alloc((size_t)N * 4);
  int*   colA   = (int*)alloc((size_t)ET * 4);
  int*   bsum   = (int*)alloc(1024);
  int*   dflag  = (int*)alloc(256);
  float* A1s    = (float*)alloc(12 * 4);
  float* A1d    = (float*)alloc(12 * 4);
  float* A2s    = (float*)alloc(1024 * 4);
  float* A2d    = (float*)alloc(1024 * 4);
  (void)ws_size;

  const int nScanB = (N + SCAN_CHUNK - 1) / SCAN_CHUNK;

  // --- CSR build + weight prep ---
  detect_i64_kernel<<<1, 64, 0, stream>>>(ei, dflag);
  hipMemsetAsync(cursor, 0, (size_t)N * 4, stream);
  prep_small<<<1, 256, 0, stream>>>(W1, as1, ad1, W2, as2, ad2, A1s, A1d, A2s, A2d);
  wt_bf16_both<<<(256 * 256 + 256 * 32 + 255) / 256, 256, 0, stream>>>(W2, W3, w2t, w3t);
  deg_kernel<<<(E + 255) / 256, 256, 0, stream>>>(ei, E, dflag, cursor);
  scan_phaseA<<<nScanB, 256, 0, stream>>>(cursor, bsum, N);
  scan_phaseC<<<nScanB, 256, 0, stream>>>(cursor, bsum, rowptr, cursor, N);
  scatter_kernel<<<(ET + 255) / 256, 256, 0, stream>>>(ei, E, N, dflag, cursor, colA);

  const int nb4 = (N + 3) / 4;

  // --- layer 1: asv1 -> agg raw x -> expand with W1 (+asv2 epilogue) ---
  k1_asv1<<<(N + 255) / 256, 256, 0, stream>>>(x, A1s, A1d, asbuf, adbuf, N);
  k2_aggx<<<nb4, 256, 0, stream>>>(x, asbuf, adbuf, rowptr, colA, aggbuf, N);
  k3_expand<<<nb4, 256, 0, stream>>>(aggbuf, W1, b1, A2s, A2d, bufB, asbuf, adbuf, N);

  // --- layer 2: h2 = h1 @ W2 (MFMA) -> bufA ; fused agg -> bufB ---
  gemm_mfma_w256<<<(N + 63) / 64, 256, 0, stream>>>(bufB, w2t, bufA, N, 256);
  gat_fused256<true><<<nb4, 256, 0, stream>>>(bufA, asbuf, adbuf, rowptr, colA, b2, bufB, N);

  // --- layer 3: MFMA GEMM+attn -> bufA[0:N*32] ; fused agg -> out ---
  {
    dim3 grid(1, (N + 127) / 128);
    gemm_mfma<4, 1, 1><<<grid, 256, 0, stream>>>(bufB, w3t, bufA, as3, ad3, asbuf, adbuf,
                                                 N, 32, 256);
  }
  gat_fused32<<<nb4, 256, 0, stream>>>(bufA, asbuf, adbuf, rowptr, colA, b3, out, N);
}

// Round 11
// 430.251 us; speedup vs baseline: 3.1204x; 1.1350x over previous
//
#include <hip/hip_runtime.h>

// ---------------------------------------------------------------------------
// GAT 3-layer forward on MI355X. R11: atomic-free CSR scatter.
//   deg pass records pos[i] = atomicAdd(cnt[dst],1); scatter is then a pure
//   permutation write colA[rowptr[d]+pos[i]] = src (NT store, no atomics).
//   Self-loop lands at rowptr[n+1]-1. cursor array + memset eliminated.
// Layer 1 stays commuted (aggregate raw x); layers 2/3 GEMM-first.
// ---------------------------------------------------------------------------

#define NEG_SLOPE 0.2f
#define SM_EPS 1e-16f
#define SCAN_CHUNK 2048

typedef __bf16 bf16x8 __attribute__((ext_vector_type(8)));
typedef float f32x4 __attribute__((ext_vector_type(4)));
typedef unsigned int u32x4 __attribute__((ext_vector_type(4)));

__device__ __forceinline__ float bf2f(unsigned short u) {
  union { unsigned int i; float f; } v; v.i = ((unsigned int)u) << 16; return v.f;
}
__device__ __forceinline__ unsigned short f2bf(float f) {
  union { float f; unsigned int i; } v; v.f = f;
  unsigned int lsb = (v.i >> 16) & 1u;
  v.i += 0x7fffu + lsb;  // RNE
  return (unsigned short)(v.i >> 16);
}
__device__ __forceinline__ void bf2x(unsigned int u, float& f0, float& f1) {
  union { unsigned int i; float f; } a, b;
  a.i = u << 16; b.i = u & 0xffff0000u;
  f0 = a.f; f1 = b.f;
}

// --- edge dtype detection: int64 arrays read as int32 have zero odd words ---
__global__ void detect_i64_kernel(const int* __restrict__ ei, int* __restrict__ flag) {
  if (blockIdx.x == 0 && threadIdx.x == 0) {
    int orv = 0;
    for (int k = 0; k < 64; ++k) orv |= ei[2 * k + 1];
    *flag = (orv == 0) ? 1 : 0;
  }
}

__device__ __forceinline__ int load_idx(const int* __restrict__ ei, int logical, int is64) {
  return is64 ? ei[2 * logical] : ei[logical];
}

// --- CSR build -------------------------------------------------------------
// pass 1: count AND record within-segment position (atomic return value)
__global__ void deg_pos_kernel(const int* __restrict__ ei, int E,
                               const int* __restrict__ flag,
                               int* __restrict__ cnt, int* __restrict__ pos) {
  int i = blockIdx.x * blockDim.x + threadIdx.x;
  if (i < E) {
    int d = load_idx(ei, E + i, *flag);
    pos[i] = atomicAdd(&cnt[d], 1);
  }
}

__global__ __launch_bounds__(256) void scan_phaseA(const int* __restrict__ deg,
                                                   int* __restrict__ bsum, int N) {
  int t = threadIdx.x;
  int base = blockIdx.x * SCAN_CHUNK + t * 8;
  int s = 0;
#pragma unroll
  for (int i = 0; i < 8; ++i) {
    int idx = base + i;
    if (idx < N) s += deg[idx] + 1;
  }
  __shared__ int red[256];
  red[t] = s;
  __syncthreads();
  for (int d = 128; d > 0; d >>= 1) {
    if (t < d) red[t] += red[t + d];
    __syncthreads();
  }
  if (t == 0) bsum[blockIdx.x] = red[0];
}

// phase C: block offset computed from raw bsum (phaseB folded in);
// local scan + offset -> rowptr
__global__ __launch_bounds__(256) void scan_phaseC(const int* __restrict__ deg,
                                                   const int* __restrict__ bsum,
                                                   int* __restrict__ rowptr, int N) {
  int t = threadIdx.x;
  __shared__ int blkoff;
  if (t == 0) {
    int o = 0;
    for (int i = 0; i < (int)blockIdx.x; ++i) o += bsum[i];
    blkoff = o;
  }
  int base = blockIdx.x * SCAN_CHUNK + t * 8;
  int v[8];
  int s = 0;
#pragma unroll
  for (int i = 0; i < 8; ++i) {
    int idx = base + i;
    v[i] = (idx < N) ? deg[idx] + 1 : 0;
    s += v[i];
  }
  __shared__ int sh[256];
  sh[t] = s;
  __syncthreads();
  for (int d = 1; d < 256; d <<= 1) {
    int u = (t >= d) ? sh[t - d] : 0;
    __syncthreads();
    sh[t] += u;
    __syncthreads();
  }
  int run = blkoff + sh[t] - s;
#pragma unroll
  for (int i = 0; i < 8; ++i) {
    int idx = base + i;
    if (idx < N) rowptr[idx] = run;
    run += v[i];
  }
  if (base < N && base + 8 >= N) rowptr[N] = run;
}

// pass 2: pure permutation write, no atomics
__global__ void scatter2_kernel(const int* __restrict__ ei, int E, int N,
                                const int* __restrict__ flag,
                                const int* __restrict__ rowptr,
                                const int* __restrict__ pos, int* __restrict__ colA) {
  int i = blockIdx.x * blockDim.x + threadIdx.x;
  int is64 = *flag;
  if (i < E) {
    int s = load_idx(ei, i, is64);
    int d = load_idx(ei, E + i, is64);
    __builtin_nontemporal_store(s, &colA[rowptr[d] + pos[i]]);
  } else if (i < E + N) {
    int n = i - E;
    __builtin_nontemporal_store(n, &colA[rowptr[n + 1] - 1]);  // self loop: last slot
  }
}

// --- merged weight transpose + bf16 cast for W2 (256x256) and W3 (256x32) --
__global__ void wt_bf16_both(const float* __restrict__ W2, const float* __restrict__ W3,
                             unsigned short* __restrict__ w2t, unsigned short* __restrict__ w3t) {
  int idx = blockIdx.x * 256 + threadIdx.x;
  if (idx < 256 * 256) {
    int k = idx >> 8, n = idx & 255;
    w2t[(size_t)n * 256 + k] = f2bf(W2[idx]);
  } else {
    int j = idx - 256 * 256;
    if (j < 256 * 32) {
      int k = j >> 5, n = j & 31;
      w3t[(size_t)n * 256 + k] = f2bf(W3[j]);
    }
  }
}

// --- prep small attention matrices ----------------------------------------
__global__ __launch_bounds__(256) void prep_small(
    const float* __restrict__ W1, const float* __restrict__ as1, const float* __restrict__ ad1,
    const float* __restrict__ W2, const float* __restrict__ as2, const float* __restrict__ ad2,
    float* __restrict__ A1s, float* __restrict__ A1d,
    float* __restrict__ A2s, float* __restrict__ A2d) {
  int c = threadIdx.x;  // 0..255
#pragma unroll
  for (int h = 0; h < 4; ++h) {
    float vs = 0.f, vd = 0.f;
    const float* wrow = W2 + (size_t)c * 256 + h * 64;
    const float* s2 = as2 + h * 64;
    const float* d2 = ad2 + h * 64;
    for (int cc = 0; cc < 64; ++cc) {
      float w = wrow[cc];
      vs += w * s2[cc];
      vd += w * d2[cc];
    }
    A2s[c * 4 + h] = vs;
    A2d[c * 4 + h] = vd;
  }
  if (c < 3) {
#pragma unroll
    for (int h = 0; h < 4; ++h) {
      float vs = 0.f, vd = 0.f;
      const float* wrow = W1 + (size_t)c * 256 + h * 64;
      const float* s1 = as1 + h * 64;
      const float* d1 = ad1 + h * 64;
      for (int cc = 0; cc < 64; ++cc) {
        float w = wrow[cc];
        vs += w * s1[cc];
        vd += w * d1[cc];
      }
      A1s[c * 4 + h] = vs;
      A1d[c * 4 + h] = vd;
    }
  }
}

// --- k1: asv1[n,h] = x[n,:]*A1s[:,h] ---------------------------------------
__global__ __launch_bounds__(256) void k1_asv1(const float* __restrict__ x,
                                               const float* __restrict__ A1s,
                                               const float* __restrict__ A1d,
                                               float* __restrict__ asv, float* __restrict__ adv,
                                               int N) {
  int n = blockIdx.x * 256 + threadIdx.x;
  if (n >= N) return;
  float x0 = x[n * 3 + 0], x1 = x[n * 3 + 1], x2 = x[n * 3 + 2];
  f32x4 s, d;
#pragma unroll
  for (int h = 0; h < 4; ++h) {
    s[h] = x0 * A1s[h] + x1 * A1s[4 + h] + x2 * A1s[8 + h];
    d[h] = x0 * A1d[h] + x1 * A1d[4 + h] + x2 * A1d[8 + h];
  }
  *(f32x4*)(asv + (size_t)n * 4) = s;
  *(f32x4*)(adv + (size_t)n * 4) = d;
}

// --- k2: layer-1 aggregation of RAW x (3 floats) per head ------------------
__global__ __launch_bounds__(256) void k2_aggx(
    const float* __restrict__ x, const float* __restrict__ asv,
    const float* __restrict__ adv, const int* __restrict__ rowptr,
    const int* __restrict__ colA, float* __restrict__ agg, int N) {
  int wv = threadIdx.x >> 6;
  int d = blockIdx.x * 4 + wv;
  if (d >= N) return;
  int lane = threadIdx.x & 63;
  int h4 = lane >> 4, el = lane & 15;
  int r0 = rowptr[d], r1 = rowptr[d + 1];
  int len = r1 - r0;
  float ad = adv[(size_t)d * 4 + h4];
  float m = -1e30f, s = 0.f;
  float ax = 0.f, ay = 0.f, az = 0.f;
  for (int base = 0; base < len; base += 16) {
    int rem = len - base; if (rem > 16) rem = 16;
    int sc = 0;
    float alpha = -1e30f;
    if (el < rem) {
      sc = colA[r0 + base + el];
      float a = asv[(size_t)sc * 4 + h4] + ad;
      alpha = (a > 0.f) ? a : NEG_SLOPE * a;
    }
    float mx = alpha;
#pragma unroll
    for (int off = 1; off < 16; off <<= 1) mx = fmaxf(mx, __shfl_xor(mx, off));
    float mn = fmaxf(m, mx);
    float scale = __expf(m - mn);
    float w = (el < rem) ? __expf(alpha - mn) : 0.f;
    float cs = w;
#pragma unroll
    for (int off = 1; off < 16; off <<= 1) cs += __shfl_xor(cs, off);
    s = s * scale + cs;
    m = mn;
    ax *= scale; ay *= scale; az *= scale;
    if (el < rem) {
      ax += w * x[(size_t)sc * 3 + 0];
      ay += w * x[(size_t)sc * 3 + 1];
      az += w * x[(size_t)sc * 3 + 2];
    }
  }
#pragma unroll
  for (int off = 1; off < 16; off <<= 1) {
    ax += __shfl_xor(ax, off);
    ay += __shfl_xor(ay, off);
    az += __shfl_xor(az, off);
  }
  if (el == 0) {
    float inv = 1.f / (s + SM_EPS);
    agg[(size_t)d * 12 + h4 * 3 + 0] = ax * inv;
    agg[(size_t)d * 12 + h4 * 3 + 1] = ay * inv;
    agg[(size_t)d * 12 + h4 * 3 + 2] = az * inv;
  }
}

// --- k3: h1 = relu(agg1 @ W1-blocks + b1) -> bf16; epilogue asv2/adv2 ------
__global__ __launch_bounds__(256) void k3_expand(
    const float* __restrict__ agg, const float* __restrict__ W1,
    const float* __restrict__ b1, const float* __restrict__ A2s,
    const float* __restrict__ A2d, unsigned short* __restrict__ h,
    float* __restrict__ asv, float* __restrict__ adv, int N) {
  int wv = threadIdx.x >> 6, lane = threadIdx.x & 63;
  int n = blockIdx.x * 4 + wv;
  if (n >= N) return;
  int hb = lane >> 4;
  float a0 = agg[(size_t)n * 12 + hb * 3 + 0];
  float a1 = agg[(size_t)n * 12 + hb * 3 + 1];
  float a2 = agg[(size_t)n * 12 + hb * 3 + 2];
  float vs[4] = {}, vd[4] = {};
  unsigned short o[4];
#pragma unroll
  for (int j = 0; j < 4; ++j) {
    int c = lane * 4 + j;
    float val = a0 * W1[c] + a1 * W1[256 + c] + a2 * W1[512 + c] + b1[c];
    val = fmaxf(val, 0.f);
    o[j] = f2bf(val);
#pragma unroll
    for (int h2 = 0; h2 < 4; ++h2) {
      vs[h2] += val * A2s[c * 4 + h2];
      vd[h2] += val * A2d[c * 4 + h2];
    }
  }
  *(uint2*)(h + (size_t)n * 256 + lane * 4) = *(uint2*)o;
#pragma unroll
  for (int off = 1; off < 64; off <<= 1) {
#pragma unroll
    for (int h2 = 0; h2 < 4; ++h2) {
      vs[h2] += __shfl_xor(vs[h2], off);
      vd[h2] += __shfl_xor(vd[h2], off);
    }
  }
  if (lane == 0) {
    f32x4 s, d;
#pragma unroll
    for (int h2 = 0; h2 < 4; ++h2) { s[h2] = vs[h2]; d[h2] = vd[h2]; }
    *(f32x4*)(asv + (size_t)n * 4) = s;
    *(f32x4*)(adv + (size_t)n * 4) = d;
  }
}

// --- layer-2 GEMM: [M,256]@[256,256], BM=64 x BN=256 (no attn epilogue) ----
__global__ __launch_bounds__(256) void gemm_mfma_w256(
    const unsigned short* __restrict__ A, const unsigned short* __restrict__ Bt,
    unsigned short* __restrict__ C, int M, int K) {
  constexpr int BM = 64, BK = 64;
  __shared__ unsigned short As[BM][BK + 8];
  __shared__ unsigned short Bs[256][BK + 8];
  const int bm = blockIdx.x * BM;
  const int tid = threadIdx.x, wid = tid >> 6, lane = tid & 63;
  const int lrow = lane & 15, lkh = lane >> 4;
  const int srow = tid >> 3, scol = (tid & 7) * 8;
  f32x4 acc[4][4] = {};
  for (int k0 = 0; k0 < K; k0 += BK) {
#pragma unroll
    for (int r0 = 0; r0 < BM; r0 += 32) {
      int r = r0 + srow, gr = bm + r;
      uint4 v = make_uint4(0u, 0u, 0u, 0u);
      if (gr < M) v = *(const uint4*)(A + (size_t)gr * K + k0 + scol);
      *(uint4*)(&As[r][scol]) = v;
    }
#pragma unroll
    for (int r0 = 0; r0 < 256; r0 += 32) {
      int r = r0 + srow;
      uint4 v = *(const uint4*)(Bt + (size_t)r * K + k0 + scol);
      *(uint4*)(&Bs[r][scol]) = v;
    }
    __syncthreads();
#pragma unroll
    for (int kk = 0; kk < 2; ++kk) {
      bf16x8 a[4], b[4];
#pragma unroll
      for (int m = 0; m < 4; ++m)
        a[m] = *(const bf16x8*)(&As[m * 16 + lrow][kk * 32 + lkh * 8]);
#pragma unroll
      for (int n = 0; n < 4; ++n)
        b[n] = *(const bf16x8*)(&Bs[wid * 64 + n * 16 + lrow][kk * 32 + lkh * 8]);
#pragma unroll
      for (int m = 0; m < 4; ++m)
#pragma unroll
        for (int n = 0; n < 4; ++n)
          acc[m][n] = __builtin_amdgcn_mfma_f32_16x16x32_bf16(a[m], b[n], acc[m][n], 0, 0, 0);
    }
    __syncthreads();
  }
#pragma unroll
  for (int m = 0; m < 4; ++m) {
#pragma unroll
    for (int q = 0; q < 4; ++q) {
      int grow = bm + m * 16 + lkh * 4 + q;
      if (grow < M) {
#pragma unroll
        for (int n = 0; n < 4; ++n)
          C[(size_t)grow * 256 + wid * 64 + n * 16 + lrow] = f2bf(acc[m][n][q]);
      }
    }
  }
}

// --- layer-3 GEMM: BM=128 x BN=32 (full width), fused attn (H=1) -----------
template <int WR, int WC, int ATT_H>
__global__ __launch_bounds__(64 * WR * WC) void gemm_mfma(
    const unsigned short* __restrict__ A, const unsigned short* __restrict__ Bt,
    unsigned short* __restrict__ C, const float* __restrict__ a_src,
    const float* __restrict__ a_dst, float* __restrict__ asv, float* __restrict__ adv,
    int M, int N, int K) {
  constexpr int BM = 32 * WR, BN = 32 * WC, BK = 64;
  constexpr int T = 64 * WR * WC;
  constexpr int RPP = T / 8;
  __shared__ unsigned short As[BM][BK + 8];
  __shared__ unsigned short Bs[BN][BK + 8];
  const int bm = blockIdx.y * BM, bn = blockIdx.x * BN;
  const int tid = threadIdx.x, wid = tid >> 6, lane = tid & 63;
  const int wr = wid / WC, wc = wid % WC;
  const int lrow = lane & 15, lkh = lane >> 4;
  const int srow = tid >> 3, scol = (tid & 7) * 8;
  f32x4 acc[2][2] = {};
  for (int k0 = 0; k0 < K; k0 += BK) {
#pragma unroll
    for (int r0 = 0; r0 < BM; r0 += RPP) {
      int r = r0 + srow, gr = bm + r;
      uint4 v = make_uint4(0u, 0u, 0u, 0u);
      if (gr < M) v = *(const uint4*)(A + (size_t)gr * K + k0 + scol);
      *(uint4*)(&As[r][scol]) = v;
    }
#pragma unroll
    for (int r0 = 0; r0 < BN; r0 += RPP) {
      int r = r0 + srow;
      if (r < BN) {
        int gn = bn + r;
        uint4 v = *(const uint4*)(Bt + (size_t)gn * K + k0 + scol);
        *(uint4*)(&Bs[r][scol]) = v;
      }
    }
    __syncthreads();
#pragma unroll
    for (int kk = 0; kk < 2; ++kk) {
      bf16x8 a0 = *(const bf16x8*)(&As[wr * 32 + lrow][kk * 32 + lkh * 8]);
      bf16x8 a1 = *(const bf16x8*)(&As[wr * 32 + 16 + lrow][kk * 32 + lkh * 8]);
      bf16x8 b0 = *(const bf16x8*)(&Bs[wc * 32 + lrow][kk * 32 + lkh * 8]);
      bf16x8 b1 = *(const bf16x8*)(&Bs[wc * 32 + 16 + lrow][kk * 32 + lkh * 8]);
      acc[0][0] = __builtin_amdgcn_mfma_f32_16x16x32_bf16(a0, b0, acc[0][0], 0, 0, 0);
      acc[0][1] = __builtin_amdgcn_mfma_f32_16x16x32_bf16(a0, b1, acc[0][1], 0, 0, 0);
      acc[1][0] = __builtin_amdgcn_mfma_f32_16x16x32_bf16(a1, b0, acc[1][0], 0, 0, 0);
      acc[1][1] = __builtin_amdgcn_mfma_f32_16x16x32_bf16(a1, b1, acc[1][1], 0, 0, 0);
    }
    __syncthreads();
  }
#pragma unroll
  for (int m = 0; m < 2; ++m) {
#pragma unroll
    for (int q = 0; q < 4; ++q) {
      int grow = bm + wr * 32 + m * 16 + lkh * 4 + q;
      if (grow < M) {
#pragma unroll
        for (int n = 0; n < 2; ++n) {
          int gcol = bn + wc * 32 + n * 16 + lrow;
          C[(size_t)grow * N + gcol] = f2bf(acc[m][n][q]);
        }
      }
    }
  }
  const int hh = (ATT_H == 1) ? 0 : (int)blockIdx.x;
  float asl[2], adl[2];
#pragma unroll
  for (int n = 0; n < 2; ++n) {
    int c = wc * 32 + n * 16 + lrow;
    asl[n] = a_src[hh * BN + c];
    adl[n] = a_dst[hh * BN + c];
  }
#pragma unroll
  for (int m = 0; m < 2; ++m) {
#pragma unroll
    for (int q = 0; q < 4; ++q) {
      float ps = acc[m][0][q] * asl[0] + acc[m][1][q] * asl[1];
      float pd = acc[m][0][q] * adl[0] + acc[m][1][q] * adl[1];
#pragma unroll
      for (int off = 1; off < 16; off <<= 1) {
        ps += __shfl_xor(ps, off);
        pd += __shfl_xor(pd, off);
      }
      int grow = bm + wr * 32 + m * 16 + lkh * 4 + q;
      if (lrow == 0 && grow < M) {
        asv[(size_t)grow * ATT_H + hh] = ps;
        adv[(size_t)grow * ATT_H + hh] = pd;
      }
    }
  }
}

// --- single-pass fused softmax+gather, H=4 C=64: wave per dst --------------
template <bool RELU>
__global__ __launch_bounds__(256) void gat_fused256(
    const unsigned short* __restrict__ hbuf, const float* __restrict__ asv,
    const float* __restrict__ adv, const int* __restrict__ rowptr,
    const int* __restrict__ colA, const float* __restrict__ bias,
    unsigned short* __restrict__ outb, int N) {
  int wv = threadIdx.x >> 6;
  int d = blockIdx.x * 4 + wv;
  if (d >= N) return;
  int lane = threadIdx.x & 63;
  int h4 = lane >> 4, el = lane & 15;       // stats role
  int g = lane >> 5, c32 = lane & 31;       // gather role
  int hh = c32 >> 3;
  int r0 = rowptr[d], r1 = rowptr[d + 1];
  int len = r1 - r0;
  float ad = adv[(size_t)d * 4 + h4];
  float m = -1e30f, s = 0.f;
  float acc[8] = {};
  const int hsrc = hh * 16;
  for (int base = 0; base < len; base += 16) {
    int rem = len - base; if (rem > 16) rem = 16;
    int sc = 0;
    float alpha = -1e30f;
    if (el < rem) {
      sc = colA[r0 + base + el];
      float a = asv[(size_t)sc * 4 + h4] + ad;
      alpha = (a > 0.f) ? a : NEG_SLOPE * a;
    }
    float mx = alpha;
#pragma unroll
    for (int off = 1; off < 16; off <<= 1) mx = fmaxf(mx, __shfl_xor(mx, off));
    float mn = fmaxf(m, mx);
    float scale = __expf(m - mn);
    float w = (el < rem) ? __expf(alpha - mn) : 0.f;
    float cs = w;
#pragma unroll
    for (int off = 1; off < 16; off <<= 1) cs += __shfl_xor(cs, off);
    s = s * scale + cs;
    m = mn;
    float scale_h = __shfl(scale, hsrc);
#pragma unroll
    for (int j = 0; j < 8; ++j) acc[j] *= scale_h;
    int e2 = 0;
    for (; e2 + 4 <= rem; e2 += 4) {
      int ea = e2 + g, eb = e2 + 2 + g;
      float wa = __shfl(w, hsrc + ea);
      int sa = __shfl(sc, hsrc + ea);
      float wb = __shfl(w, hsrc + eb);
      int sb = __shfl(sc, hsrc + eb);
      uint4 hva = *(const uint4*)(hbuf + (size_t)sa * 256 + c32 * 8);
      uint4 hvb = *(const uint4*)(hbuf + (size_t)sb * 256 + c32 * 8);
      float f0, f1;
      bf2x(hva.x, f0, f1); acc[0] += wa * f0; acc[1] += wa * f1;
      bf2x(hva.y, f0, f1); acc[2] += wa * f0; acc[3] += wa * f1;
      bf2x(hva.z, f0, f1); acc[4] += wa * f0; acc[5] += wa * f1;
      bf2x(hva.w, f0, f1); acc[6] += wa * f0; acc[7] += wa * f1;
      bf2x(hvb.x, f0, f1); acc[0] += wb * f0; acc[1] += wb * f1;
      bf2x(hvb.y, f0, f1); acc[2] += wb * f0; acc[3] += wb * f1;
      bf2x(hvb.z, f0, f1); acc[4] += wb * f0; acc[5] += wb * f1;
      bf2x(hvb.w, f0, f1); acc[6] += wb * f0; acc[7] += wb * f1;
    }
    for (; e2 < rem; e2 += 2) {
      int e = e2 + g;
      float w_e = __shfl(w, hsrc + (e & 15));
      int sc_e = __shfl(sc, hsrc + (e & 15));
      uint4 hv = *(const uint4*)(hbuf + (size_t)sc_e * 256 + c32 * 8);
      float f0, f1;
      bf2x(hv.x, f0, f1); acc[0] += w_e * f0; acc[1] += w_e * f1;
      bf2x(hv.y, f0, f1); acc[2] += w_e * f0; acc[3] += w_e * f1;
      bf2x(hv.z, f0, f1); acc[4] += w_e * f0; acc[5] += w_e * f1;
      bf2x(hv.w, f0, f1); acc[6] += w_e * f0; acc[7] += w_e * f1;
    }
  }
#pragma unroll
  for (int j = 0; j < 8; ++j) acc[j] += __shfl_xor(acc[j], 32);
  float inv = 1.f / (__shfl(s, hsrc) + SM_EPS);
  if (g == 0) {
    unsigned short o[8];
#pragma unroll
    for (int j = 0; j < 8; ++j) {
      float v = acc[j] * inv + bias[c32 * 8 + j];
      if (RELU) v = fmaxf(v, 0.f);
      o[j] = f2bf(v);
    }
    __builtin_nontemporal_store(*(u32x4*)o, (u32x4*)(outb + (size_t)d * 256 + c32 * 8));
  }
}

// --- single-pass fused softmax+gather, H=1 C=32 (layer 3), fp32 out --------
__global__ __launch_bounds__(256) void gat_fused32(
    const unsigned short* __restrict__ hbuf, const float* __restrict__ asv,
    const float* __restrict__ adv, const int* __restrict__ rowptr,
    const int* __restrict__ colA, const float* __restrict__ bias,
    float* __restrict__ out, int N) {
  int wv = threadIdx.x >> 6;
  int d = blockIdx.x * 4 + wv;
  if (d >= N) return;
  int lane = threadIdx.x & 63;
  int slot = lane >> 3, ci = lane & 7;
  int r0 = rowptr[d], r1 = rowptr[d + 1];
  int len = r1 - r0;
  float ad = adv[d];
  float m = -1e30f, s = 0.f;
  float a0 = 0.f, a1 = 0.f, a2 = 0.f, a3 = 0.f;
  for (int base = 0; base < len; base += 64) {
    int rem = len - base; if (rem > 64) rem = 64;
    int sc = 0;
    float alpha = -1e30f;
    if (lane < rem) {
      sc = colA[r0 + base + lane];
      float a = asv[sc] + ad;
      alpha = (a > 0.f) ? a : NEG_SLOPE * a;
    }
    float mx = alpha;
#pragma unroll
    for (int off = 1; off < 64; off <<= 1) mx = fmaxf(mx, __shfl_xor(mx, off));
    float mn = fmaxf(m, mx);
    float scale = __expf(m - mn);
    float w = (lane < rem) ? __expf(alpha - mn) : 0.f;
    float cs = w;
#pragma unroll
    for (int off = 1; off < 64; off <<= 1) cs += __shfl_xor(cs, off);
    s = s * scale + cs;
    m = mn;
    a0 *= scale; a1 *= scale; a2 *= scale; a3 *= scale;
    for (int e2 = 0; e2 < rem; e2 += 8) {
      int e = e2 + slot;
      float w_e = __shfl(w, e);
      int sc_e = __shfl(sc, e);
      uint2 hv = *(const uint2*)(hbuf + (size_t)sc_e * 32 + ci * 4);
      float f0, f1;
      bf2x(hv.x, f0, f1); a0 += w_e * f0; a1 += w_e * f1;
      bf2x(hv.y, f0, f1); a2 += w_e * f0; a3 += w_e * f1;
    }
  }
#pragma unroll
  for (int off = 8; off < 64; off <<= 1) {
    a0 += __shfl_xor(a0, off);
    a1 += __shfl_xor(a1, off);
    a2 += __shfl_xor(a2, off);
    a3 += __shfl_xor(a3, off);
  }
  if (slot == 0) {
    float inv = 1.f / (s + SM_EPS);
    f32x4 o;
    o.x = a0 * inv + bias[ci * 4 + 0];
    o.y = a1 * inv + bias[ci * 4 + 1];
    o.z = a2 * inv + bias[ci * 4 + 2];
    o.w = a3 * inv + bias[ci * 4 + 3];
    __builtin_nontemporal_store(o, (f32x4*)(out + (size_t)d * 32 + ci * 4));
  }
}

// ---------------------------------------------------------------------------
extern "C" void kernel_launch(void* const* d_in, const int* in_sizes, int n_in,
                              void* d_out, int out_size, void* d_ws, size_t ws_size,
                              hipStream_t stream) {
  const float* x   = (const float*)d_in[0];
  const int*   ei  = (const int*)d_in[1];
  const float* W1  = (const float*)d_in[2];
  const float* as1 = (const float*)d_in[3];
  const float* ad1 = (const float*)d_in[4];
  const float* b1  = (const float*)d_in[5];
  const float* W2  = (const float*)d_in[6];
  const float* as2 = (const float*)d_in[7];
  const float* ad2 = (const float*)d_in[8];
  const float* b2  = (const float*)d_in[9];
  const float* W3  = (const float*)d_in[10];
  const float* as3 = (const float*)d_in[11];
  const float* ad3 = (const float*)d_in[12];
  const float* b3  = (const float*)d_in[13];
  float* out = (float*)d_out;

  const int N = in_sizes[0] / 3;
  const int E = in_sizes[1] / 2;
  const int ET = E + N;  // with self loops

  char* ws = (char*)d_ws;
  size_t off = 0;
  auto alloc = [&](size_t bytes) -> void* {
    void* p = ws + off;
    off = (off + bytes + 255) & ~(size_t)255;
    return p;
  };
  unsigned short* bufA = (unsigned short*)alloc((size_t)N * 256 * 2);
  unsigned short* bufB = (unsigned short*)alloc((size_t)N * 256 * 2);
  unsigned short* w2t  = (unsigned short*)alloc((size_t)256 * 256 * 2);
  unsigned short* w3t  = (unsigned short*)alloc((size_t)32 * 256 * 2);
  float* asbuf  = (float*)alloc((size_t)N * 4 * 4);
  float* adbuf  = (float*)alloc((size_t)N * 4 * 4);
  float* aggbuf = (float*)alloc((size_t)N * 12 * 4);
  int*   rowptr = (int*)alloc((size_t)(N + 1) * 4);
  int*   cnt    = (int*)alloc((size_t)N * 4);
  int*   posb   = (int*)alloc((size_t)E * 4);
  int*   colA   = (int*)alloc((size_t)ET * 4);
  int*   bsum   = (int*)alloc(1024);
  int*   dflag  = (int*)alloc(256);
  float* A1s    = (float*)alloc(12 * 4);
  float* A1d    = (float*)alloc(12 * 4);
  float* A2s    = (float*)alloc(1024 * 4);
  float* A2d    = (float*)alloc(1024 * 4);
  (void)ws_size;

  const int nScanB = (N + SCAN_CHUNK - 1) / SCAN_CHUNK;

  // --- CSR build + weight prep ---
  detect_i64_kernel<<<1, 64, 0, stream>>>(ei, dflag);
  hipMemsetAsync(cnt, 0, (size_t)N * 4, stream);
  prep_small<<<1, 256, 0, stream>>>(W1, as1, ad1, W2, as2, ad2, A1s, A1d, A2s, A2d);
  wt_bf16_both<<<(256 * 256 + 256 * 32 + 255) / 256, 256, 0, stream>>>(W2, W3, w2t, w3t);
  deg_pos_kernel<<<(E + 255) / 256, 256, 0, stream>>>(ei, E, dflag, cnt, posb);
  scan_phaseA<<<nScanB, 256, 0, stream>>>(cnt, bsum, N);
  scan_phaseC<<<nScanB, 256, 0, stream>>>(cnt, bsum, rowptr, N);
  scatter2_kernel<<<(ET + 255) / 256, 256, 0, stream>>>(ei, E, N, dflag, rowptr, posb, colA);

  const int nb4 = (N + 3) / 4;

  // --- layer 1: asv1 -> agg raw x -> expand with W1 (+asv2 epilogue) ---
  k1_asv1<<<(N + 255) / 256, 256, 0, stream>>>(x, A1s, A1d, asbuf, adbuf, N);
  k2_aggx<<<nb4, 256, 0, stream>>>(x, asbuf, adbuf, rowptr, colA, aggbuf, N);
  k3_expand<<<nb4, 256, 0, stream>>>(aggbuf, W1, b1, A2s, A2d, bufB, asbuf, adbuf, N);

  // --- layer 2: h2 = h1 @ W2 (MFMA) -> bufA ; fused agg -> bufB ---
  gemm_mfma_w256<<<(N + 63) / 64, 256, 0, stream>>>(bufB, w2t, bufA, N, 256);
  gat_fused256<true><<<nb4, 256, 0, stream>>>(bufA, asbuf, adbuf, rowptr, colA, b2, bufB, N);

  // --- layer 3: MFMA GEMM+attn -> bufA[0:N*32] ; fused agg -> out ---
  {
    dim3 grid(1, (N + 127) / 128);
    gemm_mfma<4, 1, 1><<<grid, 256, 0, stream>>>(bufB, w3t, bufA, as3, ad3, asbuf, adbuf,
                                                 N, 32, 256);
  }
  gat_fused32<<<nb4, 256, 0, stream>>>(bufA, asbuf, adbuf, rowptr, colA, b3, out, N);
}

// Round 12
// 400.071 us; speedup vs baseline: 3.3558x; 1.0754x over previous
//
#include <hip/hip_runtime.h>

// ---------------------------------------------------------------------------
// GAT 3-layer forward on MI355X. R12:
//  - k3 fused into k2 (agg buffer + launch eliminated; head-group layout
//    makes the W1 expansion wave-local)
//  - prep_mega: deg_pos + k1(asv1, block-local A1) + weight transpose + A2
//    prep in one grid-partitioned kernel
//  - GEMM2: BM=128 x BN=256, 512 threads (16 waves/CU, half the B re-reads)
// ---------------------------------------------------------------------------

#define NEG_SLOPE 0.2f
#define SM_EPS 1e-16f
#define SCAN_CHUNK 2048

typedef __bf16 bf16x8 __attribute__((ext_vector_type(8)));
typedef float f32x4 __attribute__((ext_vector_type(4)));
typedef unsigned int u32x4 __attribute__((ext_vector_type(4)));

__device__ __forceinline__ float bf2f(unsigned short u) {
  union { unsigned int i; float f; } v; v.i = ((unsigned int)u) << 16; return v.f;
}
__device__ __forceinline__ unsigned short f2bf(float f) {
  union { float f; unsigned int i; } v; v.f = f;
  unsigned int lsb = (v.i >> 16) & 1u;
  v.i += 0x7fffu + lsb;  // RNE
  return (unsigned short)(v.i >> 16);
}
__device__ __forceinline__ void bf2x(unsigned int u, float& f0, float& f1) {
  union { unsigned int i; float f; } a, b;
  a.i = u << 16; b.i = u & 0xffff0000u;
  f0 = a.f; f1 = b.f;
}

// --- edge dtype detection: int64 arrays read as int32 have zero odd words ---
__global__ void detect_i64_kernel(const int* __restrict__ ei, int* __restrict__ flag) {
  if (blockIdx.x == 0 && threadIdx.x == 0) {
    int orv = 0;
    for (int k = 0; k < 64; ++k) orv |= ei[2 * k + 1];
    *flag = (orv == 0) ? 1 : 0;
  }
}

__device__ __forceinline__ int load_idx(const int* __restrict__ ei, int logical, int is64) {
  return is64 ? ei[2 * logical] : ei[logical];
}

// --- prep_mega: deg_pos | k1_asv1 | weight transpose | A2 prep -------------
__global__ __launch_bounds__(256) void prep_mega(
    const int* __restrict__ ei, int E, const int* __restrict__ flag,
    int* __restrict__ cnt, int* __restrict__ pos,
    const float* __restrict__ x, const float* __restrict__ W1,
    const float* __restrict__ as1, const float* __restrict__ ad1,
    float* __restrict__ asv, float* __restrict__ adv, int N,
    const float* __restrict__ W2, const float* __restrict__ W3,
    unsigned short* __restrict__ w2t, unsigned short* __restrict__ w3t,
    const float* __restrict__ as2, const float* __restrict__ ad2,
    float* __restrict__ A2s, float* __restrict__ A2d,
    int nbDeg, int nbK1, int nbWt) {
  int bid = blockIdx.x;
  int t = threadIdx.x;
  if (bid < nbDeg) {
    // pass 1 of CSR: count + record within-segment position
    int i = bid * 256 + t;
    if (i < E) {
      int d = load_idx(ei, E + i, *flag);
      pos[i] = atomicAdd(&cnt[d], 1);
    }
  } else if (bid < nbDeg + nbK1) {
    // k1: asv1/adv1 via block-local A1 = W1^T a1 (3x4, computed in LDS)
    __shared__ float A1[24];
    if (t < 24) {
      int e = t % 12;
      int k = e >> 2, h = e & 3;
      const float* av = (t < 12) ? as1 : ad1;
      const float* wr = W1 + k * 256 + h * 64;
      const float* a = av + h * 64;
      float v = 0.f;
      for (int c = 0; c < 64; ++c) v += wr[c] * a[c];
      A1[t] = v;
    }
    __syncthreads();
    int n = (bid - nbDeg) * 256 + t;
    if (n < N) {
      float x0 = x[n * 3 + 0], x1 = x[n * 3 + 1], x2 = x[n * 3 + 2];
      f32x4 s, d;
#pragma unroll
      for (int h = 0; h < 4; ++h) {
        s[h] = x0 * A1[h] + x1 * A1[4 + h] + x2 * A1[8 + h];
        d[h] = x0 * A1[12 + h] + x1 * A1[16 + h] + x2 * A1[20 + h];
      }
      *(f32x4*)(asv + (size_t)n * 4) = s;
      *(f32x4*)(adv + (size_t)n * 4) = d;
    }
  } else if (bid < nbDeg + nbK1 + nbWt) {
    // weight transpose + bf16 cast
    int idx = (bid - nbDeg - nbK1) * 256 + t;
    if (idx < 256 * 256) {
      int k = idx >> 8, n = idx & 255;
      w2t[(size_t)n * 256 + k] = f2bf(W2[idx]);
    } else {
      int j = idx - 256 * 256;
      if (j < 256 * 32) {
        int k = j >> 5, n = j & 31;
        w3t[(size_t)n * 256 + k] = f2bf(W3[j]);
      }
    }
  } else {
    // A2s/A2d = W2 a2 (256x4 each)
    int c = t;
#pragma unroll
    for (int h = 0; h < 4; ++h) {
      float vs = 0.f, vd = 0.f;
      const float* wrow = W2 + (size_t)c * 256 + h * 64;
      const float* s2 = as2 + h * 64;
      const float* d2 = ad2 + h * 64;
      for (int cc = 0; cc < 64; ++cc) {
        float w = wrow[cc];
        vs += w * s2[cc];
        vd += w * d2[cc];
      }
      A2s[c * 4 + h] = vs;
      A2d[c * 4 + h] = vd;
    }
  }
}

__global__ __launch_bounds__(256) void scan_phaseA(const int* __restrict__ deg,
                                                   int* __restrict__ bsum, int N) {
  int t = threadIdx.x;
  int base = blockIdx.x * SCAN_CHUNK + t * 8;
  int s = 0;
#pragma unroll
  for (int i = 0; i < 8; ++i) {
    int idx = base + i;
    if (idx < N) s += deg[idx] + 1;
  }
  __shared__ int red[256];
  red[t] = s;
  __syncthreads();
  for (int d = 128; d > 0; d >>= 1) {
    if (t < d) red[t] += red[t + d];
    __syncthreads();
  }
  if (t == 0) bsum[blockIdx.x] = red[0];
}

__global__ __launch_bounds__(256) void scan_phaseC(const int* __restrict__ deg,
                                                   const int* __restrict__ bsum,
                                                   int* __restrict__ rowptr, int N) {
  int t = threadIdx.x;
  __shared__ int blkoff;
  if (t == 0) {
    int o = 0;
    for (int i = 0; i < (int)blockIdx.x; ++i) o += bsum[i];
    blkoff = o;
  }
  int base = blockIdx.x * SCAN_CHUNK + t * 8;
  int v[8];
  int s = 0;
#pragma unroll
  for (int i = 0; i < 8; ++i) {
    int idx = base + i;
    v[i] = (idx < N) ? deg[idx] + 1 : 0;
    s += v[i];
  }
  __shared__ int sh[256];
  sh[t] = s;
  __syncthreads();
  for (int d = 1; d < 256; d <<= 1) {
    int u = (t >= d) ? sh[t - d] : 0;
    __syncthreads();
    sh[t] += u;
    __syncthreads();
  }
  int run = blkoff + sh[t] - s;
#pragma unroll
  for (int i = 0; i < 8; ++i) {
    int idx = base + i;
    if (idx < N) rowptr[idx] = run;
    run += v[i];
  }
  if (base < N && base + 8 >= N) rowptr[N] = run;
}

// pass 2 of CSR: pure permutation write, no atomics
__global__ void scatter2_kernel(const int* __restrict__ ei, int E, int N,
                                const int* __restrict__ flag,
                                const int* __restrict__ rowptr,
                                const int* __restrict__ pos, int* __restrict__ colA) {
  int i = blockIdx.x * blockDim.x + threadIdx.x;
  int is64 = *flag;
  if (i < E) {
    int s = load_idx(ei, i, is64);
    int d = load_idx(ei, E + i, is64);
    __builtin_nontemporal_store(s, &colA[rowptr[d] + pos[i]]);
  } else if (i < E + N) {
    int n = i - E;
    __builtin_nontemporal_store(n, &colA[rowptr[n + 1] - 1]);  // self loop: last slot
  }
}

// --- k2_fused: layer-1 agg of raw x + W1 expansion + asv2 epilogue ---------
// wave per dst; lane = h4*16+el. After the 16-lane butterfly every lane of
// head-group h4 holds (ax,ay,az,s); channel head (lane>>4) == h4, so the
// expansion is wave-local. Writes h1 (bf16) + asv2/adv2 directly.
__global__ __launch_bounds__(256) void k2_fused(
    const float* __restrict__ x, const float* __restrict__ asv,
    const float* __restrict__ adv, const int* __restrict__ rowptr,
    const int* __restrict__ colA, const float* __restrict__ W1,
    const float* __restrict__ b1, const float* __restrict__ A2s,
    const float* __restrict__ A2d, unsigned short* __restrict__ h,
    float* __restrict__ asv2, float* __restrict__ adv2, int N) {
  int wv = threadIdx.x >> 6;
  int d = blockIdx.x * 4 + wv;
  if (d >= N) return;
  int lane = threadIdx.x & 63;
  int h4 = lane >> 4, el = lane & 15;
  int r0 = rowptr[d], r1 = rowptr[d + 1];
  int len = r1 - r0;
  float ad = adv[(size_t)d * 4 + h4];
  float m = -1e30f, s = 0.f;
  float ax = 0.f, ay = 0.f, az = 0.f;
  for (int base = 0; base < len; base += 16) {
    int rem = len - base; if (rem > 16) rem = 16;
    int sc = 0;
    float alpha = -1e30f;
    if (el < rem) {
      sc = colA[r0 + base + el];
      float a = asv[(size_t)sc * 4 + h4] + ad;
      alpha = (a > 0.f) ? a : NEG_SLOPE * a;
    }
    float mx = alpha;
#pragma unroll
    for (int off = 1; off < 16; off <<= 1) mx = fmaxf(mx, __shfl_xor(mx, off));
    float mn = fmaxf(m, mx);
    float scale = __expf(m - mn);
    float w = (el < rem) ? __expf(alpha - mn) : 0.f;
    float cs = w;
#pragma unroll
    for (int off = 1; off < 16; off <<= 1) cs += __shfl_xor(cs, off);
    s = s * scale + cs;
    m = mn;
    ax *= scale; ay *= scale; az *= scale;
    if (el < rem) {
      ax += w * x[(size_t)sc * 3 + 0];
      ay += w * x[(size_t)sc * 3 + 1];
      az += w * x[(size_t)sc * 3 + 2];
    }
  }
  // butterfly: all 16 lanes of the group get the full sums
#pragma unroll
  for (int off = 1; off < 16; off <<= 1) {
    ax += __shfl_xor(ax, off);
    ay += __shfl_xor(ay, off);
    az += __shfl_xor(az, off);
  }
  float inv = 1.f / (s + SM_EPS);
  ax *= inv; ay *= inv; az *= inv;
  // expansion: lane owns channels [lane*4, lane*4+4), head lane>>4 == h4
  float vs[4] = {}, vd[4] = {};
  unsigned short o[4];
#pragma unroll
  for (int j = 0; j < 4; ++j) {
    int c = lane * 4 + j;
    float val = ax * W1[c] + ay * W1[256 + c] + az * W1[512 + c] + b1[c];
    val = fmaxf(val, 0.f);
    o[j] = f2bf(val);
#pragma unroll
    for (int h2 = 0; h2 < 4; ++h2) {
      vs[h2] += val * A2s[c * 4 + h2];
      vd[h2] += val * A2d[c * 4 + h2];
    }
  }
  *(uint2*)(h + (size_t)d * 256 + lane * 4) = *(uint2*)o;
#pragma unroll
  for (int off = 1; off < 64; off <<= 1) {
#pragma unroll
    for (int h2 = 0; h2 < 4; ++h2) {
      vs[h2] += __shfl_xor(vs[h2], off);
      vd[h2] += __shfl_xor(vd[h2], off);
    }
  }
  if (lane == 0) {
    f32x4 sv, dv;
#pragma unroll
    for (int h2 = 0; h2 < 4; ++h2) { sv[h2] = vs[h2]; dv[h2] = vd[h2]; }
    *(f32x4*)(asv2 + (size_t)d * 4) = sv;
    *(f32x4*)(adv2 + (size_t)d * 4) = dv;
  }
}

// --- layer-2 GEMM: [M,256]@[256,256], BM=128 x BN=256, 512 threads ---------
__global__ __launch_bounds__(512) void gemm_mfma_w256(
    const unsigned short* __restrict__ A, const unsigned short* __restrict__ Bt,
    unsigned short* __restrict__ C, int M, int K) {
  constexpr int BM = 128, BK = 64;
  __shared__ unsigned short As[BM][BK + 8];
  __shared__ unsigned short Bs[256][BK + 8];
  const int bm = blockIdx.x * BM;
  const int tid = threadIdx.x, wid = tid >> 6, lane = tid & 63;
  const int wr = wid >> 2, wc = wid & 3;  // 2x4 wave grid: 64 rows x 64 cols each
  const int lrow = lane & 15, lkh = lane >> 4;
  const int srow = tid >> 3, scol = (tid & 7) * 8;  // 64 rows x 64 cols per pass
  f32x4 acc[4][4] = {};
  for (int k0 = 0; k0 < K; k0 += BK) {
#pragma unroll
    for (int r0 = 0; r0 < BM; r0 += 64) {
      int r = r0 + srow, gr = bm + r;
      uint4 v = make_uint4(0u, 0u, 0u, 0u);
      if (gr < M) v = *(const uint4*)(A + (size_t)gr * K + k0 + scol);
      *(uint4*)(&As[r][scol]) = v;
    }
#pragma unroll
    for (int r0 = 0; r0 < 256; r0 += 64) {
      int r = r0 + srow;
      uint4 v = *(const uint4*)(Bt + (size_t)r * K + k0 + scol);
      *(uint4*)(&Bs[r][scol]) = v;
    }
    __syncthreads();
#pragma unroll
    for (int kk = 0; kk < 2; ++kk) {
      bf16x8 a[4], b[4];
#pragma unroll
      for (int m = 0; m < 4; ++m)
        a[m] = *(const bf16x8*)(&As[wr * 64 + m * 16 + lrow][kk * 32 + lkh * 8]);
#pragma unroll
      for (int n = 0; n < 4; ++n)
        b[n] = *(const bf16x8*)(&Bs[wc * 64 + n * 16 + lrow][kk * 32 + lkh * 8]);
#pragma unroll
      for (int m = 0; m < 4; ++m)
#pragma unroll
        for (int n = 0; n < 4; ++n)
          acc[m][n] = __builtin_amdgcn_mfma_f32_16x16x32_bf16(a[m], b[n], acc[m][n], 0, 0, 0);
    }
    __syncthreads();
  }
#pragma unroll
  for (int m = 0; m < 4; ++m) {
#pragma unroll
    for (int q = 0; q < 4; ++q) {
      int grow = bm + wr * 64 + m * 16 + lkh * 4 + q;
      if (grow < M) {
#pragma unroll
        for (int n = 0; n < 4; ++n)
          C[(size_t)grow * 256 + wc * 64 + n * 16 + lrow] = f2bf(acc[m][n][q]);
      }
    }
  }
}

// --- layer-3 GEMM: BM=128 x BN=32 (full width), fused attn (H=1) -----------
template <int WR, int WC, int ATT_H>
__global__ __launch_bounds__(64 * WR * WC) void gemm_mfma(
    const unsigned short* __restrict__ A, const unsigned short* __restrict__ Bt,
    unsigned short* __restrict__ C, const float* __restrict__ a_src,
    const float* __restrict__ a_dst, float* __restrict__ asv, float* __restrict__ adv,
    int M, int N, int K) {
  constexpr int BM = 32 * WR, BN = 32 * WC, BK = 64;
  constexpr int T = 64 * WR * WC;
  constexpr int RPP = T / 8;
  __shared__ unsigned short As[BM][BK + 8];
  __shared__ unsigned short Bs[BN][BK + 8];
  const int bm = blockIdx.y * BM, bn = blockIdx.x * BN;
  const int tid = threadIdx.x, wid = tid >> 6, lane = tid & 63;
  const int wr = wid / WC, wc = wid % WC;
  const int lrow = lane & 15, lkh = lane >> 4;
  const int srow = tid >> 3, scol = (tid & 7) * 8;
  f32x4 acc[2][2] = {};
  for (int k0 = 0; k0 < K; k0 += BK) {
#pragma unroll
    for (int r0 = 0; r0 < BM; r0 += RPP) {
      int r = r0 + srow, gr = bm + r;
      uint4 v = make_uint4(0u, 0u, 0u, 0u);
      if (gr < M) v = *(const uint4*)(A + (size_t)gr * K + k0 + scol);
      *(uint4*)(&As[r][scol]) = v;
    }
#pragma unroll
    for (int r0 = 0; r0 < BN; r0 += RPP) {
      int r = r0 + srow;
      if (r < BN) {
        int gn = bn + r;
        uint4 v = *(const uint4*)(Bt + (size_t)gn * K + k0 + scol);
        *(uint4*)(&Bs[r][scol]) = v;
      }
    }
    __syncthreads();
#pragma unroll
    for (int kk = 0; kk < 2; ++kk) {
      bf16x8 a0 = *(const bf16x8*)(&As[wr * 32 + lrow][kk * 32 + lkh * 8]);
      bf16x8 a1 = *(const bf16x8*)(&As[wr * 32 + 16 + lrow][kk * 32 + lkh * 8]);
      bf16x8 b0 = *(const bf16x8*)(&Bs[wc * 32 + lrow][kk * 32 + lkh * 8]);
      bf16x8 b1 = *(const bf16x8*)(&Bs[wc * 32 + 16 + lrow][kk * 32 + lkh * 8]);
      acc[0][0] = __builtin_amdgcn_mfma_f32_16x16x32_bf16(a0, b0, acc[0][0], 0, 0, 0);
      acc[0][1] = __builtin_amdgcn_mfma_f32_16x16x32_bf16(a0, b1, acc[0][1], 0, 0, 0);
      acc[1][0] = __builtin_amdgcn_mfma_f32_16x16x32_bf16(a1, b0, acc[1][0], 0, 0, 0);
      acc[1][1] = __builtin_amdgcn_mfma_f32_16x16x32_bf16(a1, b1, acc[1][1], 0, 0, 0);
    }
    __syncthreads();
  }
#pragma unroll
  for (int m = 0; m < 2; ++m) {
#pragma unroll
    for (int q = 0; q < 4; ++q) {
      int grow = bm + wr * 32 + m * 16 + lkh * 4 + q;
      if (grow < M) {
#pragma unroll
        for (int n = 0; n < 2; ++n) {
          int gcol = bn + wc * 32 + n * 16 + lrow;
          C[(size_t)grow * N + gcol] = f2bf(acc[m][n][q]);
        }
      }
    }
  }
  const int hh = (ATT_H == 1) ? 0 : (int)blockIdx.x;
  float asl[2], adl[2];
#pragma unroll
  for (int n = 0; n < 2; ++n) {
    int c = wc * 32 + n * 16 + lrow;
    asl[n] = a_src[hh * BN + c];
    adl[n] = a_dst[hh * BN + c];
  }
#pragma unroll
  for (int m = 0; m < 2; ++m) {
#pragma unroll
    for (int q = 0; q < 4; ++q) {
      float ps = acc[m][0][q] * asl[0] + acc[m][1][q] * asl[1];
      float pd = acc[m][0][q] * adl[0] + acc[m][1][q] * adl[1];
#pragma unroll
      for (int off = 1; off < 16; off <<= 1) {
        ps += __shfl_xor(ps, off);
        pd += __shfl_xor(pd, off);
      }
      int grow = bm + wr * 32 + m * 16 + lkh * 4 + q;
      if (lrow == 0 && grow < M) {
        asv[(size_t)grow * ATT_H + hh] = ps;
        adv[(size_t)grow * ATT_H + hh] = pd;
      }
    }
  }
}

// --- single-pass fused softmax+gather, H=4 C=64: wave per dst --------------
template <bool RELU>
__global__ __launch_bounds__(256) void gat_fused256(
    const unsigned short* __restrict__ hbuf, const float* __restrict__ asv,
    const float* __restrict__ adv, const int* __restrict__ rowptr,
    const int* __restrict__ colA, const float* __restrict__ bias,
    unsigned short* __restrict__ outb, int N) {
  int wv = threadIdx.x >> 6;
  int d = blockIdx.x * 4 + wv;
  if (d >= N) return;
  int lane = threadIdx.x & 63;
  int h4 = lane >> 4, el = lane & 15;       // stats role
  int g = lane >> 5, c32 = lane & 31;       // gather role
  int hh = c32 >> 3;
  int r0 = rowptr[d], r1 = rowptr[d + 1];
  int len = r1 - r0;
  float ad = adv[(size_t)d * 4 + h4];
  float m = -1e30f, s = 0.f;
  float acc[8] = {};
  const int hsrc = hh * 16;
  for (int base = 0; base < len; base += 16) {
    int rem = len - base; if (rem > 16) rem = 16;
    int sc = 0;
    float alpha = -1e30f;
    if (el < rem) {
      sc = colA[r0 + base + el];
      float a = asv[(size_t)sc * 4 + h4] + ad;
      alpha = (a > 0.f) ? a : NEG_SLOPE * a;
    }
    float mx = alpha;
#pragma unroll
    for (int off = 1; off < 16; off <<= 1) mx = fmaxf(mx, __shfl_xor(mx, off));
    float mn = fmaxf(m, mx);
    float scale = __expf(m - mn);
    float w = (el < rem) ? __expf(alpha - mn) : 0.f;
    float cs = w;
#pragma unroll
    for (int off = 1; off < 16; off <<= 1) cs += __shfl_xor(cs, off);
    s = s * scale + cs;
    m = mn;
    float scale_h = __shfl(scale, hsrc);
#pragma unroll
    for (int j = 0; j < 8; ++j) acc[j] *= scale_h;
    int e2 = 0;
    for (; e2 + 4 <= rem; e2 += 4) {
      int ea = e2 + g, eb = e2 + 2 + g;
      float wa = __shfl(w, hsrc + ea);
      int sa = __shfl(sc, hsrc + ea);
      float wb = __shfl(w, hsrc + eb);
      int sb = __shfl(sc, hsrc + eb);
      uint4 hva = *(const uint4*)(hbuf + (size_t)sa * 256 + c32 * 8);
      uint4 hvb = *(const uint4*)(hbuf + (size_t)sb * 256 + c32 * 8);
      float f0, f1;
      bf2x(hva.x, f0, f1); acc[0] += wa * f0; acc[1] += wa * f1;
      bf2x(hva.y, f0, f1); acc[2] += wa * f0; acc[3] += wa * f1;
      bf2x(hva.z, f0, f1); acc[4] += wa * f0; acc[5] += wa * f1;
      bf2x(hva.w, f0, f1); acc[6] += wa * f0; acc[7] += wa * f1;
      bf2x(hvb.x, f0, f1); acc[0] += wb * f0; acc[1] += wb * f1;
      bf2x(hvb.y, f0, f1); acc[2] += wb * f0; acc[3] += wb * f1;
      bf2x(hvb.z, f0, f1); acc[4] += wb * f0; acc[5] += wb * f1;
      bf2x(hvb.w, f0, f1); acc[6] += wb * f0; acc[7] += wb * f1;
    }
    for (; e2 < rem; e2 += 2) {
      int e = e2 + g;
      float w_e = __shfl(w, hsrc + (e & 15));
      int sc_e = __shfl(sc, hsrc + (e & 15));
      uint4 hv = *(const uint4*)(hbuf + (size_t)sc_e * 256 + c32 * 8);
      float f0, f1;
      bf2x(hv.x, f0, f1); acc[0] += w_e * f0; acc[1] += w_e * f1;
      bf2x(hv.y, f0, f1); acc[2] += w_e * f0; acc[3] += w_e * f1;
      bf2x(hv.z, f0, f1); acc[4] += w_e * f0; acc[5] += w_e * f1;
      bf2x(hv.w, f0, f1); acc[6] += w_e * f0; acc[7] += w_e * f1;
    }
  }
#pragma unroll
  for (int j = 0; j < 8; ++j) acc[j] += __shfl_xor(acc[j], 32);
  float inv = 1.f / (__shfl(s, hsrc) + SM_EPS);
  if (g == 0) {
    unsigned short o[8];
#pragma unroll
    for (int j = 0; j < 8; ++j) {
      float v = acc[j] * inv + bias[c32 * 8 + j];
      if (RELU) v = fmaxf(v, 0.f);
      o[j] = f2bf(v);
    }
    __builtin_nontemporal_store(*(u32x4*)o, (u32x4*)(outb + (size_t)d * 256 + c32 * 8));
  }
}

// --- single-pass fused softmax+gather, H=1 C=32 (layer 3), fp32 out --------
__global__ __launch_bounds__(256) void gat_fused32(
    const unsigned short* __restrict__ hbuf, const float* __restrict__ asv,
    const float* __restrict__ adv, const int* __restrict__ rowptr,
    const int* __restrict__ colA, const float* __restrict__ bias,
    float* __restrict__ out, int N) {
  int wv = threadIdx.x >> 6;
  int d = blockIdx.x * 4 + wv;
  if (d >= N) return;
  int lane = threadIdx.x & 63;
  int slot = lane >> 3, ci = lane & 7;
  int r0 = rowptr[d], r1 = rowptr[d + 1];
  int len = r1 - r0;
  float ad = adv[d];
  float m = -1e30f, s = 0.f;
  float a0 = 0.f, a1 = 0.f, a2 = 0.f, a3 = 0.f;
  for (int base = 0; base < len; base += 64) {
    int rem = len - base; if (rem > 64) rem = 64;
    int sc = 0;
    float alpha = -1e30f;
    if (lane < rem) {
      sc = colA[r0 + base + lane];
      float a = asv[sc] + ad;
      alpha = (a > 0.f) ? a : NEG_SLOPE * a;
    }
    float mx = alpha;
#pragma unroll
    for (int off = 1; off < 64; off <<= 1) mx = fmaxf(mx, __shfl_xor(mx, off));
    float mn = fmaxf(m, mx);
    float scale = __expf(m - mn);
    float w = (lane < rem) ? __expf(alpha - mn) : 0.f;
    float cs = w;
#pragma unroll
    for (int off = 1; off < 64; off <<= 1) cs += __shfl_xor(cs, off);
    s = s * scale + cs;
    m = mn;
    a0 *= scale; a1 *= scale; a2 *= scale; a3 *= scale;
    for (int e2 = 0; e2 < rem; e2 += 8) {
      int e = e2 + slot;
      float w_e = __shfl(w, e);
      int sc_e = __shfl(sc, e);
      uint2 hv = *(const uint2*)(hbuf + (size_t)sc_e * 32 + ci * 4);
      float f0, f1;
      bf2x(hv.x, f0, f1); a0 += w_e * f0; a1 += w_e * f1;
      bf2x(hv.y, f0, f1); a2 += w_e * f0; a3 += w_e * f1;
    }
  }
#pragma unroll
  for (int off = 8; off < 64; off <<= 1) {
    a0 += __shfl_xor(a0, off);
    a1 += __shfl_xor(a1, off);
    a2 += __shfl_xor(a2, off);
    a3 += __shfl_xor(a3, off);
  }
  if (slot == 0) {
    float inv = 1.f / (s + SM_EPS);
    f32x4 o;
    o.x = a0 * inv + bias[ci * 4 + 0];
    o.y = a1 * inv + bias[ci * 4 + 1];
    o.z = a2 * inv + bias[ci * 4 + 2];
    o.w = a3 * inv + bias[ci * 4 + 3];
    __builtin_nontemporal_store(o, (f32x4*)(out + (size_t)d * 32 + ci * 4));
  }
}

// ---------------------------------------------------------------------------
extern "C" void kernel_launch(void* const* d_in, const int* in_sizes, int n_in,
                              void* d_out, int out_size, void* d_ws, size_t ws_size,
                              hipStream_t stream) {
  const float* x   = (const float*)d_in[0];
  const int*   ei  = (const int*)d_in[1];
  const float* W1  = (const float*)d_in[2];
  const float* as1 = (const float*)d_in[3];
  const float* ad1 = (const float*)d_in[4];
  const float* b1  = (const float*)d_in[5];
  const float* W2  = (const float*)d_in[6];
  const float* as2 = (const float*)d_in[7];
  const float* ad2 = (const float*)d_in[8];
  const float* b2  = (const float*)d_in[9];
  const float* W3  = (const float*)d_in[10];
  const float* as3 = (const float*)d_in[11];
  const float* ad3 = (const float*)d_in[12];
  const float* b3  = (const float*)d_in[13];
  float* out = (float*)d_out;

  const int N = in_sizes[0] / 3;
  const int E = in_sizes[1] / 2;
  const int ET = E + N;  // with self loops

  char* ws = (char*)d_ws;
  size_t off = 0;
  auto alloc = [&](size_t bytes) -> void* {
    void* p = ws + off;
    off = (off + bytes + 255) & ~(size_t)255;
    return p;
  };
  unsigned short* bufA = (unsigned short*)alloc((size_t)N * 256 * 2);
  unsigned short* bufB = (unsigned short*)alloc((size_t)N * 256 * 2);
  unsigned short* w2t  = (unsigned short*)alloc((size_t)256 * 256 * 2);
  unsigned short* w3t  = (unsigned short*)alloc((size_t)32 * 256 * 2);
  float* asbuf  = (float*)alloc((size_t)N * 4 * 4);
  float* adbuf  = (float*)alloc((size_t)N * 4 * 4);
  float* asbuf2 = (float*)alloc((size_t)N * 4 * 4);
  float* adbuf2 = (float*)alloc((size_t)N * 4 * 4);
  int*   rowptr = (int*)alloc((size_t)(N + 1) * 4);
  int*   cnt    = (int*)alloc((size_t)N * 4);
  int*   posb   = (int*)alloc((size_t)E * 4);
  int*   colA   = (int*)alloc((size_t)ET * 4);
  int*   bsum   = (int*)alloc(1024);
  int*   dflag  = (int*)alloc(256);
  float* A2s    = (float*)alloc(1024 * 4);
  float* A2d    = (float*)alloc(1024 * 4);
  (void)ws_size;

  const int nScanB = (N + SCAN_CHUNK - 1) / SCAN_CHUNK;
  const int nbDeg = (E + 255) / 256;
  const int nbK1  = (N + 255) / 256;
  const int nbWt  = (256 * 256 + 256 * 32 + 255) / 256;

  // --- CSR build + weight prep (fused) ---
  detect_i64_kernel<<<1, 64, 0, stream>>>(ei, dflag);
  hipMemsetAsync(cnt, 0, (size_t)N * 4, stream);
  prep_mega<<<nbDeg + nbK1 + nbWt + 1, 256, 0, stream>>>(
      ei, E, dflag, cnt, posb, x, W1, as1, ad1, asbuf, adbuf, N,
      W2, W3, w2t, w3t, as2, ad2, A2s, A2d, nbDeg, nbK1, nbWt);
  scan_phaseA<<<nScanB, 256, 0, stream>>>(cnt, bsum, N);
  scan_phaseC<<<nScanB, 256, 0, stream>>>(cnt, bsum, rowptr, N);
  scatter2_kernel<<<(ET + 255) / 256, 256, 0, stream>>>(ei, E, N, dflag, rowptr, posb, colA);

  const int nb4 = (N + 3) / 4;

  // --- layer 1: fused agg(raw x) + W1 expand + asv2 epilogue -> bufB ---
  k2_fused<<<nb4, 256, 0, stream>>>(x, asbuf, adbuf, rowptr, colA, W1, b1,
                                    A2s, A2d, bufB, asbuf2, adbuf2, N);

  // --- layer 2: h2 = h1 @ W2 (MFMA) -> bufA ; fused agg -> bufB ---
  gemm_mfma_w256<<<(N + 127) / 128, 512, 0, stream>>>(bufB, w2t, bufA, N, 256);
  gat_fused256<true><<<nb4, 256, 0, stream>>>(bufA, asbuf2, adbuf2, rowptr, colA, b2, bufB, N);

  // --- layer 3: MFMA GEMM+attn -> bufA[0:N*32] ; fused agg -> out ---
  {
    dim3 grid(1, (N + 127) / 128);
    gemm_mfma<4, 1, 1><<<grid, 256, 0, stream>>>(bufB, w3t, bufA, as3, ad3, asbuf, adbuf,
                                                 N, 32, 256);
  }
  gat_fused32<<<nb4, 256, 0, stream>>>(bufA, asbuf, adbuf, rowptr, colA, b3, out, N);
}